// Round 1
// baseline (12431.290 us; speedup 1.0000x reference)
//
#include <hip/hip_runtime.h>
#include <math.h>

#define EMBED 512
#define HEADS 8
#define DH 64
#define MM 256
#define LSEG 17
#define NPAD 4352
#define NTOK 4097
#define N0 4096
#define BATCH 4
#define CIN 1536
#define QSCALE 0.125f
#define BH 32   // BATCH*HEADS

// ---------------- block reduction helpers (blockDim.x == 256) ----------------
__device__ __forceinline__ float block_sum(float v, float* red) {
  #pragma unroll
  for (int o = 1; o < 64; o <<= 1) v += __shfl_xor(v, o);
  int lane = threadIdx.x & 63, wid = threadIdx.x >> 6;
  if (lane == 0) red[wid] = v;
  __syncthreads();
  float r = red[0] + red[1] + red[2] + red[3];
  __syncthreads();
  return r;
}
__device__ __forceinline__ float block_max(float v, float* red) {
  #pragma unroll
  for (int o = 1; o < 64; o <<= 1) v = fmaxf(v, __shfl_xor(v, o));
  int lane = threadIdx.x & 63, wid = threadIdx.x >> 6;
  if (lane == 0) red[wid] = v;
  __syncthreads();
  float r = fmaxf(fmaxf(red[0], red[1]), fmaxf(red[2], red[3]));
  __syncthreads();
  return r;
}

// ---------------- generic tiled GEMM  C = A(M,K) @ W(N,K)^T  -----------------
// mode 0: v=relu(acc+bias); h[(b*NTOK+1+n)*EMBED+col] = v   (row = b*N0+n)
// mode 1: qkv scatter: sec=col/512 -> q/k/v[(b*H+hh)*NPAD+n)*DH+d], q *= QSCALE
// mode 2: out0[row*EMBED+col] += acc + bias[col]             (residual add)
__global__ __launch_bounds__(256) void gemm_abt(
    const float* __restrict__ A, const float* __restrict__ W,
    int Mrows, int Ncols, int K, const float* __restrict__ bias,
    float* __restrict__ out0, float* __restrict__ out1, float* __restrict__ out2,
    int mode)
{
  __shared__ float As[16][68];
  __shared__ float Bs[16][68];
  int tid = threadIdx.x;
  int tx = tid & 15, ty = tid >> 4;
  int rowBase = blockIdx.y * 64, colBase = blockIdx.x * 64;
  int lk = tid & 15, lr = tid >> 4;
  float acc[4][4] = {};
  for (int kb = 0; kb < K; kb += 16) {
    #pragma unroll
    for (int p = 0; p < 4; p++) {
      int r = lr + p * 16;
      int grow = rowBase + r;
      As[lk][r] = (grow < Mrows) ? A[(size_t)grow * K + kb + lk] : 0.f;
      int gcol = colBase + r;
      Bs[lk][r] = (gcol < Ncols) ? W[(size_t)gcol * K + kb + lk] : 0.f;
    }
    __syncthreads();
    #pragma unroll
    for (int kk = 0; kk < 16; kk++) {
      float a0[4], b0[4];
      #pragma unroll
      for (int i = 0; i < 4; i++) a0[i] = As[kk][ty * 4 + i];
      #pragma unroll
      for (int j = 0; j < 4; j++) b0[j] = Bs[kk][tx * 4 + j];
      #pragma unroll
      for (int i = 0; i < 4; i++)
        #pragma unroll
        for (int j = 0; j < 4; j++) acc[i][j] += a0[i] * b0[j];
    }
    __syncthreads();
  }
  #pragma unroll
  for (int i = 0; i < 4; i++) {
    int row = rowBase + ty * 4 + i;
    if (row >= Mrows) continue;
    #pragma unroll
    for (int j = 0; j < 4; j++) {
      int col = colBase + tx * 4 + j;
      float v = acc[i][j];
      if (mode == 0) {
        v += bias[col];
        v = fmaxf(v, 0.f);
        int b = row / N0, n = row % N0;
        out0[((size_t)b * NTOK + 1 + n) * EMBED + col] = v;
      } else if (mode == 1) {
        int b = row / NPAD, n = row % NPAD;
        int sec = col / EMBED;
        int hh = (col % EMBED) / DH;
        int d = col & 63;
        float* dst = (sec == 0) ? out0 : ((sec == 1) ? out1 : out2);
        if (sec == 0) v *= QSCALE;
        dst[(((size_t)b * HEADS + hh) * NPAD + n) * DH + d] = v;
      } else {
        v += bias[col];
        out0[(size_t)row * EMBED + col] += v;
      }
    }
  }
}

// ------------- batched NN GEMM:  C = gamma * A @ (beta*I + sgn*B) ------------
// A: (batch, Msize, K)  B: (batch, K, Nsize)  C: (batch, Msize, Nsize)
__global__ __launch_bounds__(256) void gemm_nn_batched(
    const float* __restrict__ A, const float* __restrict__ B, float* __restrict__ C,
    int Msize, int Nsize, int K, float beta_diag, float sgn, float gamma)
{
  __shared__ float As[16][68];
  __shared__ float Bs[16][68];
  int batch = blockIdx.z;
  const float* Ab = A + (size_t)batch * Msize * K;
  const float* Bb = B + (size_t)batch * K * Nsize;
  float* Cb = C + (size_t)batch * Msize * Nsize;
  int tid = threadIdx.x;
  int tx = tid & 15, ty = tid >> 4;
  int rowBase = blockIdx.y * 64, colBase = blockIdx.x * 64;
  int lkA = tid & 15, lrA = tid >> 4;
  int lcB = tid & 63, lkB = tid >> 6;
  float acc[4][4] = {};
  for (int kb = 0; kb < K; kb += 16) {
    #pragma unroll
    for (int p = 0; p < 4; p++) {
      int r = lrA + p * 16;
      As[lkA][r] = Ab[(size_t)(rowBase + r) * K + kb + lkA];
    }
    #pragma unroll
    for (int p = 0; p < 4; p++) {
      int kk = lkB + p * 4;
      int gc = colBase + lcB;
      float v = (gc < Nsize) ? Bb[(size_t)(kb + kk) * Nsize + gc] : 0.f;
      v = sgn * v + ((kb + kk) == gc ? beta_diag : 0.f);
      Bs[kk][lcB] = v;
    }
    __syncthreads();
    #pragma unroll
    for (int kk = 0; kk < 16; kk++) {
      float a0[4], b0[4];
      #pragma unroll
      for (int i = 0; i < 4; i++) a0[i] = As[kk][ty * 4 + i];
      #pragma unroll
      for (int j = 0; j < 4; j++) b0[j] = Bs[kk][tx * 4 + j];
      #pragma unroll
      for (int i = 0; i < 4; i++)
        #pragma unroll
        for (int j = 0; j < 4; j++) acc[i][j] += a0[i] * b0[j];
    }
    __syncthreads();
  }
  #pragma unroll
  for (int i = 0; i < 4; i++) {
    int row = rowBase + ty * 4 + i;
    #pragma unroll
    for (int j = 0; j < 4; j++) {
      int col = colBase + tx * 4 + j;
      if (col < Nsize) Cb[(size_t)row * Nsize + col] = gamma * acc[i][j];
    }
  }
}

// ---------------- small utility kernels ----------------
__global__ void cls_kernel(const float* __restrict__ cls, float* __restrict__ h) {
  int t = blockIdx.x * blockDim.x + threadIdx.x;
  if (t >= BATCH * EMBED) return;
  int b = t / EMBED, c = t % EMBED;
  h[(size_t)b * NTOK * EMBED + c] = cls[c];
}

__global__ void zero_pad_kernel(float* __restrict__ xpad) {
  int t = blockIdx.x * blockDim.x + threadIdx.x;
  const int per = 255 * EMBED;
  if (t >= BATCH * per) return;
  int b = t / per, r = t % per;
  xpad[(size_t)b * NPAD * EMBED + r] = 0.f;
}

__global__ __launch_bounds__(256) void ln_pad_kernel(
    const float* __restrict__ h, const float* __restrict__ g,
    const float* __restrict__ be, float* __restrict__ xpad)
{
  __shared__ float red[4];
  int row = blockIdx.x;
  int b = row / NTOK, j = row % NTOK;
  const float* x = h + (size_t)row * EMBED;
  int tid = threadIdx.x;
  float v0 = x[tid], v1 = x[tid + 256];
  float mu = block_sum(v0 + v1, red) * (1.f / 512.f);
  float d0 = v0 - mu, d1 = v1 - mu;
  float var = block_sum(d0 * d0 + d1 * d1, red) * (1.f / 512.f);
  float inv = 1.f / sqrtf(var + 1e-5f);
  float* o = xpad + ((size_t)b * NPAD + 255 + j) * EMBED;
  o[tid]       = d0 * inv * g[tid]       + be[tid];
  o[tid + 256] = d1 * inv * g[tid + 256] + be[tid + 256];
}

__global__ __launch_bounds__(256) void landmarks_kernel(
    const float* __restrict__ q, const float* __restrict__ k,
    float* __restrict__ qland, float* __restrict__ kland)
{
  int bh = blockIdx.y;
  int m = blockIdx.x * 4 + (threadIdx.x >> 6);
  int d = threadIdx.x & 63;
  const float* qb = q + (size_t)bh * NPAD * DH;
  const float* kb = k + (size_t)bh * NPAD * DH;
  float sq = 0.f, sk = 0.f;
  int base = m * LSEG;
  #pragma unroll
  for (int t = 0; t < LSEG; t++) {
    sq += qb[(size_t)(base + t) * DH + d];
    sk += kb[(size_t)(base + t) * DH + d];
  }
  qland[((size_t)bh * MM + m) * DH + d] = sq * (1.f / LSEG);
  kland[((size_t)bh * MM + m) * DH + d] = sk * (1.f / LSEG);
}

__global__ __launch_bounds__(256) void s2_softmax_kernel(
    const float* __restrict__ qland, const float* __restrict__ kland,
    float* __restrict__ a2)
{
  __shared__ float qrow[64];
  __shared__ float red[4];
  int bh = blockIdx.y, m = blockIdx.x, tid = threadIdx.x;
  if (tid < 64) qrow[tid] = qland[((size_t)bh * MM + m) * DH + tid];
  __syncthreads();
  const float* kb = kland + (size_t)bh * MM * DH + (size_t)tid * DH;
  float s = 0.f;
  #pragma unroll 16
  for (int d = 0; d < 64; d++) s += qrow[d] * kb[d];
  float mx = block_max(s, red);
  float e = __expf(s - mx);
  float tot = block_sum(e, red);
  a2[((size_t)bh * MM + m) * MM + tid] = e / tot;
}

__global__ void init_denom_kernel(float* __restrict__ denoms) {
  if (threadIdx.x < 2) denoms[threadIdx.x] = 0.f;
}

__global__ __launch_bounds__(256) void denom_kernel(
    const float* __restrict__ a2, float* __restrict__ denoms)
{
  __shared__ float red[4];
  int bh = blockIdx.x, tid = threadIdx.x;
  const float* A = a2 + (size_t)bh * MM * MM;
  float rs = 0.f, cs = 0.f;
  for (int j = 0; j < MM; j++) rs += A[(size_t)tid * MM + j];
  for (int i = 0; i < MM; i++) cs += A[(size_t)i * MM + tid];
  float mr = block_max(rs, red);
  float mc = block_max(cs, red);
  if (tid == 0) {
    atomicMax((int*)&denoms[0], __float_as_int(mr));
    atomicMax((int*)&denoms[1], __float_as_int(mc));
  }
}

__global__ void z0_kernel(const float* __restrict__ a2,
                          const float* __restrict__ denoms, float* __restrict__ z)
{
  int bh = blockIdx.z;
  int i = blockIdx.y * 4 + threadIdx.y;
  int j = blockIdx.x * 64 + threadIdx.x;
  float denom = denoms[0] * denoms[1];
  z[((size_t)bh * MM + i) * MM + j] = a2[((size_t)bh * MM + j) * MM + i] / denom;
}

// a3 = softmax(q_land @ k^T) row, fused with @ v  ->  kv (bh, 256, 64)
__global__ __launch_bounds__(256) void a3v_kernel(
    const float* __restrict__ qland, const float* __restrict__ k,
    const float* __restrict__ v, float* __restrict__ kv)
{
  __shared__ float sc[NPAD];
  __shared__ float red[4];
  __shared__ float outp[4][64];
  int bh = blockIdx.y, m = blockIdx.x;
  int tid = threadIdx.x, wid = tid >> 6, lane = tid & 63;
  const float* kb = k + (size_t)bh * NPAD * DH;
  const float* vb = v + (size_t)bh * NPAD * DH;
  float ql = qland[((size_t)bh * MM + m) * DH + lane];
  for (int n = wid; n < NPAD; n += 4) {
    float p = ql * kb[(size_t)n * DH + lane];
    #pragma unroll
    for (int o = 1; o < 64; o <<= 1) p += __shfl_xor(p, o);
    if (lane == 0) sc[n] = p;
  }
  __syncthreads();
  float mx = -3.0e38f;
  for (int n = tid; n < NPAD; n += 256) mx = fmaxf(mx, sc[n]);
  mx = block_max(mx, red);
  float sm = 0.f;
  for (int n = tid; n < NPAD; n += 256) {
    float e = __expf(sc[n] - mx);
    sc[n] = e;
    sm += e;
  }
  float tot = block_sum(sm, red);
  float invs = 1.f / tot;
  float acc = 0.f;
  int n0 = wid * (NPAD / 4), n1 = n0 + NPAD / 4;
  for (int n = n0; n < n1; n++) acc += sc[n] * vb[(size_t)n * DH + lane];
  outp[wid][lane] = acc;
  __syncthreads();
  if (wid == 0) {
    float r = (outp[0][lane] + outp[1][lane] + outp[2][lane] + outp[3][lane]) * invs;
    kv[((size_t)bh * MM + m) * DH + lane] = r;
  }
}

// a1 row softmax fused with @ kv2, plus depthwise res-conv(33) on v
__global__ __launch_bounds__(256) void a1_res_kernel(
    const float* __restrict__ q, const float* __restrict__ kland,
    const float* __restrict__ kv2, const float* __restrict__ v,
    const float* __restrict__ resw, float* __restrict__ attn)
{
  __shared__ float qrow[64];
  __shared__ float sc[256];
  __shared__ float red[4];
  __shared__ float outp[4][64];
  int bh = blockIdx.y, tid = threadIdx.x, wid = tid >> 6, lane = tid & 63;
  int b = bh >> 3, hh = bh & 7;
  int n = 255 + blockIdx.x;
  if (tid < 64) qrow[tid] = q[((size_t)bh * NPAD + n) * DH + tid];
  __syncthreads();
  const float* klb = kland + (size_t)bh * MM * DH + (size_t)tid * DH;
  float s = 0.f;
  #pragma unroll 16
  for (int d = 0; d < 64; d++) s += qrow[d] * klb[d];
  float mx = block_max(s, red);
  float e = __expf(s - mx);
  sc[tid] = e;
  float tot = block_sum(e, red);
  float invs = 1.f / tot;
  const float* kvb = kv2 + (size_t)bh * MM * DH;
  float acc = 0.f;
  int j0 = wid * 64;
  for (int j = j0; j < j0 + 64; j++) acc += sc[j] * kvb[(size_t)j * DH + lane];
  outp[wid][lane] = acc;
  __syncthreads();
  if (wid == 0) {
    float o = (outp[0][lane] + outp[1][lane] + outp[2][lane] + outp[3][lane]) * invs;
    const float* vb = v + (size_t)bh * NPAD * DH;
    const float* w = resw + hh * 33;
    float r = 0.f;
    #pragma unroll
    for (int t = 0; t < 33; t++) {
      int nn = n - 16 + t;
      if (nn < NPAD) r += vb[(size_t)nn * DH + lane] * w[t];
    }
    attn[((size_t)b * NTOK + (n - 255)) * EMBED + hh * DH + lane] = o + r;
  }
}

// combine 7x7 + 5x5 + 3x3 + identity into one 7x7 depthwise kernel
__global__ void prep_wcomb_kernel(
    const float* __restrict__ pw7, const float* __restrict__ pw5,
    const float* __restrict__ pw3, const float* __restrict__ pb7,
    const float* __restrict__ pb5, const float* __restrict__ pb3,
    float* __restrict__ wcomb, float* __restrict__ biasc)
{
  int i = blockIdx.x * blockDim.x + threadIdx.x;
  if (i < EMBED * 49) {
    int c = i / 49, tap = i % 49;
    int ky = tap / 7, kx = tap % 7;
    float v = pw7[c * 49 + tap];
    if (ky >= 1 && ky <= 5 && kx >= 1 && kx <= 5) v += pw5[c * 25 + (ky - 1) * 5 + (kx - 1)];
    if (ky >= 2 && ky <= 4 && kx >= 2 && kx <= 4) v += pw3[c * 9 + (ky - 2) * 3 + (kx - 2)];
    if (ky == 3 && kx == 3) v += 1.f;
    wcomb[tap * EMBED + c] = v;
  }
  if (i < EMBED) biasc[i] = pb7[i] + pb5[i] + pb3[i];
}

__global__ void copy_feat_kernel(const float* __restrict__ h, float* __restrict__ tmp) {
  size_t t = (size_t)blockIdx.x * blockDim.x + threadIdx.x;
  if (t >= (size_t)BATCH * N0 * EMBED) return;
  size_t per = (size_t)N0 * EMBED;
  size_t b = t / per, r = t % per;
  tmp[t] = h[((size_t)b * NTOK + 1) * EMBED + r];
}

__global__ __launch_bounds__(256) void dwconv_kernel(
    const float* __restrict__ tmp, const float* __restrict__ wcomb,
    const float* __restrict__ biasc, float* __restrict__ h)
{
  __shared__ float wsm[49][64];
  int cb = blockIdx.x * 64;
  int c = cb + threadIdx.x;
  int b = blockIdx.z;
  int n = blockIdx.y * 4 + threadIdx.y;
  int y = n >> 6, x = n & 63;
  int tid = threadIdx.y * 64 + threadIdx.x;
  for (int i = tid; i < 49 * 64; i += 256) {
    int tap = i >> 6, cc = i & 63;
    wsm[tap][cc] = wcomb[tap * EMBED + cb + cc];
  }
  __syncthreads();
  const float* src = tmp + (size_t)b * N0 * EMBED;
  float acc = biasc[c];
  #pragma unroll
  for (int ky = 0; ky < 7; ky++) {
    int yy = y + ky - 3;
    if (yy < 0 || yy >= 64) continue;
    #pragma unroll
    for (int kx = 0; kx < 7; kx++) {
      int xx = x + kx - 3;
      if (xx < 0 || xx >= 64) continue;
      acc += src[((size_t)yy * 64 + xx) * EMBED + c] * wsm[ky * 7 + kx][threadIdx.x];
    }
  }
  h[((size_t)b * NTOK + 1 + n) * EMBED + c] = acc;
}

__global__ __launch_bounds__(256) void final_kernel(
    const float* __restrict__ h, const float* __restrict__ g,
    const float* __restrict__ be, const float* __restrict__ W2,
    const float* __restrict__ b2, float* __restrict__ out)
{
  __shared__ float red[4];
  int b = blockIdx.x, tid = threadIdx.x;
  const float* x = h + (size_t)b * NTOK * EMBED;
  float v0 = x[tid], v1 = x[tid + 256];
  float mu = block_sum(v0 + v1, red) * (1.f / 512.f);
  float d0 = v0 - mu, d1 = v1 - mu;
  float var = block_sum(d0 * d0 + d1 * d1, red) * (1.f / 512.f);
  float inv = 1.f / sqrtf(var + 1e-5f);
  float xn0 = d0 * inv * g[tid] + be[tid];
  float xn1 = d1 * inv * g[tid + 256] + be[tid + 256];
  float l0 = block_sum(xn0 * W2[tid] + xn1 * W2[tid + 256], red);
  float l1 = block_sum(xn0 * W2[512 + tid] + xn1 * W2[512 + tid + 256], red);
  if (tid == 0) {
    l0 += b2[0]; l1 += b2[1];
    out[b * 2 + 0] = l0;
    out[b * 2 + 1] = l1;
    float mx = fmaxf(l0, l1);
    float e0 = expf(l0 - mx), e1 = expf(l1 - mx);
    float s = e0 + e1;
    out[8 + b * 2 + 0] = e0 / s;
    out[8 + b * 2 + 1] = e1 / s;
    out[16 + b] = (l1 > l0) ? 1.f : 0.f;
  }
}

// ------------------------------- host side -----------------------------------
extern "C" void kernel_launch(void* const* d_in, const int* in_sizes, int n_in,
                              void* d_out, int out_size, void* d_ws, size_t ws_size,
                              hipStream_t stream)
{
  const float* data = (const float*)d_in[0];
  const float* W1   = (const float*)d_in[1];
  const float* b1   = (const float*)d_in[2];
  const float* cls  = (const float*)d_in[3];
  const float* lng[2]  = {(const float*)d_in[4],  (const float*)d_in[10]};
  const float* lnb[2]  = {(const float*)d_in[5],  (const float*)d_in[11]};
  const float* Wqkv[2] = {(const float*)d_in[6],  (const float*)d_in[12]};
  const float* Wo[2]   = {(const float*)d_in[7],  (const float*)d_in[13]};
  const float* bo[2]   = {(const float*)d_in[8],  (const float*)d_in[14]};
  const float* resw[2] = {(const float*)d_in[9],  (const float*)d_in[15]};
  const float* pw7 = (const float*)d_in[16];
  const float* pb7 = (const float*)d_in[17];
  const float* pw5 = (const float*)d_in[18];
  const float* pb5 = (const float*)d_in[19];
  const float* pw3 = (const float*)d_in[20];
  const float* pb3 = (const float*)d_in[21];
  const float* lnfg = (const float*)d_in[22];
  const float* lnfb = (const float*)d_in[23];
  const float* W2  = (const float*)d_in[24];
  const float* b2  = (const float*)d_in[25];

  float* ws = (float*)d_ws;
  size_t off = 0;
  auto alloc = [&](size_t n) { float* p = ws + off; off += n; return p; };
  float* hbuf  = alloc((size_t)BATCH * NTOK * EMBED);
  float* xpad  = alloc((size_t)BATCH * NPAD * EMBED);   // also reused as attn_out
  float* qbuf  = alloc((size_t)BH * NPAD * DH);         // also reused as conv tmp
  float* kbuf  = alloc((size_t)BH * NPAD * DH);
  float* vbuf  = alloc((size_t)BH * NPAD * DH);
  float* qland = alloc((size_t)BH * MM * DH);
  float* kland = alloc((size_t)BH * MM * DH);
  float* a2    = alloc((size_t)BH * MM * MM);
  float* za    = alloc((size_t)BH * MM * MM);
  float* zb    = alloc((size_t)BH * MM * MM);
  float* xzb   = alloc((size_t)BH * MM * MM);
  float* t1b   = alloc((size_t)BH * MM * MM);
  float* t2b   = alloc((size_t)BH * MM * MM);
  float* kvb   = alloc((size_t)BH * MM * DH);
  float* kv2b  = alloc((size_t)BH * MM * DH);
  float* wcomb = alloc(49 * EMBED);
  float* biasc = alloc(EMBED);
  float* denoms = alloc(64);
  float* attn = xpad;

  // h = relu(data @ W1^T + b1), plus cls row
  gemm_abt<<<dim3(EMBED / 64, (BATCH * N0) / 64), 256, 0, stream>>>(
      data, W1, BATCH * N0, EMBED, CIN, b1, hbuf, nullptr, nullptr, 0);
  cls_kernel<<<dim3((BATCH * EMBED + 255) / 256), 256, 0, stream>>>(cls, hbuf);

  for (int layer = 0; layer < 2; layer++) {
    ln_pad_kernel<<<dim3(BATCH * NTOK), 256, 0, stream>>>(hbuf, lng[layer], lnb[layer], xpad);
    zero_pad_kernel<<<dim3((BATCH * 255 * EMBED + 255) / 256), 256, 0, stream>>>(xpad);
    gemm_abt<<<dim3((3 * EMBED) / 64, (BATCH * NPAD) / 64), 256, 0, stream>>>(
        xpad, Wqkv[layer], BATCH * NPAD, 3 * EMBED, EMBED, nullptr, qbuf, kbuf, vbuf, 1);
    landmarks_kernel<<<dim3(MM / 4, BH), 256, 0, stream>>>(qbuf, kbuf, qland, kland);
    s2_softmax_kernel<<<dim3(MM, BH), 256, 0, stream>>>(qland, kland, a2);
    init_denom_kernel<<<1, 64, 0, stream>>>(denoms);
    denom_kernel<<<dim3(BH), 256, 0, stream>>>(a2, denoms);
    z0_kernel<<<dim3(MM / 64, MM / 4, BH), dim3(64, 4), 0, stream>>>(a2, denoms, za);
    float* zin = za;
    float* zout = zb;
    for (int it = 0; it < 6; it++) {
      gemm_nn_batched<<<dim3(4, 4, BH), 256, 0, stream>>>(a2, zin, xzb, MM, MM, MM, 0.f, 1.f, 1.f);
      gemm_nn_batched<<<dim3(4, 4, BH), 256, 0, stream>>>(xzb, xzb, t1b, MM, MM, MM, 7.f, -1.f, 1.f);
      gemm_nn_batched<<<dim3(4, 4, BH), 256, 0, stream>>>(xzb, t1b, t2b, MM, MM, MM, 15.f, -1.f, 1.f);
      gemm_nn_batched<<<dim3(4, 4, BH), 256, 0, stream>>>(zin, t2b, zout, MM, MM, MM, 13.f, -1.f, 0.25f);
      float* t = zin; zin = zout; zout = t;
    }
    a3v_kernel<<<dim3(MM, BH), 256, 0, stream>>>(qland, kbuf, vbuf, kvb);
    gemm_nn_batched<<<dim3(1, 4, BH), 256, 0, stream>>>(zin, kvb, kv2b, MM, DH, MM, 0.f, 1.f, 1.f);
    a1_res_kernel<<<dim3(NTOK, BH), 256, 0, stream>>>(qbuf, kland, kv2b, vbuf, resw[layer], attn);
    gemm_abt<<<dim3(EMBED / 64, (BATCH * NTOK + 63) / 64), 256, 0, stream>>>(
        attn, Wo[layer], BATCH * NTOK, EMBED, EMBED, bo[layer], hbuf, nullptr, nullptr, 2);

    if (layer == 0) {
      prep_wcomb_kernel<<<dim3((EMBED * 49 + 255) / 256), 256, 0, stream>>>(
          pw7, pw5, pw3, pb7, pb5, pb3, wcomb, biasc);
      copy_feat_kernel<<<dim3((unsigned)(((size_t)BATCH * N0 * EMBED + 255) / 256)), 256, 0, stream>>>(hbuf, qbuf);
      dwconv_kernel<<<dim3(EMBED / 64, N0 / 4, BATCH), dim3(64, 4), 0, stream>>>(qbuf, wcomb, biasc, hbuf);
    }
  }

  final_kernel<<<dim3(BATCH), 256, 0, stream>>>(hbuf, lnfg, lnfb, W2, b2, (float*)d_out);
}

// Round 2
// 6445.109 us; speedup vs baseline: 1.9288x; 1.9288x over previous
//
#include <hip/hip_runtime.h>
#include <math.h>

#define EMBED 512
#define HEADS 8
#define DH 64
#define MM 256
#define LSEG 17
#define NPAD 4352
#define NTOK 4097
#define N0 4096
#define BATCH 4
#define CIN 1536
#define QSCALE 0.125f
#define BH 32   // BATCH*HEADS

// ---------------- block reduction helpers (blockDim.x == 256) ----------------
__device__ __forceinline__ float block_sum(float v, float* red) {
  #pragma unroll
  for (int o = 1; o < 64; o <<= 1) v += __shfl_xor(v, o);
  int lane = threadIdx.x & 63, wid = threadIdx.x >> 6;
  if (lane == 0) red[wid] = v;
  __syncthreads();
  float r = red[0] + red[1] + red[2] + red[3];
  __syncthreads();
  return r;
}
__device__ __forceinline__ float block_max(float v, float* red) {
  #pragma unroll
  for (int o = 1; o < 64; o <<= 1) v = fmaxf(v, __shfl_xor(v, o));
  int lane = threadIdx.x & 63, wid = threadIdx.x >> 6;
  if (lane == 0) red[wid] = v;
  __syncthreads();
  float r = fmaxf(fmaxf(red[0], red[1]), fmaxf(red[2], red[3]));
  __syncthreads();
  return r;
}

// ---------------- generic tiled GEMM  C = A(M,K) @ W(N,K)^T  -----------------
__global__ __launch_bounds__(256) void gemm_abt(
    const float* __restrict__ A, const float* __restrict__ W,
    int Mrows, int Ncols, int K, const float* __restrict__ bias,
    float* __restrict__ out0, float* __restrict__ out1, float* __restrict__ out2,
    int mode)
{
  __shared__ float As[16][68];
  __shared__ float Bs[16][68];
  int tid = threadIdx.x;
  int tx = tid & 15, ty = tid >> 4;
  int rowBase = blockIdx.y * 64, colBase = blockIdx.x * 64;
  int lk = tid & 15, lr = tid >> 4;
  float acc[4][4] = {};
  for (int kb = 0; kb < K; kb += 16) {
    #pragma unroll
    for (int p = 0; p < 4; p++) {
      int r = lr + p * 16;
      int grow = rowBase + r;
      As[lk][r] = (grow < Mrows) ? A[(size_t)grow * K + kb + lk] : 0.f;
      int gcol = colBase + r;
      Bs[lk][r] = (gcol < Ncols) ? W[(size_t)gcol * K + kb + lk] : 0.f;
    }
    __syncthreads();
    #pragma unroll
    for (int kk = 0; kk < 16; kk++) {
      float a0[4], b0[4];
      #pragma unroll
      for (int i = 0; i < 4; i++) a0[i] = As[kk][ty * 4 + i];
      #pragma unroll
      for (int j = 0; j < 4; j++) b0[j] = Bs[kk][tx * 4 + j];
      #pragma unroll
      for (int i = 0; i < 4; i++)
        #pragma unroll
        for (int j = 0; j < 4; j++) acc[i][j] += a0[i] * b0[j];
    }
    __syncthreads();
  }
  #pragma unroll
  for (int i = 0; i < 4; i++) {
    int row = rowBase + ty * 4 + i;
    if (row >= Mrows) continue;
    #pragma unroll
    for (int j = 0; j < 4; j++) {
      int col = colBase + tx * 4 + j;
      float v = acc[i][j];
      if (mode == 0) {
        v += bias[col];
        v = fmaxf(v, 0.f);
        int b = row / N0, n = row % N0;
        out0[((size_t)b * NTOK + 1 + n) * EMBED + col] = v;
      } else if (mode == 1) {
        int b = row / NPAD, n = row % NPAD;
        int sec = col / EMBED;
        int hh = (col % EMBED) / DH;
        int d = col & 63;
        float* dst = (sec == 0) ? out0 : ((sec == 1) ? out1 : out2);
        if (sec == 0) v *= QSCALE;
        dst[(((size_t)b * HEADS + hh) * NPAD + n) * DH + d] = v;
      } else {
        v += bias[col];
        out0[(size_t)row * EMBED + col] += v;
      }
    }
  }
}

// ------------- batched NN GEMM:  C = gamma * A @ (beta*I + sgn*B) ------------
__global__ __launch_bounds__(256) void gemm_nn_batched(
    const float* __restrict__ A, const float* __restrict__ B, float* __restrict__ C,
    int Msize, int Nsize, int K, float beta_diag, float sgn, float gamma)
{
  __shared__ float As[16][68];
  __shared__ float Bs[16][68];
  int batch = blockIdx.z;
  const float* Ab = A + (size_t)batch * Msize * K;
  const float* Bb = B + (size_t)batch * K * Nsize;
  float* Cb = C + (size_t)batch * Msize * Nsize;
  int tid = threadIdx.x;
  int tx = tid & 15, ty = tid >> 4;
  int rowBase = blockIdx.y * 64, colBase = blockIdx.x * 64;
  int lkA = tid & 15, lrA = tid >> 4;
  int lcB = tid & 63, lkB = tid >> 6;
  float acc[4][4] = {};
  for (int kb = 0; kb < K; kb += 16) {
    #pragma unroll
    for (int p = 0; p < 4; p++) {
      int r = lrA + p * 16;
      As[lkA][r] = Ab[(size_t)(rowBase + r) * K + kb + lkA];
    }
    #pragma unroll
    for (int p = 0; p < 4; p++) {
      int kk = lkB + p * 4;
      int gc = colBase + lcB;
      float v = (gc < Nsize) ? Bb[(size_t)(kb + kk) * Nsize + gc] : 0.f;
      v = sgn * v + ((kb + kk) == gc ? beta_diag : 0.f);
      Bs[kk][lcB] = v;
    }
    __syncthreads();
    #pragma unroll
    for (int kk = 0; kk < 16; kk++) {
      float a0[4], b0[4];
      #pragma unroll
      for (int i = 0; i < 4; i++) a0[i] = As[kk][ty * 4 + i];
      #pragma unroll
      for (int j = 0; j < 4; j++) b0[j] = Bs[kk][tx * 4 + j];
      #pragma unroll
      for (int i = 0; i < 4; i++)
        #pragma unroll
        for (int j = 0; j < 4; j++) acc[i][j] += a0[i] * b0[j];
    }
    __syncthreads();
  }
  #pragma unroll
  for (int i = 0; i < 4; i++) {
    int row = rowBase + ty * 4 + i;
    #pragma unroll
    for (int j = 0; j < 4; j++) {
      int col = colBase + tx * 4 + j;
      if (col < Nsize) Cb[(size_t)row * Nsize + col] = gamma * acc[i][j];
    }
  }
}

// ---------------- small utility kernels ----------------
__global__ void cls_kernel(const float* __restrict__ cls, float* __restrict__ h) {
  int t = blockIdx.x * blockDim.x + threadIdx.x;
  if (t >= BATCH * EMBED) return;
  int b = t / EMBED, c = t % EMBED;
  h[(size_t)b * NTOK * EMBED + c] = cls[c];
}

__global__ void zero_pad_kernel(float* __restrict__ xpad) {
  int t = blockIdx.x * blockDim.x + threadIdx.x;
  const int per = 255 * EMBED;
  if (t >= BATCH * per) return;
  int b = t / per, r = t % per;
  xpad[(size_t)b * NPAD * EMBED + r] = 0.f;
}

__global__ __launch_bounds__(256) void ln_pad_kernel(
    const float* __restrict__ h, const float* __restrict__ g,
    const float* __restrict__ be, float* __restrict__ xpad)
{
  __shared__ float red[4];
  int row = blockIdx.x;
  int b = row / NTOK, j = row % NTOK;
  const float* x = h + (size_t)row * EMBED;
  int tid = threadIdx.x;
  float v0 = x[tid], v1 = x[tid + 256];
  float mu = block_sum(v0 + v1, red) * (1.f / 512.f);
  float d0 = v0 - mu, d1 = v1 - mu;
  float var = block_sum(d0 * d0 + d1 * d1, red) * (1.f / 512.f);
  float inv = 1.f / sqrtf(var + 1e-5f);
  float* o = xpad + ((size_t)b * NPAD + 255 + j) * EMBED;
  o[tid]       = d0 * inv * g[tid]       + be[tid];
  o[tid + 256] = d1 * inv * g[tid + 256] + be[tid + 256];
}

__global__ __launch_bounds__(256) void landmarks_kernel(
    const float* __restrict__ q, const float* __restrict__ k,
    float* __restrict__ qland, float* __restrict__ kland)
{
  int bh = blockIdx.y;
  int m = blockIdx.x * 4 + (threadIdx.x >> 6);
  int d = threadIdx.x & 63;
  const float* qb = q + (size_t)bh * NPAD * DH;
  const float* kb = k + (size_t)bh * NPAD * DH;
  float sq = 0.f, sk = 0.f;
  int base = m * LSEG;
  #pragma unroll
  for (int t = 0; t < LSEG; t++) {
    sq += qb[(size_t)(base + t) * DH + d];
    sk += kb[(size_t)(base + t) * DH + d];
  }
  qland[((size_t)bh * MM + m) * DH + d] = sq * (1.f / LSEG);
  kland[((size_t)bh * MM + m) * DH + d] = sk * (1.f / LSEG);
}

__global__ __launch_bounds__(256) void s2_softmax_kernel(
    const float* __restrict__ qland, const float* __restrict__ kland,
    float* __restrict__ a2)
{
  __shared__ float qrow[64];
  __shared__ float red[4];
  int bh = blockIdx.y, m = blockIdx.x, tid = threadIdx.x;
  if (tid < 64) qrow[tid] = qland[((size_t)bh * MM + m) * DH + tid];
  __syncthreads();
  const float* kb = kland + (size_t)bh * MM * DH + (size_t)tid * DH;
  float s = 0.f;
  #pragma unroll 16
  for (int d = 0; d < 64; d++) s += qrow[d] * kb[d];
  float mx = block_max(s, red);
  float e = __expf(s - mx);
  float tot = block_sum(e, red);
  a2[((size_t)bh * MM + m) * MM + tid] = e / tot;
}

__global__ void init_denom_kernel(float* __restrict__ denoms) {
  if (threadIdx.x < 2) denoms[threadIdx.x] = 0.f;
}

__global__ __launch_bounds__(256) void denom_kernel(
    const float* __restrict__ a2, float* __restrict__ denoms)
{
  __shared__ float red[4];
  int bh = blockIdx.x, tid = threadIdx.x;
  const float* A = a2 + (size_t)bh * MM * MM;
  float rs = 0.f, cs = 0.f;
  for (int j = 0; j < MM; j++) rs += A[(size_t)tid * MM + j];
  for (int i = 0; i < MM; i++) cs += A[(size_t)i * MM + tid];
  float mr = block_max(rs, red);
  float mc = block_max(cs, red);
  if (tid == 0) {
    atomicMax((int*)&denoms[0], __float_as_int(mr));
    atomicMax((int*)&denoms[1], __float_as_int(mc));
  }
}

__global__ void z0_kernel(const float* __restrict__ a2,
                          const float* __restrict__ denoms, float* __restrict__ z)
{
  int bh = blockIdx.z;
  int i = blockIdx.y * 4 + threadIdx.y;
  int j = blockIdx.x * 64 + threadIdx.x;
  float denom = denoms[0] * denoms[1];
  z[((size_t)bh * MM + i) * MM + j] = a2[((size_t)bh * MM + j) * MM + i] / denom;
}

// ---------- a3@v, flash-style: block = 32 landmarks x one bh -----------------
// s3 = qland(256,64) @ k^T(64,4352); softmax over 4352; @ v(4352,64) -> kv
__global__ __launch_bounds__(256) void a3v_flash_kernel(
    const float* __restrict__ qland, const float* __restrict__ k,
    const float* __restrict__ v, float* __restrict__ kv)
{
  __shared__ float qs[32][65];
  __shared__ float ks[64][65];
  __shared__ float vs[64][65];
  __shared__ float ps[32][65];
  int bh = blockIdx.y;
  int l0 = blockIdx.x * 32;
  int tid = threadIdx.x;
  int tx = tid & 15, ty = tid >> 4;
  int r0 = ty * 2, r1 = r0 + 1;
  const float* kb = k + (size_t)bh * NPAD * DH;
  const float* vb = v + (size_t)bh * NPAD * DH;

  for (int i = tid; i < 32 * 64; i += 256)
    qs[i >> 6][i & 63] = qland[((size_t)bh * MM + l0 + (i >> 6)) * DH + (i & 63)];

  float O[2][4] = {};
  float mrow[2] = {-3.0e38f, -3.0e38f};
  float lrow[2] = {0.f, 0.f};

  for (int nt = 0; nt < NPAD / 64; nt++) {
    __syncthreads();   // protect ks/vs (and qs on first iter)
    for (int i = tid; i < 64 * 64; i += 256) {
      int lr = i >> 6, d = i & 63;
      ks[lr][d] = kb[(size_t)(nt * 64 + lr) * DH + d];
      vs[lr][d] = vb[(size_t)(nt * 64 + lr) * DH + d];
    }
    __syncthreads();
    // s-chunk: 32 x 64, per-thread 2x4
    float s[2][4] = {};
    #pragma unroll 8
    for (int d = 0; d < 64; d++) {
      float a0 = qs[r0][d], a1 = qs[r1][d];
      #pragma unroll
      for (int j = 0; j < 4; j++) {
        float bv = ks[tx * 4 + j][d];
        s[0][j] += a0 * bv;
        s[1][j] += a1 * bv;
      }
    }
    #pragma unroll
    for (int i = 0; i < 2; i++) {
      float mx = fmaxf(fmaxf(s[i][0], s[i][1]), fmaxf(s[i][2], s[i][3]));
      #pragma unroll
      for (int o = 1; o < 16; o <<= 1) mx = fmaxf(mx, __shfl_xor(mx, o));
      float mnew = fmaxf(mrow[i], mx);
      float alpha = __expf(mrow[i] - mnew);
      mrow[i] = mnew;
      float psum = 0.f;
      int rr = r0 + i;
      #pragma unroll
      for (int j = 0; j < 4; j++) {
        float e = __expf(s[i][j] - mnew);
        ps[rr][tx * 4 + j] = e;
        psum += e;
      }
      #pragma unroll
      for (int o = 1; o < 16; o <<= 1) psum += __shfl_xor(psum, o);
      lrow[i] = lrow[i] * alpha + psum;
      #pragma unroll
      for (int j = 0; j < 4; j++) O[i][j] *= alpha;
    }
    __syncthreads();
    // O += P(32x64) @ vs(64x64)
    #pragma unroll 8
    for (int kk = 0; kk < 64; kk++) {
      float a0 = ps[r0][kk], a1 = ps[r1][kk];
      #pragma unroll
      for (int j = 0; j < 4; j++) {
        float bv = vs[kk][tx * 4 + j];
        O[0][j] += a0 * bv;
        O[1][j] += a1 * bv;
      }
    }
  }
  #pragma unroll
  for (int i = 0; i < 2; i++) {
    float inv = 1.f / lrow[i];
    #pragma unroll
    for (int j = 0; j < 4; j++)
      kv[((size_t)bh * MM + l0 + r0 + i) * DH + tx * 4 + j] = O[i][j] * inv;
  }
}

// ------ fused a1-softmax @ kv2 + depthwise res-conv(33): 32 rows / block ----
__global__ __launch_bounds__(256) void attn1_kernel(
    const float* __restrict__ q, const float* __restrict__ kland,
    const float* __restrict__ kv2, const float* __restrict__ v,
    const float* __restrict__ resw, float* __restrict__ attn)
{
  __shared__ float qs[32][65];
  __shared__ float tile[64][65];   // reused: kland tiles, kv2 tiles, v window
  __shared__ float ps[32][257];
  __shared__ float invl[32];
  __shared__ float wsm[33];
  int bh = blockIdx.y;
  int b = bh >> 3, hh = bh & 7;
  int n0 = 255 + blockIdx.x * 32;
  int tid = threadIdx.x;
  int tx = tid & 15, ty = tid >> 4;
  int r0 = ty * 2, r1 = r0 + 1;
  const float* qb = q + (size_t)bh * NPAD * DH;
  const float* klb = kland + (size_t)bh * MM * DH;
  const float* kvb = kv2 + (size_t)bh * MM * DH;
  const float* vb = v + (size_t)bh * NPAD * DH;

  // stage q rows n0..n0+31 (clamped)
  for (int i = tid; i < 32 * 64; i += 256) {
    int row = i >> 6, d = i & 63;
    int g = n0 + row; if (g > NPAD - 1) g = NPAD - 1;
    qs[row][d] = qb[(size_t)g * DH + d];
  }
  if (tid < 33) wsm[tid] = resw[hh * 33 + tid];

  // s1 = q_tile @ kland^T  -> ps[32][256]
  for (int lt = 0; lt < 4; lt++) {
    __syncthreads();
    for (int i = tid; i < 64 * 64; i += 256)
      tile[i >> 6][i & 63] = klb[(size_t)(lt * 64 + (i >> 6)) * DH + (i & 63)];
    __syncthreads();
    float s[2][4] = {};
    #pragma unroll 8
    for (int d = 0; d < 64; d++) {
      float a0 = qs[r0][d], a1 = qs[r1][d];
      #pragma unroll
      for (int j = 0; j < 4; j++) {
        float bv = tile[tx * 4 + j][d];
        s[0][j] += a0 * bv;
        s[1][j] += a1 * bv;
      }
    }
    #pragma unroll
    for (int j = 0; j < 4; j++) {
      ps[r0][lt * 64 + tx * 4 + j] = s[0][j];
      ps[r1][lt * 64 + tx * 4 + j] = s[1][j];
    }
  }
  __syncthreads();

  // softmax per row: 8 threads per row
  {
    int row = tid >> 3, l8 = tid & 7;
    float mx = -3.0e38f;
    for (int c = l8; c < 256; c += 8) mx = fmaxf(mx, ps[row][c]);
    #pragma unroll
    for (int o = 1; o < 8; o <<= 1) mx = fmaxf(mx, __shfl_xor(mx, o));
    float sm = 0.f;
    for (int c = l8; c < 256; c += 8) {
      float e = __expf(ps[row][c] - mx);
      ps[row][c] = e;
      sm += e;
    }
    #pragma unroll
    for (int o = 1; o < 8; o <<= 1) sm += __shfl_xor(sm, o);
    if (l8 == 0) invl[row] = 1.f / sm;
  }

  // O = P(32x256) @ kv2(256x64)
  float O[2][4] = {};
  for (int jt = 0; jt < 4; jt++) {
    __syncthreads();
    for (int i = tid; i < 64 * 64; i += 256)
      tile[i >> 6][i & 63] = kvb[(size_t)(jt * 64 + (i >> 6)) * DH + (i & 63)];
    __syncthreads();
    #pragma unroll 8
    for (int kk = 0; kk < 64; kk++) {
      float a0 = ps[r0][jt * 64 + kk], a1 = ps[r1][jt * 64 + kk];
      #pragma unroll
      for (int j = 0; j < 4; j++) {
        float bv = tile[kk][tx * 4 + j];
        O[0][j] += a0 * bv;
        O[1][j] += a1 * bv;
      }
    }
  }

  // stage v window rows n0-16 .. n0+47 into tile, then conv + write
  __syncthreads();
  for (int i = tid; i < 64 * 64; i += 256) {
    int lr = i >> 6, d = i & 63;
    int g = n0 - 16 + lr;
    tile[lr][d] = (g <= NPAD - 1) ? vb[(size_t)g * DH + d] : 0.f;
  }
  __syncthreads();
  #pragma unroll
  for (int i = 0; i < 2; i++) {
    int r = r0 + i;
    int n = n0 + r;
    if (n > NPAD - 1) continue;
    float il = invl[r];
    #pragma unroll
    for (int j = 0; j < 4; j++) {
      int c = tx * 4 + j;
      float cacc = 0.f;
      #pragma unroll 11
      for (int t = 0; t < 33; t++) cacc += tile[r + t][c] * wsm[t];
      attn[((size_t)b * NTOK + (n - 255)) * EMBED + hh * DH + c] = O[i][j] * il + cacc;
    }
  }
}

// combine 7x7 + 5x5 + 3x3 + identity into one 7x7 depthwise kernel
__global__ void prep_wcomb_kernel(
    const float* __restrict__ pw7, const float* __restrict__ pw5,
    const float* __restrict__ pw3, const float* __restrict__ pb7,
    const float* __restrict__ pb5, const float* __restrict__ pb3,
    float* __restrict__ wcomb, float* __restrict__ biasc)
{
  int i = blockIdx.x * blockDim.x + threadIdx.x;
  if (i < EMBED * 49) {
    int c = i / 49, tap = i % 49;
    int ky = tap / 7, kx = tap % 7;
    float v = pw7[c * 49 + tap];
    if (ky >= 1 && ky <= 5 && kx >= 1 && kx <= 5) v += pw5[c * 25 + (ky - 1) * 5 + (kx - 1)];
    if (ky >= 2 && ky <= 4 && kx >= 2 && kx <= 4) v += pw3[c * 9 + (ky - 2) * 3 + (kx - 2)];
    if (ky == 3 && kx == 3) v += 1.f;
    wcomb[tap * EMBED + c] = v;
  }
  if (i < EMBED) biasc[i] = pb7[i] + pb5[i] + pb3[i];
}

__global__ void copy_feat_kernel(const float* __restrict__ h, float* __restrict__ tmp) {
  size_t t = (size_t)blockIdx.x * blockDim.x + threadIdx.x;
  if (t >= (size_t)BATCH * N0 * EMBED) return;
  size_t per = (size_t)N0 * EMBED;
  size_t b = t / per, r = t % per;
  tmp[t] = h[((size_t)b * NTOK + 1) * EMBED + r];
}

__global__ __launch_bounds__(256) void dwconv_kernel(
    const float* __restrict__ tmp, const float* __restrict__ wcomb,
    const float* __restrict__ biasc, float* __restrict__ h)
{
  __shared__ float wsm[49][64];
  int cb = blockIdx.x * 64;
  int c = cb + threadIdx.x;
  int b = blockIdx.z;
  int n = blockIdx.y * 4 + threadIdx.y;
  int y = n >> 6, x = n & 63;
  int tid = threadIdx.y * 64 + threadIdx.x;
  for (int i = tid; i < 49 * 64; i += 256) {
    int tap = i >> 6, cc = i & 63;
    wsm[tap][cc] = wcomb[tap * EMBED + cb + cc];
  }
  __syncthreads();
  const float* src = tmp + (size_t)b * N0 * EMBED;
  float acc = biasc[c];
  #pragma unroll
  for (int ky = 0; ky < 7; ky++) {
    int yy = y + ky - 3;
    if (yy < 0 || yy >= 64) continue;
    #pragma unroll
    for (int kx = 0; kx < 7; kx++) {
      int xx = x + kx - 3;
      if (xx < 0 || xx >= 64) continue;
      acc += src[((size_t)yy * 64 + xx) * EMBED + c] * wsm[ky * 7 + kx][threadIdx.x];
    }
  }
  h[((size_t)b * NTOK + 1 + n) * EMBED + c] = acc;
}

__global__ __launch_bounds__(256) void final_kernel(
    const float* __restrict__ h, const float* __restrict__ g,
    const float* __restrict__ be, const float* __restrict__ W2,
    const float* __restrict__ b2, float* __restrict__ out)
{
  __shared__ float red[4];
  int b = blockIdx.x, tid = threadIdx.x;
  const float* x = h + (size_t)b * NTOK * EMBED;
  float v0 = x[tid], v1 = x[tid + 256];
  float mu = block_sum(v0 + v1, red) * (1.f / 512.f);
  float d0 = v0 - mu, d1 = v1 - mu;
  float var = block_sum(d0 * d0 + d1 * d1, red) * (1.f / 512.f);
  float inv = 1.f / sqrtf(var + 1e-5f);
  float xn0 = d0 * inv * g[tid] + be[tid];
  float xn1 = d1 * inv * g[tid + 256] + be[tid + 256];
  float l0 = block_sum(xn0 * W2[tid] + xn1 * W2[tid + 256], red);
  float l1 = block_sum(xn0 * W2[512 + tid] + xn1 * W2[512 + tid + 256], red);
  if (tid == 0) {
    l0 += b2[0]; l1 += b2[1];
    out[b * 2 + 0] = l0;
    out[b * 2 + 1] = l1;
    float mx = fmaxf(l0, l1);
    float e0 = expf(l0 - mx), e1 = expf(l1 - mx);
    float s = e0 + e1;
    out[8 + b * 2 + 0] = e0 / s;
    out[8 + b * 2 + 1] = e1 / s;
    out[16 + b] = (l1 > l0) ? 1.f : 0.f;
  }
}

// ------------------------------- host side -----------------------------------
extern "C" void kernel_launch(void* const* d_in, const int* in_sizes, int n_in,
                              void* d_out, int out_size, void* d_ws, size_t ws_size,
                              hipStream_t stream)
{
  const float* data = (const float*)d_in[0];
  const float* W1   = (const float*)d_in[1];
  const float* b1   = (const float*)d_in[2];
  const float* cls  = (const float*)d_in[3];
  const float* lng[2]  = {(const float*)d_in[4],  (const float*)d_in[10]};
  const float* lnb[2]  = {(const float*)d_in[5],  (const float*)d_in[11]};
  const float* Wqkv[2] = {(const float*)d_in[6],  (const float*)d_in[12]};
  const float* Wo[2]   = {(const float*)d_in[7],  (const float*)d_in[13]};
  const float* bo[2]   = {(const float*)d_in[8],  (const float*)d_in[14]};
  const float* resw[2] = {(const float*)d_in[9],  (const float*)d_in[15]};
  const float* pw7 = (const float*)d_in[16];
  const float* pb7 = (const float*)d_in[17];
  const float* pw5 = (const float*)d_in[18];
  const float* pb5 = (const float*)d_in[19];
  const float* pw3 = (const float*)d_in[20];
  const float* pb3 = (const float*)d_in[21];
  const float* lnfg = (const float*)d_in[22];
  const float* lnfb = (const float*)d_in[23];
  const float* W2  = (const float*)d_in[24];
  const float* b2  = (const float*)d_in[25];

  float* ws = (float*)d_ws;
  size_t off = 0;
  auto alloc = [&](size_t n) { float* p = ws + off; off += n; return p; };
  float* hbuf  = alloc((size_t)BATCH * NTOK * EMBED);
  float* xpad  = alloc((size_t)BATCH * NPAD * EMBED);   // also reused as attn_out
  float* qbuf  = alloc((size_t)BH * NPAD * DH);         // also reused as conv tmp
  float* kbuf  = alloc((size_t)BH * NPAD * DH);
  float* vbuf  = alloc((size_t)BH * NPAD * DH);
  float* qland = alloc((size_t)BH * MM * DH);
  float* kland = alloc((size_t)BH * MM * DH);
  float* a2    = alloc((size_t)BH * MM * MM);
  float* za    = alloc((size_t)BH * MM * MM);
  float* zb    = alloc((size_t)BH * MM * MM);
  float* xzb   = alloc((size_t)BH * MM * MM);
  float* t1b   = alloc((size_t)BH * MM * MM);
  float* t2b   = alloc((size_t)BH * MM * MM);
  float* kvb   = alloc((size_t)BH * MM * DH);
  float* kv2b  = alloc((size_t)BH * MM * DH);
  float* wcomb = alloc(49 * EMBED);
  float* biasc = alloc(EMBED);
  float* denoms = alloc(64);
  float* attn = xpad;

  gemm_abt<<<dim3(EMBED / 64, (BATCH * N0) / 64), 256, 0, stream>>>(
      data, W1, BATCH * N0, EMBED, CIN, b1, hbuf, nullptr, nullptr, 0);
  cls_kernel<<<dim3((BATCH * EMBED + 255) / 256), 256, 0, stream>>>(cls, hbuf);

  for (int layer = 0; layer < 2; layer++) {
    ln_pad_kernel<<<dim3(BATCH * NTOK), 256, 0, stream>>>(hbuf, lng[layer], lnb[layer], xpad);
    zero_pad_kernel<<<dim3((BATCH * 255 * EMBED + 255) / 256), 256, 0, stream>>>(xpad);
    gemm_abt<<<dim3((3 * EMBED) / 64, (BATCH * NPAD) / 64), 256, 0, stream>>>(
        xpad, Wqkv[layer], BATCH * NPAD, 3 * EMBED, EMBED, nullptr, qbuf, kbuf, vbuf, 1);
    landmarks_kernel<<<dim3(MM / 4, BH), 256, 0, stream>>>(qbuf, kbuf, qland, kland);
    s2_softmax_kernel<<<dim3(MM, BH), 256, 0, stream>>>(qland, kland, a2);
    init_denom_kernel<<<1, 64, 0, stream>>>(denoms);
    denom_kernel<<<dim3(BH), 256, 0, stream>>>(a2, denoms);
    z0_kernel<<<dim3(MM / 64, MM / 4, BH), dim3(64, 4), 0, stream>>>(a2, denoms, za);
    float* zin = za;
    float* zout = zb;
    for (int it = 0; it < 6; it++) {
      gemm_nn_batched<<<dim3(4, 4, BH), 256, 0, stream>>>(a2, zin, xzb, MM, MM, MM, 0.f, 1.f, 1.f);
      gemm_nn_batched<<<dim3(4, 4, BH), 256, 0, stream>>>(xzb, xzb, t1b, MM, MM, MM, 7.f, -1.f, 1.f);
      gemm_nn_batched<<<dim3(4, 4, BH), 256, 0, stream>>>(xzb, t1b, t2b, MM, MM, MM, 15.f, -1.f, 1.f);
      gemm_nn_batched<<<dim3(4, 4, BH), 256, 0, stream>>>(zin, t2b, zout, MM, MM, MM, 13.f, -1.f, 0.25f);
      float* t = zin; zin = zout; zout = t;
    }
    a3v_flash_kernel<<<dim3(MM / 32, BH), 256, 0, stream>>>(qland, kbuf, vbuf, kvb);
    gemm_nn_batched<<<dim3(1, 4, BH), 256, 0, stream>>>(zin, kvb, kv2b, MM, DH, MM, 0.f, 1.f, 1.f);
    attn1_kernel<<<dim3((NTOK + 31) / 32, BH), 256, 0, stream>>>(
        qbuf, kland, kv2b, vbuf, resw[layer], attn);
    gemm_abt<<<dim3(EMBED / 64, (BATCH * NTOK + 63) / 64), 256, 0, stream>>>(
        attn, Wo[layer], BATCH * NTOK, EMBED, EMBED, bo[layer], hbuf, nullptr, nullptr, 2);

    if (layer == 0) {
      prep_wcomb_kernel<<<dim3((EMBED * 49 + 255) / 256), 256, 0, stream>>>(
          pw7, pw5, pw3, pb7, pb5, pb3, wcomb, biasc);
      copy_feat_kernel<<<dim3((unsigned)(((size_t)BATCH * N0 * EMBED + 255) / 256)), 256, 0, stream>>>(hbuf, qbuf);
      dwconv_kernel<<<dim3(EMBED / 64, N0 / 4, BATCH), dim3(64, 4), 0, stream>>>(qbuf, wcomb, biasc, hbuf);
    }
  }

  final_kernel<<<dim3(BATCH), 256, 0, stream>>>(hbuf, lnfg, lnfb, W2, b2, (float*)d_out);
}

// Round 3
// 4473.385 us; speedup vs baseline: 2.7789x; 1.4408x over previous
//
#include <hip/hip_runtime.h>
#include <math.h>

#define EMBED 512
#define HEADS 8
#define DH 64
#define MM 256
#define LSEG 17
#define NPAD 4352
#define NTOK 4097
#define N0 4096
#define BATCH 4
#define CIN 1536
#define QSCALE 0.125f
#define BH 32   // BATCH*HEADS
#define NSEG 17 // key segments of 256 for a3v

typedef float fp32x4 __attribute__((ext_vector_type(4)));
typedef short bf16x8 __attribute__((ext_vector_type(8)));

__device__ __forceinline__ unsigned short f2bf(float f) {
  unsigned int u = __float_as_uint(f);
  u += 0x7fffu + ((u >> 16) & 1u);
  return (unsigned short)(u >> 16);
}

// ---------------- block reduction helpers (blockDim.x == 256) ----------------
__device__ __forceinline__ float block_sum(float v, float* red) {
  #pragma unroll
  for (int o = 1; o < 64; o <<= 1) v += __shfl_xor(v, o);
  int lane = threadIdx.x & 63, wid = threadIdx.x >> 6;
  if (lane == 0) red[wid] = v;
  __syncthreads();
  float r = red[0] + red[1] + red[2] + red[3];
  __syncthreads();
  return r;
}
__device__ __forceinline__ float block_max(float v, float* red) {
  #pragma unroll
  for (int o = 1; o < 64; o <<= 1) v = fmaxf(v, __shfl_xor(v, o));
  int lane = threadIdx.x & 63, wid = threadIdx.x >> 6;
  if (lane == 0) red[wid] = v;
  __syncthreads();
  float r = fmaxf(fmaxf(red[0], red[1]), fmaxf(red[2], red[3]));
  __syncthreads();
  return r;
}

// ------------- bf16-MFMA tiled GEMM  C = A(M,K) @ W(N,K)^T  ------------------
// fp32 in (converted to bf16 in staging), fp32 accumulate via MFMA.
// mode 0: v=relu(acc+bias); h[(b*NTOK+1+n)*EMBED+col] = v   (row = b*N0+n)
// mode 1: qkv scatter: sec=col/512 -> q/k/v[((b*H+hh)*NPAD+n)*DH+d], q *= QSCALE
// mode 2: out0[row*EMBED+col] += acc + bias[col]
__global__ __launch_bounds__(256) void gemm_abt(
    const float* __restrict__ A, const float* __restrict__ W,
    int Mrows, int Ncols, int K, const float* __restrict__ bias,
    float* __restrict__ out0, float* __restrict__ out1, float* __restrict__ out2,
    int mode)
{
  // stride 40 shorts (80 B = 5x16B): b128 frag reads land 2-way on banks (free)
  __shared__ unsigned short As[64][40];
  __shared__ unsigned short Ws[64][40];
  int tid = threadIdx.x;
  int lane = tid & 63;
  int wv = tid >> 6;            // wave id 0..3 -> M strip
  int rowBase = blockIdx.y * 64, colBase = blockIdx.x * 64;
  int quad = lane >> 4;         // 0..3
  int l15 = lane & 15;

  int sr = tid >> 2;            // staging row 0..63
  int skc = (tid & 3) * 8;      // staging k offset 0,8,16,24

  fp32x4 acc[4] = {fp32x4{0,0,0,0}, fp32x4{0,0,0,0}, fp32x4{0,0,0,0}, fp32x4{0,0,0,0}};

  for (int kb = 0; kb < K; kb += 32) {
    __syncthreads();
    // stage A tile (64 x 32) -> bf16
    {
      int grow = rowBase + sr;
      float va[8];
      if (grow < Mrows) {
        const float4* p = (const float4*)&A[(size_t)grow * K + kb + skc];
        float4 v0 = p[0], v1 = p[1];
        va[0]=v0.x; va[1]=v0.y; va[2]=v0.z; va[3]=v0.w;
        va[4]=v1.x; va[5]=v1.y; va[6]=v1.z; va[7]=v1.w;
      } else {
        #pragma unroll
        for (int j = 0; j < 8; j++) va[j] = 0.f;
      }
      bf16x8 pk;
      #pragma unroll
      for (int j = 0; j < 8; j++) pk[j] = (short)f2bf(va[j]);
      *(bf16x8*)&As[sr][skc] = pk;
    }
    // stage W tile (64 x 32) -> bf16  (Ncols always multiple of 64)
    {
      int gcol = colBase + sr;
      const float4* p = (const float4*)&W[(size_t)gcol * K + kb + skc];
      float4 v0 = p[0], v1 = p[1];
      float vb[8] = {v0.x, v0.y, v0.z, v0.w, v1.x, v1.y, v1.z, v1.w};
      bf16x8 pk;
      #pragma unroll
      for (int j = 0; j < 8; j++) pk[j] = (short)f2bf(vb[j]);
      *(bf16x8*)&Ws[sr][skc] = pk;
    }
    __syncthreads();
    bf16x8 aF = *(const bf16x8*)&As[wv * 16 + l15][quad * 8];
    #pragma unroll
    for (int ns = 0; ns < 4; ns++) {
      bf16x8 bF = *(const bf16x8*)&Ws[ns * 16 + l15][quad * 8];
      acc[ns] = __builtin_amdgcn_mfma_f32_16x16x32_bf16(aF, bF, acc[ns], 0, 0, 0);
    }
  }

  // epilogue: C/D layout col=lane&15, row=quad*4+reg
  #pragma unroll
  for (int ns = 0; ns < 4; ns++) {
    int col = colBase + ns * 16 + l15;
    #pragma unroll
    for (int i = 0; i < 4; i++) {
      int row = rowBase + wv * 16 + quad * 4 + i;
      if (row >= Mrows) continue;
      float v = acc[ns][i];
      if (mode == 0) {
        v += bias[col];
        v = fmaxf(v, 0.f);
        int b = row / N0, n = row % N0;
        out0[((size_t)b * NTOK + 1 + n) * EMBED + col] = v;
      } else if (mode == 1) {
        int b = row / NPAD, n = row % NPAD;
        int sec = col / EMBED;
        int hh = (col % EMBED) / DH;
        int d = col & 63;
        float* dst = (sec == 0) ? out0 : ((sec == 1) ? out1 : out2);
        if (sec == 0) v *= QSCALE;
        dst[(((size_t)b * HEADS + hh) * NPAD + n) * DH + d] = v;
      } else {
        v += bias[col];
        out0[(size_t)row * EMBED + col] += v;
      }
    }
  }
}

// ------------- batched NN GEMM:  C = gamma * A @ (beta*I + sgn*B) ------------
__global__ __launch_bounds__(256) void gemm_nn_batched(
    const float* __restrict__ A, const float* __restrict__ B, float* __restrict__ C,
    int Msize, int Nsize, int K, float beta_diag, float sgn, float gamma)
{
  __shared__ float As[16][68];
  __shared__ float Bs[16][68];
  int batch = blockIdx.z;
  const float* Ab = A + (size_t)batch * Msize * K;
  const float* Bb = B + (size_t)batch * K * Nsize;
  float* Cb = C + (size_t)batch * Msize * Nsize;
  int tid = threadIdx.x;
  int tx = tid & 15, ty = tid >> 4;
  int rowBase = blockIdx.y * 64, colBase = blockIdx.x * 64;
  int lkA = tid & 15, lrA = tid >> 4;
  int lcB = tid & 63, lkB = tid >> 6;
  float acc[4][4] = {};
  for (int kb = 0; kb < K; kb += 16) {
    #pragma unroll
    for (int p = 0; p < 4; p++) {
      int r = lrA + p * 16;
      As[lkA][r] = Ab[(size_t)(rowBase + r) * K + kb + lkA];
    }
    #pragma unroll
    for (int p = 0; p < 4; p++) {
      int kk = lkB + p * 4;
      int gc = colBase + lcB;
      float v = (gc < Nsize) ? Bb[(size_t)(kb + kk) * Nsize + gc] : 0.f;
      v = sgn * v + ((kb + kk) == gc ? beta_diag : 0.f);
      Bs[kk][lcB] = v;
    }
    __syncthreads();
    #pragma unroll
    for (int kk = 0; kk < 16; kk++) {
      float a0[4], b0[4];
      #pragma unroll
      for (int i = 0; i < 4; i++) a0[i] = As[kk][ty * 4 + i];
      #pragma unroll
      for (int j = 0; j < 4; j++) b0[j] = Bs[kk][tx * 4 + j];
      #pragma unroll
      for (int i = 0; i < 4; i++)
        #pragma unroll
        for (int j = 0; j < 4; j++) acc[i][j] += a0[i] * b0[j];
    }
    __syncthreads();
  }
  #pragma unroll
  for (int i = 0; i < 4; i++) {
    int row = rowBase + ty * 4 + i;
    #pragma unroll
    for (int j = 0; j < 4; j++) {
      int col = colBase + tx * 4 + j;
      if (col < Nsize) Cb[(size_t)row * Nsize + col] = gamma * acc[i][j];
    }
  }
}

// ---------------- small utility kernels ----------------
__global__ void cls_kernel(const float* __restrict__ cls, float* __restrict__ h) {
  int t = blockIdx.x * blockDim.x + threadIdx.x;
  if (t >= BATCH * EMBED) return;
  int b = t / EMBED, c = t % EMBED;
  h[(size_t)b * NTOK * EMBED + c] = cls[c];
}

__global__ void zero_pad_kernel(float* __restrict__ xpad) {
  int t = blockIdx.x * blockDim.x + threadIdx.x;
  const int per = 255 * EMBED;
  if (t >= BATCH * per) return;
  int b = t / per, r = t % per;
  xpad[(size_t)b * NPAD * EMBED + r] = 0.f;
}

__global__ __launch_bounds__(256) void ln_pad_kernel(
    const float* __restrict__ h, const float* __restrict__ g,
    const float* __restrict__ be, float* __restrict__ xpad)
{
  __shared__ float red[4];
  int row = blockIdx.x;
  int b = row / NTOK, j = row % NTOK;
  const float* x = h + (size_t)row * EMBED;
  int tid = threadIdx.x;
  float v0 = x[tid], v1 = x[tid + 256];
  float mu = block_sum(v0 + v1, red) * (1.f / 512.f);
  float d0 = v0 - mu, d1 = v1 - mu;
  float var = block_sum(d0 * d0 + d1 * d1, red) * (1.f / 512.f);
  float inv = 1.f / sqrtf(var + 1e-5f);
  float* o = xpad + ((size_t)b * NPAD + 255 + j) * EMBED;
  o[tid]       = d0 * inv * g[tid]       + be[tid];
  o[tid + 256] = d1 * inv * g[tid + 256] + be[tid + 256];
}

__global__ __launch_bounds__(256) void landmarks_kernel(
    const float* __restrict__ q, const float* __restrict__ k,
    float* __restrict__ qland, float* __restrict__ kland)
{
  int bh = blockIdx.y;
  int m = blockIdx.x * 4 + (threadIdx.x >> 6);
  int d = threadIdx.x & 63;
  const float* qb = q + (size_t)bh * NPAD * DH;
  const float* kb = k + (size_t)bh * NPAD * DH;
  float sq = 0.f, sk = 0.f;
  int base = m * LSEG;
  #pragma unroll
  for (int t = 0; t < LSEG; t++) {
    sq += qb[(size_t)(base + t) * DH + d];
    sk += kb[(size_t)(base + t) * DH + d];
  }
  qland[((size_t)bh * MM + m) * DH + d] = sq * (1.f / LSEG);
  kland[((size_t)bh * MM + m) * DH + d] = sk * (1.f / LSEG);
}

__global__ __launch_bounds__(256) void s2_softmax_kernel(
    const float* __restrict__ qland, const float* __restrict__ kland,
    float* __restrict__ a2)
{
  __shared__ float qrow[64];
  __shared__ float red[4];
  int bh = blockIdx.y, m = blockIdx.x, tid = threadIdx.x;
  if (tid < 64) qrow[tid] = qland[((size_t)bh * MM + m) * DH + tid];
  __syncthreads();
  const float* kb = kland + (size_t)bh * MM * DH + (size_t)tid * DH;
  float s = 0.f;
  #pragma unroll 16
  for (int d = 0; d < 64; d++) s += qrow[d] * kb[d];
  float mx = block_max(s, red);
  float e = __expf(s - mx);
  float tot = block_sum(e, red);
  a2[((size_t)bh * MM + m) * MM + tid] = e / tot;
}

__global__ void init_denom_kernel(float* __restrict__ denoms) {
  if (threadIdx.x < 2) denoms[threadIdx.x] = 0.f;
}

__global__ __launch_bounds__(256) void denom_kernel(
    const float* __restrict__ a2, float* __restrict__ denoms)
{
  __shared__ float red[4];
  int bh = blockIdx.x, tid = threadIdx.x;
  const float* A = a2 + (size_t)bh * MM * MM;
  float rs = 0.f, cs = 0.f;
  for (int j = 0; j < MM; j++) rs += A[(size_t)tid * MM + j];
  for (int i = 0; i < MM; i++) cs += A[(size_t)i * MM + tid];
  float mr = block_max(rs, red);
  float mc = block_max(cs, red);
  if (tid == 0) {
    atomicMax((int*)&denoms[0], __float_as_int(mr));
    atomicMax((int*)&denoms[1], __float_as_int(mc));
  }
}

__global__ void z0_kernel(const float* __restrict__ a2,
                          const float* __restrict__ denoms, float* __restrict__ z)
{
  int bh = blockIdx.z;
  int i = blockIdx.y * 4 + threadIdx.y;
  int j = blockIdx.x * 64 + threadIdx.x;
  float denom = denoms[0] * denoms[1];
  z[((size_t)bh * MM + i) * MM + j] = a2[((size_t)bh * MM + j) * MM + i] / denom;
}

// ---------- a3@v partial flash: block = 32 landmarks x 256-key segment -------
// writes unnormalized partial O + per-row partial (m, l); merged exactly later.
__global__ __launch_bounds__(256) void a3v_part_kernel(
    const float* __restrict__ qland, const float* __restrict__ k,
    const float* __restrict__ v, float* __restrict__ Opart,
    float* __restrict__ mpart, float* __restrict__ lpart)
{
  __shared__ float qs[32][65];
  __shared__ float ks[64][65];
  __shared__ float vs[64][65];
  __shared__ float ps[32][65];
  int bh = blockIdx.y;
  int ltile = blockIdx.x & 7;
  int seg = blockIdx.x >> 3;
  int l0 = ltile * 32;
  int key0 = seg * 256;
  int tid = threadIdx.x;
  int tx = tid & 15, ty = tid >> 4;
  int r0 = ty * 2, r1 = r0 + 1;
  const float* kb = k + (size_t)bh * NPAD * DH;
  const float* vb = v + (size_t)bh * NPAD * DH;

  for (int i = tid; i < 32 * 64; i += 256)
    qs[i >> 6][i & 63] = qland[((size_t)bh * MM + l0 + (i >> 6)) * DH + (i & 63)];

  float O[2][4] = {};
  float mrow[2] = {-3.0e38f, -3.0e38f};
  float lrow[2] = {0.f, 0.f};

  for (int nt = 0; nt < 4; nt++) {
    __syncthreads();
    for (int i = tid; i < 64 * 64; i += 256) {
      int lr = i >> 6, d = i & 63;
      ks[lr][d] = kb[(size_t)(key0 + nt * 64 + lr) * DH + d];
      vs[lr][d] = vb[(size_t)(key0 + nt * 64 + lr) * DH + d];
    }
    __syncthreads();
    float s[2][4] = {};
    #pragma unroll 8
    for (int d = 0; d < 64; d++) {
      float a0 = qs[r0][d], a1 = qs[r1][d];
      #pragma unroll
      for (int j = 0; j < 4; j++) {
        float bv = ks[tx * 4 + j][d];
        s[0][j] += a0 * bv;
        s[1][j] += a1 * bv;
      }
    }
    #pragma unroll
    for (int i = 0; i < 2; i++) {
      float mx = fmaxf(fmaxf(s[i][0], s[i][1]), fmaxf(s[i][2], s[i][3]));
      #pragma unroll
      for (int o = 1; o < 16; o <<= 1) mx = fmaxf(mx, __shfl_xor(mx, o));
      float mnew = fmaxf(mrow[i], mx);
      float alpha = __expf(mrow[i] - mnew);
      mrow[i] = mnew;
      float psum = 0.f;
      int rr = r0 + i;
      #pragma unroll
      for (int j = 0; j < 4; j++) {
        float e = __expf(s[i][j] - mnew);
        ps[rr][tx * 4 + j] = e;
        psum += e;
      }
      #pragma unroll
      for (int o = 1; o < 16; o <<= 1) psum += __shfl_xor(psum, o);
      lrow[i] = lrow[i] * alpha + psum;
      #pragma unroll
      for (int j = 0; j < 4; j++) O[i][j] *= alpha;
    }
    __syncthreads();
    #pragma unroll 8
    for (int kk = 0; kk < 64; kk++) {
      float a0 = ps[r0][kk], a1 = ps[r1][kk];
      #pragma unroll
      for (int j = 0; j < 4; j++) {
        float bv = vs[kk][tx * 4 + j];
        O[0][j] += a0 * bv;
        O[1][j] += a1 * bv;
      }
    }
  }
  size_t base = ((size_t)seg * BH + bh) * MM + l0;
  #pragma unroll
  for (int i = 0; i < 2; i++) {
    int rr = r0 + i;
    #pragma unroll
    for (int j = 0; j < 4; j++)
      Opart[(base + rr) * DH + tx * 4 + j] = O[i][j];
    if (tx == 0) {
      mpart[base + rr] = mrow[i];
      lpart[base + rr] = lrow[i];
    }
  }
}

// merge 17 segment partials exactly -> kv
__global__ __launch_bounds__(256) void a3v_merge_kernel(
    const float* __restrict__ Opart, const float* __restrict__ mpart,
    const float* __restrict__ lpart, float* __restrict__ kv)
{
  int bh = blockIdx.y;
  int lbase = blockIdx.x * 64;
  int d = threadIdx.x & 63, lsub = threadIdx.x >> 6;
  for (int li = lsub; li < 64; li += 4) {
    int lm = lbase + li;
    float M = -3.0e38f;
    #pragma unroll
    for (int s = 0; s < NSEG; s++)
      M = fmaxf(M, mpart[((size_t)s * BH + bh) * MM + lm]);
    float L = 0.f, O = 0.f;
    #pragma unroll
    for (int s = 0; s < NSEG; s++) {
      size_t idx = ((size_t)s * BH + bh) * MM + lm;
      float w = __expf(mpart[idx] - M);
      L += lpart[idx] * w;
      O += Opart[idx * DH + d] * w;
    }
    kv[((size_t)bh * MM + lm) * DH + d] = O / L;
  }
}

// ------ fused a1-softmax @ kv2 + depthwise res-conv(33): 32 rows / block ----
__global__ __launch_bounds__(256) void attn1_kernel(
    const float* __restrict__ q, const float* __restrict__ kland,
    const float* __restrict__ kv2, const float* __restrict__ v,
    const float* __restrict__ resw, float* __restrict__ attn)
{
  __shared__ float qs[32][65];
  __shared__ float tile[64][65];   // reused: kland tiles, kv2 tiles, v window
  __shared__ float ps[32][257];
  __shared__ float invl[32];
  __shared__ float wsm[33];
  int bh = blockIdx.y;
  int b = bh >> 3, hh = bh & 7;
  int n0 = 255 + blockIdx.x * 32;
  int tid = threadIdx.x;
  int tx = tid & 15, ty = tid >> 4;
  int r0 = ty * 2, r1 = r0 + 1;
  const float* qb = q + (size_t)bh * NPAD * DH;
  const float* klb = kland + (size_t)bh * MM * DH;
  const float* kvb = kv2 + (size_t)bh * MM * DH;
  const float* vb = v + (size_t)bh * NPAD * DH;

  for (int i = tid; i < 32 * 64; i += 256) {
    int row = i >> 6, d = i & 63;
    int g = n0 + row; if (g > NPAD - 1) g = NPAD - 1;
    qs[row][d] = qb[(size_t)g * DH + d];
  }
  if (tid < 33) wsm[tid] = resw[hh * 33 + tid];

  for (int lt = 0; lt < 4; lt++) {
    __syncthreads();
    for (int i = tid; i < 64 * 64; i += 256)
      tile[i >> 6][i & 63] = klb[(size_t)(lt * 64 + (i >> 6)) * DH + (i & 63)];
    __syncthreads();
    float s[2][4] = {};
    #pragma unroll 8
    for (int d = 0; d < 64; d++) {
      float a0 = qs[r0][d], a1 = qs[r1][d];
      #pragma unroll
      for (int j = 0; j < 4; j++) {
        float bv = tile[tx * 4 + j][d];
        s[0][j] += a0 * bv;
        s[1][j] += a1 * bv;
      }
    }
    #pragma unroll
    for (int j = 0; j < 4; j++) {
      ps[r0][lt * 64 + tx * 4 + j] = s[0][j];
      ps[r1][lt * 64 + tx * 4 + j] = s[1][j];
    }
  }
  __syncthreads();

  {
    int row = tid >> 3, l8 = tid & 7;
    float mx = -3.0e38f;
    for (int c = l8; c < 256; c += 8) mx = fmaxf(mx, ps[row][c]);
    #pragma unroll
    for (int o = 1; o < 8; o <<= 1) mx = fmaxf(mx, __shfl_xor(mx, o));
    float sm = 0.f;
    for (int c = l8; c < 256; c += 8) {
      float e = __expf(ps[row][c] - mx);
      ps[row][c] = e;
      sm += e;
    }
    #pragma unroll
    for (int o = 1; o < 8; o <<= 1) sm += __shfl_xor(sm, o);
    if (l8 == 0) invl[row] = 1.f / sm;
  }

  float O[2][4] = {};
  for (int jt = 0; jt < 4; jt++) {
    __syncthreads();
    for (int i = tid; i < 64 * 64; i += 256)
      tile[i >> 6][i & 63] = kvb[(size_t)(jt * 64 + (i >> 6)) * DH + (i & 63)];
    __syncthreads();
    #pragma unroll 8
    for (int kk = 0; kk < 64; kk++) {
      float a0 = ps[r0][jt * 64 + kk], a1 = ps[r1][jt * 64 + kk];
      #pragma unroll
      for (int j = 0; j < 4; j++) {
        float bv = tile[kk][tx * 4 + j];
        O[0][j] += a0 * bv;
        O[1][j] += a1 * bv;
      }
    }
  }

  __syncthreads();
  for (int i = tid; i < 64 * 64; i += 256) {
    int lr = i >> 6, d = i & 63;
    int g = n0 - 16 + lr;
    tile[lr][d] = (g <= NPAD - 1) ? vb[(size_t)g * DH + d] : 0.f;
  }
  __syncthreads();
  #pragma unroll
  for (int i = 0; i < 2; i++) {
    int r = r0 + i;
    int n = n0 + r;
    if (n > NPAD - 1) continue;
    float il = invl[r];
    #pragma unroll
    for (int j = 0; j < 4; j++) {
      int c = tx * 4 + j;
      float cacc = 0.f;
      #pragma unroll 11
      for (int t = 0; t < 33; t++) cacc += tile[r + t][c] * wsm[t];
      attn[((size_t)b * NTOK + (n - 255)) * EMBED + hh * DH + c] = O[i][j] * il + cacc;
    }
  }
}

// combine 7x7 + 5x5 + 3x3 + identity into one 7x7 depthwise kernel
__global__ void prep_wcomb_kernel(
    const float* __restrict__ pw7, const float* __restrict__ pw5,
    const float* __restrict__ pw3, const float* __restrict__ pb7,
    const float* __restrict__ pb5, const float* __restrict__ pb3,
    float* __restrict__ wcomb, float* __restrict__ biasc)
{
  int i = blockIdx.x * blockDim.x + threadIdx.x;
  if (i < EMBED * 49) {
    int c = i / 49, tap = i % 49;
    int ky = tap / 7, kx = tap % 7;
    float v = pw7[c * 49 + tap];
    if (ky >= 1 && ky <= 5 && kx >= 1 && kx <= 5) v += pw5[c * 25 + (ky - 1) * 5 + (kx - 1)];
    if (ky >= 2 && ky <= 4 && kx >= 2 && kx <= 4) v += pw3[c * 9 + (ky - 2) * 3 + (kx - 2)];
    if (ky == 3 && kx == 3) v += 1.f;
    wcomb[tap * EMBED + c] = v;
  }
  if (i < EMBED) biasc[i] = pb7[i] + pb5[i] + pb3[i];
}

__global__ void copy_feat_kernel(const float* __restrict__ h, float* __restrict__ tmp) {
  size_t t = (size_t)blockIdx.x * blockDim.x + threadIdx.x;
  if (t >= (size_t)BATCH * N0 * EMBED) return;
  size_t per = (size_t)N0 * EMBED;
  size_t b = t / per, r = t % per;
  tmp[t] = h[((size_t)b * NTOK + 1) * EMBED + r];
}

__global__ __launch_bounds__(256) void dwconv_kernel(
    const float* __restrict__ tmp, const float* __restrict__ wcomb,
    const float* __restrict__ biasc, float* __restrict__ h)
{
  __shared__ float wsm[49][64];
  int cb = blockIdx.x * 64;
  int c = cb + threadIdx.x;
  int b = blockIdx.z;
  int n = blockIdx.y * 4 + threadIdx.y;
  int y = n >> 6, x = n & 63;
  int tid = threadIdx.y * 64 + threadIdx.x;
  for (int i = tid; i < 49 * 64; i += 256) {
    int tap = i >> 6, cc = i & 63;
    wsm[tap][cc] = wcomb[tap * EMBED + cb + cc];
  }
  __syncthreads();
  const float* src = tmp + (size_t)b * N0 * EMBED;
  float acc = biasc[c];
  #pragma unroll
  for (int ky = 0; ky < 7; ky++) {
    int yy = y + ky - 3;
    if (yy < 0 || yy >= 64) continue;
    #pragma unroll
    for (int kx = 0; kx < 7; kx++) {
      int xx = x + kx - 3;
      if (xx < 0 || xx >= 64) continue;
      acc += src[((size_t)yy * 64 + xx) * EMBED + c] * wsm[ky * 7 + kx][threadIdx.x];
    }
  }
  h[((size_t)b * NTOK + 1 + n) * EMBED + c] = acc;
}

__global__ __launch_bounds__(256) void final_kernel(
    const float* __restrict__ h, const float* __restrict__ g,
    const float* __restrict__ be, const float* __restrict__ W2,
    const float* __restrict__ b2, float* __restrict__ out)
{
  __shared__ float red[4];
  int b = blockIdx.x, tid = threadIdx.x;
  const float* x = h + (size_t)b * NTOK * EMBED;
  float v0 = x[tid], v1 = x[tid + 256];
  float mu = block_sum(v0 + v1, red) * (1.f / 512.f);
  float d0 = v0 - mu, d1 = v1 - mu;
  float var = block_sum(d0 * d0 + d1 * d1, red) * (1.f / 512.f);
  float inv = 1.f / sqrtf(var + 1e-5f);
  float xn0 = d0 * inv * g[tid] + be[tid];
  float xn1 = d1 * inv * g[tid + 256] + be[tid + 256];
  float l0 = block_sum(xn0 * W2[tid] + xn1 * W2[tid + 256], red);
  float l1 = block_sum(xn0 * W2[512 + tid] + xn1 * W2[512 + tid + 256], red);
  if (tid == 0) {
    l0 += b2[0]; l1 += b2[1];
    out[b * 2 + 0] = l0;
    out[b * 2 + 1] = l1;
    float mx = fmaxf(l0, l1);
    float e0 = expf(l0 - mx), e1 = expf(l1 - mx);
    float s = e0 + e1;
    out[8 + b * 2 + 0] = e0 / s;
    out[8 + b * 2 + 1] = e1 / s;
    out[16 + b] = (l1 > l0) ? 1.f : 0.f;
  }
}

// ------------------------------- host side -----------------------------------
extern "C" void kernel_launch(void* const* d_in, const int* in_sizes, int n_in,
                              void* d_out, int out_size, void* d_ws, size_t ws_size,
                              hipStream_t stream)
{
  const float* data = (const float*)d_in[0];
  const float* W1   = (const float*)d_in[1];
  const float* b1   = (const float*)d_in[2];
  const float* cls  = (const float*)d_in[3];
  const float* lng[2]  = {(const float*)d_in[4],  (const float*)d_in[10]};
  const float* lnb[2]  = {(const float*)d_in[5],  (const float*)d_in[11]};
  const float* Wqkv[2] = {(const float*)d_in[6],  (const float*)d_in[12]};
  const float* Wo[2]   = {(const float*)d_in[7],  (const float*)d_in[13]};
  const float* bo[2]   = {(const float*)d_in[8],  (const float*)d_in[14]};
  const float* resw[2] = {(const float*)d_in[9],  (const float*)d_in[15]};
  const float* pw7 = (const float*)d_in[16];
  const float* pb7 = (const float*)d_in[17];
  const float* pw5 = (const float*)d_in[18];
  const float* pb5 = (const float*)d_in[19];
  const float* pw3 = (const float*)d_in[20];
  const float* pb3 = (const float*)d_in[21];
  const float* lnfg = (const float*)d_in[22];
  const float* lnfb = (const float*)d_in[23];
  const float* W2  = (const float*)d_in[24];
  const float* b2  = (const float*)d_in[25];

  float* ws = (float*)d_ws;
  size_t off = 0;
  auto alloc = [&](size_t n) { float* p = ws + off; off += n; return p; };
  float* hbuf  = alloc((size_t)BATCH * NTOK * EMBED);
  float* xpad  = alloc((size_t)BATCH * NPAD * EMBED);   // also reused as attn_out
  float* qbuf  = alloc((size_t)BH * NPAD * DH);         // also reused as conv tmp
  float* kbuf  = alloc((size_t)BH * NPAD * DH);
  float* vbuf  = alloc((size_t)BH * NPAD * DH);
  float* qland = alloc((size_t)BH * MM * DH);
  float* kland = alloc((size_t)BH * MM * DH);
  float* a2    = alloc((size_t)BH * MM * MM);
  float* za    = alloc((size_t)BH * MM * MM);
  float* zb    = alloc((size_t)BH * MM * MM);
  float* xzb   = alloc((size_t)BH * MM * MM);
  float* t1b   = alloc((size_t)BH * MM * MM);
  float* t2b   = alloc((size_t)BH * MM * MM);
  float* kvb   = alloc((size_t)BH * MM * DH);
  float* kv2b  = alloc((size_t)BH * MM * DH);
  float* wcomb = alloc(49 * EMBED);
  float* biasc = alloc(EMBED);
  float* denoms = alloc(64);
  float* mpart = alloc((size_t)NSEG * BH * MM);
  float* lpart = alloc((size_t)NSEG * BH * MM);
  float* attn = xpad;
  float* Opart = za;   // overlay: a3v partials live in za..t2b (needs 9.14M < 10.49M floats)

  gemm_abt<<<dim3(EMBED / 64, (BATCH * N0) / 64), 256, 0, stream>>>(
      data, W1, BATCH * N0, EMBED, CIN, b1, hbuf, nullptr, nullptr, 0);
  cls_kernel<<<dim3((BATCH * EMBED + 255) / 256), 256, 0, stream>>>(cls, hbuf);

  for (int layer = 0; layer < 2; layer++) {
    ln_pad_kernel<<<dim3(BATCH * NTOK), 256, 0, stream>>>(hbuf, lng[layer], lnb[layer], xpad);
    zero_pad_kernel<<<dim3((BATCH * 255 * EMBED + 255) / 256), 256, 0, stream>>>(xpad);
    gemm_abt<<<dim3((3 * EMBED) / 64, (BATCH * NPAD) / 64), 256, 0, stream>>>(
        xpad, Wqkv[layer], BATCH * NPAD, 3 * EMBED, EMBED, nullptr, qbuf, kbuf, vbuf, 1);
    landmarks_kernel<<<dim3(MM / 4, BH), 256, 0, stream>>>(qbuf, kbuf, qland, kland);
    s2_softmax_kernel<<<dim3(MM, BH), 256, 0, stream>>>(qland, kland, a2);
    init_denom_kernel<<<1, 64, 0, stream>>>(denoms);
    denom_kernel<<<dim3(BH), 256, 0, stream>>>(a2, denoms);

    // a3@v before pinv so Opart can overlay the pinv scratch buffers
    a3v_part_kernel<<<dim3(8 * NSEG, BH), 256, 0, stream>>>(
        qland, kbuf, vbuf, Opart, mpart, lpart);
    a3v_merge_kernel<<<dim3(MM / 64, BH), 256, 0, stream>>>(Opart, mpart, lpart, kvb);

    z0_kernel<<<dim3(MM / 64, MM / 4, BH), dim3(64, 4), 0, stream>>>(a2, denoms, za);
    float* zin = za;
    float* zout = zb;
    for (int it = 0; it < 6; it++) {
      gemm_nn_batched<<<dim3(4, 4, BH), 256, 0, stream>>>(a2, zin, xzb, MM, MM, MM, 0.f, 1.f, 1.f);
      gemm_nn_batched<<<dim3(4, 4, BH), 256, 0, stream>>>(xzb, xzb, t1b, MM, MM, MM, 7.f, -1.f, 1.f);
      gemm_nn_batched<<<dim3(4, 4, BH), 256, 0, stream>>>(xzb, t1b, t2b, MM, MM, MM, 15.f, -1.f, 1.f);
      gemm_nn_batched<<<dim3(4, 4, BH), 256, 0, stream>>>(zin, t2b, zout, MM, MM, MM, 13.f, -1.f, 0.25f);
      float* t = zin; zin = zout; zout = t;
    }
    gemm_nn_batched<<<dim3(1, 4, BH), 256, 0, stream>>>(zin, kvb, kv2b, MM, DH, MM, 0.f, 1.f, 1.f);
    attn1_kernel<<<dim3((NTOK + 31) / 32, BH), 256, 0, stream>>>(
        qbuf, kland, kv2b, vbuf, resw[layer], attn);
    gemm_abt<<<dim3(EMBED / 64, (BATCH * NTOK + 63) / 64), 256, 0, stream>>>(
        attn, Wo[layer], BATCH * NTOK, EMBED, EMBED, bo[layer], hbuf, nullptr, nullptr, 2);

    if (layer == 0) {
      prep_wcomb_kernel<<<dim3((EMBED * 49 + 255) / 256), 256, 0, stream>>>(
          pw7, pw5, pw3, pb7, pb5, pb3, wcomb, biasc);
      copy_feat_kernel<<<dim3((unsigned)(((size_t)BATCH * N0 * EMBED + 255) / 256)), 256, 0, stream>>>(hbuf, qbuf);
      dwconv_kernel<<<dim3(EMBED / 64, N0 / 4, BATCH), dim3(64, 4), 0, stream>>>(qbuf, wcomb, biasc, hbuf);
    }
  }

  final_kernel<<<dim3(BATCH), 256, 0, stream>>>(hbuf, lnfg, lnfb, W2, b2, (float*)d_out);
}

// Round 4
// 2566.153 us; speedup vs baseline: 4.8443x; 1.7432x over previous
//
#include <hip/hip_runtime.h>
#include <math.h>

#define EMBED 512
#define HEADS 8
#define DH 64
#define MM 256
#define LSEG 17
#define NPAD 4352
#define NTOK 4097
#define N0 4096
#define BATCH 4
#define CIN 1536
#define QSCALE 0.125f
#define BH 32   // BATCH*HEADS
#define NSEG 17 // key segments of 256 for a3v

typedef float fp32x4 __attribute__((ext_vector_type(4)));
typedef short bf16x8 __attribute__((ext_vector_type(8)));
typedef short bf16x4 __attribute__((ext_vector_type(4)));

__device__ __forceinline__ unsigned short f2bf(float f) {
  unsigned int u = __float_as_uint(f);
  u += 0x7fffu + ((u >> 16) & 1u);
  return (unsigned short)(u >> 16);
}

// ---------------- block reduction helpers (blockDim.x == 256) ----------------
__device__ __forceinline__ float block_sum(float v, float* red) {
  #pragma unroll
  for (int o = 1; o < 64; o <<= 1) v += __shfl_xor(v, o);
  int lane = threadIdx.x & 63, wid = threadIdx.x >> 6;
  if (lane == 0) red[wid] = v;
  __syncthreads();
  float r = red[0] + red[1] + red[2] + red[3];
  __syncthreads();
  return r;
}
__device__ __forceinline__ float block_max(float v, float* red) {
  #pragma unroll
  for (int o = 1; o < 64; o <<= 1) v = fmaxf(v, __shfl_xor(v, o));
  int lane = threadIdx.x & 63, wid = threadIdx.x >> 6;
  if (lane == 0) red[wid] = v;
  __syncthreads();
  float r = fmaxf(fmaxf(red[0], red[1]), fmaxf(red[2], red[3]));
  __syncthreads();
  return r;
}

// ------------- bf16-MFMA tiled GEMM  C = A(M,K) @ W(N,K)^T  ------------------
__global__ __launch_bounds__(256) void gemm_abt(
    const float* __restrict__ A, const float* __restrict__ W,
    int Mrows, int Ncols, int K, const float* __restrict__ bias,
    float* __restrict__ out0, float* __restrict__ out1, float* __restrict__ out2,
    int mode)
{
  __shared__ unsigned short As[64][40];
  __shared__ unsigned short Ws[64][40];
  int tid = threadIdx.x;
  int lane = tid & 63;
  int wv = tid >> 6;
  int rowBase = blockIdx.y * 64, colBase = blockIdx.x * 64;
  int quad = lane >> 4;
  int l15 = lane & 15;
  int sr = tid >> 2;
  int skc = (tid & 3) * 8;

  fp32x4 acc[4] = {fp32x4{0,0,0,0}, fp32x4{0,0,0,0}, fp32x4{0,0,0,0}, fp32x4{0,0,0,0}};

  for (int kb = 0; kb < K; kb += 32) {
    __syncthreads();
    {
      int grow = rowBase + sr;
      float va[8];
      if (grow < Mrows) {
        const float4* p = (const float4*)&A[(size_t)grow * K + kb + skc];
        float4 v0 = p[0], v1 = p[1];
        va[0]=v0.x; va[1]=v0.y; va[2]=v0.z; va[3]=v0.w;
        va[4]=v1.x; va[5]=v1.y; va[6]=v1.z; va[7]=v1.w;
      } else {
        #pragma unroll
        for (int j = 0; j < 8; j++) va[j] = 0.f;
      }
      bf16x8 pk;
      #pragma unroll
      for (int j = 0; j < 8; j++) pk[j] = (short)f2bf(va[j]);
      *(bf16x8*)&As[sr][skc] = pk;
    }
    {
      int gcol = colBase + sr;
      const float4* p = (const float4*)&W[(size_t)gcol * K + kb + skc];
      float4 v0 = p[0], v1 = p[1];
      float vb[8] = {v0.x, v0.y, v0.z, v0.w, v1.x, v1.y, v1.z, v1.w};
      bf16x8 pk;
      #pragma unroll
      for (int j = 0; j < 8; j++) pk[j] = (short)f2bf(vb[j]);
      *(bf16x8*)&Ws[sr][skc] = pk;
    }
    __syncthreads();
    bf16x8 aF = *(const bf16x8*)&As[wv * 16 + l15][quad * 8];
    #pragma unroll
    for (int ns = 0; ns < 4; ns++) {
      bf16x8 bF = *(const bf16x8*)&Ws[ns * 16 + l15][quad * 8];
      acc[ns] = __builtin_amdgcn_mfma_f32_16x16x32_bf16(aF, bF, acc[ns], 0, 0, 0);
    }
  }

  #pragma unroll
  for (int ns = 0; ns < 4; ns++) {
    int col = colBase + ns * 16 + l15;
    #pragma unroll
    for (int i = 0; i < 4; i++) {
      int row = rowBase + wv * 16 + quad * 4 + i;
      if (row >= Mrows) continue;
      float v = acc[ns][i];
      if (mode == 0) {
        v += bias[col];
        v = fmaxf(v, 0.f);
        int b = row / N0, n = row % N0;
        out0[((size_t)b * NTOK + 1 + n) * EMBED + col] = v;
      } else if (mode == 1) {
        int b = row / NPAD, n = row % NPAD;
        int sec = col / EMBED;
        int hh = (col % EMBED) / DH;
        int d = col & 63;
        float* dst = (sec == 0) ? out0 : ((sec == 1) ? out1 : out2);
        if (sec == 0) v *= QSCALE;
        dst[(((size_t)b * HEADS + hh) * NPAD + n) * DH + d] = v;
      } else {
        v += bias[col];
        out0[(size_t)row * EMBED + col] += v;
      }
    }
  }
}

// ---- bf16-MFMA batched NN GEMM:  C = gamma*(sgn*(A@B) + beta*A)  ------------
// A: (batch, 256, 256)  B: (batch, 256, Nsize)
// transOut=0: C[row][col] (Nsize cols); transOut=1: C[col][256=row] (kv2T)
#define BSWZ(n, k) ((((k) + (((n) >> 3) & 3) * 8)) & 31)
__global__ __launch_bounds__(256) void gemm_nn_mfma(
    const float* __restrict__ A, const float* __restrict__ B, float* __restrict__ C,
    int Nsize, float beta, float sgn, float gamma, int transOut)
{
  __shared__ unsigned short As[64][40];
  __shared__ unsigned short BsT[64][40];
  int batch = blockIdx.z;
  const float* Ab = A + (size_t)batch * MM * MM;
  const float* Bb = B + (size_t)batch * MM * Nsize;
  float* Cb = C + (size_t)batch * MM * Nsize;
  int tid = threadIdx.x;
  int lane = tid & 63, wv = tid >> 6, quad = lane >> 4, l15 = lane & 15;
  int rowBase = blockIdx.y * 64, colBase = blockIdx.x * 64;
  int asr = tid >> 2, ask = (tid & 3) * 8;
  int bkr = tid >> 3;            // k-row within 32-step
  int bnc = (tid & 7) * 8;       // col base
  fp32x4 acc[4] = {fp32x4{0,0,0,0}, fp32x4{0,0,0,0}, fp32x4{0,0,0,0}, fp32x4{0,0,0,0}};

  for (int kb = 0; kb < MM; kb += 32) {
    __syncthreads();
    {
      const float4* p = (const float4*)&Ab[(size_t)(rowBase + asr) * MM + kb + ask];
      float4 v0 = p[0], v1 = p[1];
      float va[8] = {v0.x, v0.y, v0.z, v0.w, v1.x, v1.y, v1.z, v1.w};
      bf16x8 pk;
      #pragma unroll
      for (int j = 0; j < 8; j++) pk[j] = (short)f2bf(va[j]);
      *(bf16x8*)&As[asr][ask] = pk;
    }
    {
      const float4* p = (const float4*)&Bb[(size_t)(kb + bkr) * Nsize + colBase + bnc];
      float4 v0 = p[0], v1 = p[1];
      float vb[8] = {v0.x, v0.y, v0.z, v0.w, v1.x, v1.y, v1.z, v1.w};
      #pragma unroll
      for (int j = 0; j < 8; j++) {
        int n = bnc + j;
        BsT[n][BSWZ(n, bkr)] = f2bf(vb[j]);
      }
    }
    __syncthreads();
    bf16x8 aF = *(const bf16x8*)&As[wv * 16 + l15][quad * 8];
    #pragma unroll
    for (int ct = 0; ct < 4; ct++) {
      int n = ct * 16 + l15;
      bf16x8 bF = *(const bf16x8*)&BsT[n][BSWZ(n, quad * 8)];
      acc[ct] = __builtin_amdgcn_mfma_f32_16x16x32_bf16(aF, bF, acc[ct], 0, 0, 0);
    }
  }

  #pragma unroll
  for (int ct = 0; ct < 4; ct++) {
    int col = colBase + ct * 16 + l15;
    #pragma unroll
    for (int i = 0; i < 4; i++) {
      int row = rowBase + wv * 16 + quad * 4 + i;
      float v = sgn * acc[ct][i];
      if (beta != 0.f) v += beta * Ab[(size_t)row * MM + col];
      v *= gamma;
      if (transOut == 0) Cb[(size_t)row * Nsize + col] = v;
      else               Cb[(size_t)col * MM + row] = v;
    }
  }
}

// ---------------- small utility kernels ----------------
__global__ void cls_kernel(const float* __restrict__ cls, float* __restrict__ h) {
  int t = blockIdx.x * blockDim.x + threadIdx.x;
  if (t >= BATCH * EMBED) return;
  int b = t / EMBED, c = t % EMBED;
  h[(size_t)b * NTOK * EMBED + c] = cls[c];
}

__global__ void zero_pad_kernel(float* __restrict__ xpad) {
  int t = blockIdx.x * blockDim.x + threadIdx.x;
  const int per = 255 * EMBED;
  if (t >= BATCH * per) return;
  int b = t / per, r = t % per;
  xpad[(size_t)b * NPAD * EMBED + r] = 0.f;
}

__global__ __launch_bounds__(256) void ln_pad_kernel(
    const float* __restrict__ h, const float* __restrict__ g,
    const float* __restrict__ be, float* __restrict__ xpad)
{
  __shared__ float red[4];
  int row = blockIdx.x;
  int b = row / NTOK, j = row % NTOK;
  const float* x = h + (size_t)row * EMBED;
  int tid = threadIdx.x;
  float v0 = x[tid], v1 = x[tid + 256];
  float mu = block_sum(v0 + v1, red) * (1.f / 512.f);
  float d0 = v0 - mu, d1 = v1 - mu;
  float var = block_sum(d0 * d0 + d1 * d1, red) * (1.f / 512.f);
  float inv = 1.f / sqrtf(var + 1e-5f);
  float* o = xpad + ((size_t)b * NPAD + 255 + j) * EMBED;
  o[tid]       = d0 * inv * g[tid]       + be[tid];
  o[tid + 256] = d1 * inv * g[tid + 256] + be[tid + 256];
}

__global__ __launch_bounds__(256) void landmarks_kernel(
    const float* __restrict__ q, const float* __restrict__ k,
    float* __restrict__ qland, float* __restrict__ kland)
{
  int bh = blockIdx.y;
  int m = blockIdx.x * 4 + (threadIdx.x >> 6);
  int d = threadIdx.x & 63;
  const float* qb = q + (size_t)bh * NPAD * DH;
  const float* kb = k + (size_t)bh * NPAD * DH;
  float sq = 0.f, sk = 0.f;
  int base = m * LSEG;
  #pragma unroll
  for (int t = 0; t < LSEG; t++) {
    sq += qb[(size_t)(base + t) * DH + d];
    sk += kb[(size_t)(base + t) * DH + d];
  }
  qland[((size_t)bh * MM + m) * DH + d] = sq * (1.f / LSEG);
  kland[((size_t)bh * MM + m) * DH + d] = sk * (1.f / LSEG);
}

__global__ __launch_bounds__(256) void s2_softmax_kernel(
    const float* __restrict__ qland, const float* __restrict__ kland,
    float* __restrict__ a2)
{
  __shared__ float qrow[64];
  __shared__ float red[4];
  int bh = blockIdx.y, m = blockIdx.x, tid = threadIdx.x;
  if (tid < 64) qrow[tid] = qland[((size_t)bh * MM + m) * DH + tid];
  __syncthreads();
  const float* kb = kland + (size_t)bh * MM * DH + (size_t)tid * DH;
  float s = 0.f;
  #pragma unroll 16
  for (int d = 0; d < 64; d++) s += qrow[d] * kb[d];
  float mx = block_max(s, red);
  float e = __expf(s - mx);
  float tot = block_sum(e, red);
  a2[((size_t)bh * MM + m) * MM + tid] = e / tot;
}

__global__ void init_denom_kernel(float* __restrict__ denoms) {
  if (threadIdx.x < 2) denoms[threadIdx.x] = 0.f;
}

__global__ __launch_bounds__(256) void denom_kernel(
    const float* __restrict__ a2, float* __restrict__ denoms)
{
  __shared__ float red[4];
  int bh = blockIdx.x, tid = threadIdx.x;
  const float* A = a2 + (size_t)bh * MM * MM;
  float rs = 0.f, cs = 0.f;
  for (int j = 0; j < MM; j++) rs += A[(size_t)tid * MM + j];
  for (int i = 0; i < MM; i++) cs += A[(size_t)i * MM + tid];
  float mr = block_max(rs, red);
  float mc = block_max(cs, red);
  if (tid == 0) {
    atomicMax((int*)&denoms[0], __float_as_int(mr));
    atomicMax((int*)&denoms[1], __float_as_int(mc));
  }
}

__global__ void z0_kernel(const float* __restrict__ a2,
                          const float* __restrict__ denoms, float* __restrict__ z)
{
  int bh = blockIdx.z;
  int i = blockIdx.y * 4 + threadIdx.y;
  int j = blockIdx.x * 64 + threadIdx.x;
  float denom = denoms[0] * denoms[1];
  z[((size_t)bh * MM + i) * MM + j] = a2[((size_t)bh * MM + j) * MM + i] / denom;
}

// ---------- a3@v partial flash: block = 32 landmarks x 256-key segment -------
__global__ __launch_bounds__(256) void a3v_part_kernel(
    const float* __restrict__ qland, const float* __restrict__ k,
    const float* __restrict__ v, float* __restrict__ Opart,
    float* __restrict__ mpart, float* __restrict__ lpart)
{
  __shared__ float qs[32][65];
  __shared__ float ks[64][65];
  __shared__ float vs[64][65];
  __shared__ float ps[32][65];
  int bh = blockIdx.y;
  int ltile = blockIdx.x & 7;
  int seg = blockIdx.x >> 3;
  int l0 = ltile * 32;
  int key0 = seg * 256;
  int tid = threadIdx.x;
  int tx = tid & 15, ty = tid >> 4;
  int r0 = ty * 2, r1 = r0 + 1;
  const float* kb = k + (size_t)bh * NPAD * DH;
  const float* vb = v + (size_t)bh * NPAD * DH;

  for (int i = tid; i < 32 * 64; i += 256)
    qs[i >> 6][i & 63] = qland[((size_t)bh * MM + l0 + (i >> 6)) * DH + (i & 63)];

  float O[2][4] = {};
  float mrow[2] = {-3.0e38f, -3.0e38f};
  float lrow[2] = {0.f, 0.f};

  for (int nt = 0; nt < 4; nt++) {
    __syncthreads();
    for (int i = tid; i < 64 * 64; i += 256) {
      int lr = i >> 6, d = i & 63;
      ks[lr][d] = kb[(size_t)(key0 + nt * 64 + lr) * DH + d];
      vs[lr][d] = vb[(size_t)(key0 + nt * 64 + lr) * DH + d];
    }
    __syncthreads();
    float s[2][4] = {};
    #pragma unroll 8
    for (int d = 0; d < 64; d++) {
      float a0 = qs[r0][d], a1 = qs[r1][d];
      #pragma unroll
      for (int j = 0; j < 4; j++) {
        float bv = ks[tx * 4 + j][d];
        s[0][j] += a0 * bv;
        s[1][j] += a1 * bv;
      }
    }
    #pragma unroll
    for (int i = 0; i < 2; i++) {
      float mx = fmaxf(fmaxf(s[i][0], s[i][1]), fmaxf(s[i][2], s[i][3]));
      #pragma unroll
      for (int o = 1; o < 16; o <<= 1) mx = fmaxf(mx, __shfl_xor(mx, o));
      float mnew = fmaxf(mrow[i], mx);
      float alpha = __expf(mrow[i] - mnew);
      mrow[i] = mnew;
      float psum = 0.f;
      int rr = r0 + i;
      #pragma unroll
      for (int j = 0; j < 4; j++) {
        float e = __expf(s[i][j] - mnew);
        ps[rr][tx * 4 + j] = e;
        psum += e;
      }
      #pragma unroll
      for (int o = 1; o < 16; o <<= 1) psum += __shfl_xor(psum, o);
      lrow[i] = lrow[i] * alpha + psum;
      #pragma unroll
      for (int j = 0; j < 4; j++) O[i][j] *= alpha;
    }
    __syncthreads();
    #pragma unroll 8
    for (int kk = 0; kk < 64; kk++) {
      float a0 = ps[r0][kk], a1 = ps[r1][kk];
      #pragma unroll
      for (int j = 0; j < 4; j++) {
        float bv = vs[kk][tx * 4 + j];
        O[0][j] += a0 * bv;
        O[1][j] += a1 * bv;
      }
    }
  }
  size_t base = ((size_t)seg * BH + bh) * MM + l0;
  #pragma unroll
  for (int i = 0; i < 2; i++) {
    int rr = r0 + i;
    #pragma unroll
    for (int j = 0; j < 4; j++)
      Opart[(base + rr) * DH + tx * 4 + j] = O[i][j];
    if (tx == 0) {
      mpart[base + rr] = mrow[i];
      lpart[base + rr] = lrow[i];
    }
  }
}

__global__ __launch_bounds__(256) void a3v_merge_kernel(
    const float* __restrict__ Opart, const float* __restrict__ mpart,
    const float* __restrict__ lpart, float* __restrict__ kv)
{
  int bh = blockIdx.y;
  int lbase = blockIdx.x * 64;
  int d = threadIdx.x & 63, lsub = threadIdx.x >> 6;
  for (int li = lsub; li < 64; li += 4) {
    int lm = lbase + li;
    float M = -3.0e38f;
    #pragma unroll
    for (int s = 0; s < NSEG; s++)
      M = fmaxf(M, mpart[((size_t)s * BH + bh) * MM + lm]);
    float L = 0.f, O = 0.f;
    #pragma unroll
    for (int s = 0; s < NSEG; s++) {
      size_t idx = ((size_t)s * BH + bh) * MM + lm;
      float w = __expf(mpart[idx] - M);
      L += lpart[idx] * w;
      O += Opart[idx * DH + d] * w;
    }
    kv[((size_t)bh * MM + lm) * DH + d] = O / L;
  }
}

// ---- MFMA fused a1-softmax @ kv2T + depthwise res-conv(33): 64 rows/block ---
__global__ __launch_bounds__(256, 2) void attn1_mfma(
    const float* __restrict__ q, const float* __restrict__ kland,
    const float* __restrict__ kv2T, const float* __restrict__ v,
    const float* __restrict__ resw, float* __restrict__ attn)
{
  __shared__ __align__(16) unsigned short qs[64][40];     //  5120 B
  __shared__ __align__(16) unsigned short klp[256][72];   // 36864 B: kland frags -> P (stride 264)
  __shared__ __align__(16) unsigned short kvs[64][264];   // 33792 B: kv2T frags -> vwin fp32 [96][68]
  __shared__ float wsm[33];
  int tid = threadIdx.x;
  int lane = tid & 63, wv = tid >> 6, quad = lane >> 4, l15 = lane & 15;
  int bh = blockIdx.y, b = bh >> 3, hh = bh & 7;
  int n0 = 255 + blockIdx.x * 64;
  const float* qb  = q + (size_t)bh * NPAD * DH;
  const float* klb = kland + (size_t)bh * MM * DH;
  const float* kvb = kv2T + (size_t)bh * DH * MM;
  const float* vb  = v + (size_t)bh * NPAD * DH;
  if (tid < 33) wsm[tid] = resw[hh * 33 + tid];

  // stage q (64 rows x 64 d), row-clamped
  {
    int sr = tid >> 2, dc = (tid & 3) * 16;
    int g = n0 + sr; if (g > NPAD - 1) g = NPAD - 1;
    const float4* p = (const float4*)&qb[(size_t)g * DH + dc];
    float4 v0 = p[0], v1 = p[1], v2 = p[2], v3 = p[3];
    float va[16] = {v0.x,v0.y,v0.z,v0.w, v1.x,v1.y,v1.z,v1.w,
                    v2.x,v2.y,v2.z,v2.w, v3.x,v3.y,v3.z,v3.w};
    bf16x8 p0, p1;
    #pragma unroll
    for (int j = 0; j < 8; j++) { p0[j] = (short)f2bf(va[j]); p1[j] = (short)f2bf(va[8 + j]); }
    *(bf16x8*)&qs[sr][dc] = p0;
    *(bf16x8*)&qs[sr][dc + 8] = p1;
  }
  // stage kland 256x64 (stride 72)
  #pragma unroll
  for (int i = 0; i < 16; i++) {
    int idx = i * 1024 + tid * 4;
    int r = idx >> 6, c = idx & 63;
    float4 vv = *(const float4*)&klb[(size_t)r * DH + c];
    bf16x4 pk = { (short)f2bf(vv.x), (short)f2bf(vv.y), (short)f2bf(vv.z), (short)f2bf(vv.w) };
    *(bf16x4*)&klp[r][c] = pk;
  }
  // stage kv2T 64x256 (stride 264)
  #pragma unroll
  for (int i = 0; i < 16; i++) {
    int idx = i * 1024 + tid * 4;
    int r = idx >> 8, c = idx & 255;
    float4 vv = *(const float4*)&kvb[(size_t)r * MM + c];
    bf16x4 pk = { (short)f2bf(vv.x), (short)f2bf(vv.y), (short)f2bf(vv.z), (short)f2bf(vv.w) };
    *(bf16x4*)&kvs[r][c] = pk;
  }
  __syncthreads();

  // s1 = Q @ kland^T : 64x256 in C-layout regs
  fp32x4 sacc[16];
  #pragma unroll
  for (int ct = 0; ct < 16; ct++) sacc[ct] = fp32x4{0,0,0,0};
  bf16x8 aF0 = *(const bf16x8*)&qs[wv * 16 + l15][quad * 8];
  bf16x8 aF1 = *(const bf16x8*)&qs[wv * 16 + l15][32 + quad * 8];
  #pragma unroll
  for (int ct = 0; ct < 16; ct++) {
    bf16x8 b0 = *(const bf16x8*)&klp[ct * 16 + l15][quad * 8];
    bf16x8 b1 = *(const bf16x8*)&klp[ct * 16 + l15][32 + quad * 8];
    sacc[ct] = __builtin_amdgcn_mfma_f32_16x16x32_bf16(aF0, b0, sacc[ct], 0, 0, 0);
    sacc[ct] = __builtin_amdgcn_mfma_f32_16x16x32_bf16(aF1, b1, sacc[ct], 0, 0, 0);
  }
  // register softmax: row = quad*4+i, cols spread over l15 x 16 tiles
  #pragma unroll
  for (int i = 0; i < 4; i++) {
    float m = -3.0e38f;
    #pragma unroll
    for (int ct = 0; ct < 16; ct++) m = fmaxf(m, sacc[ct][i]);
    #pragma unroll
    for (int o = 1; o < 16; o <<= 1) m = fmaxf(m, __shfl_xor(m, o));
    float s = 0.f;
    #pragma unroll
    for (int ct = 0; ct < 16; ct++) {
      float e = __expf(sacc[ct][i] - m);
      sacc[ct][i] = e;
      s += e;
    }
    #pragma unroll
    for (int o = 1; o < 16; o <<= 1) s += __shfl_xor(s, o);
    float inv = 1.f / s;
    #pragma unroll
    for (int ct = 0; ct < 16; ct++) sacc[ct][i] *= inv;
  }
  __syncthreads();   // all waves done reading klp as kland
  // write P (normalized, bf16) into klp region, stride 264
  unsigned short* P = &klp[0][0];
  #pragma unroll
  for (int ct = 0; ct < 16; ct++)
    #pragma unroll
    for (int i = 0; i < 4; i++)
      P[(size_t)(wv * 16 + quad * 4 + i) * 264 + ct * 16 + l15] = f2bf(sacc[ct][i]);
  __syncthreads();

  // O = P @ kv2  (kv2T frags contiguous)
  fp32x4 oacc[4] = {fp32x4{0,0,0,0}, fp32x4{0,0,0,0}, fp32x4{0,0,0,0}, fp32x4{0,0,0,0}};
  #pragma unroll
  for (int ks = 0; ks < 8; ks++) {
    bf16x8 aP = *(const bf16x8*)&P[(size_t)(wv * 16 + l15) * 264 + ks * 32 + quad * 8];
    #pragma unroll
    for (int ct = 0; ct < 4; ct++) {
      bf16x8 bV = *(const bf16x8*)&kvs[ct * 16 + l15][ks * 32 + quad * 8];
      oacc[ct] = __builtin_amdgcn_mfma_f32_16x16x32_bf16(aP, bV, oacc[ct], 0, 0, 0);
    }
  }
  __syncthreads();   // done with kvs as kv2T
  // stage v window rows n0-16 .. n0+79 as fp32 [96][68] into kvs region
  float* vwin = (float*)&kvs[0][0];
  #pragma unroll
  for (int i = 0; i < 6; i++) {
    int r = i * 16 + (tid >> 4), c = (tid & 15) * 4;
    int g = n0 - 16 + r;
    float4 vv;
    if (g <= NPAD - 1) vv = *(const float4*)&vb[(size_t)g * DH + c];
    else { vv.x = 0.f; vv.y = 0.f; vv.z = 0.f; vv.w = 0.f; }
    *(float4*)&vwin[r * 68 + c] = vv;
  }
  __syncthreads();
  // conv + write
  #pragma unroll
  for (int ct = 0; ct < 4; ct++) {
    int c = ct * 16 + l15;
    #pragma unroll
    for (int i = 0; i < 4; i++) {
      int rl = wv * 16 + quad * 4 + i;
      int n = n0 + rl;
      if (n > NPAD - 1) continue;
      float ca = 0.f;
      #pragma unroll 11
      for (int t = 0; t < 33; t++) ca += vwin[(rl + t) * 68 + c] * wsm[t];
      attn[((size_t)b * NTOK + (n - 255)) * EMBED + hh * DH + c] = oacc[ct][i] + ca;
    }
  }
}

// combine 7x7 + 5x5 + 3x3 + identity into one 7x7 depthwise kernel
__global__ void prep_wcomb_kernel(
    const float* __restrict__ pw7, const float* __restrict__ pw5,
    const float* __restrict__ pw3, const float* __restrict__ pb7,
    const float* __restrict__ pb5, const float* __restrict__ pb3,
    float* __restrict__ wcomb, float* __restrict__ biasc)
{
  int i = blockIdx.x * blockDim.x + threadIdx.x;
  if (i < EMBED * 49) {
    int c = i / 49, tap = i % 49;
    int ky = tap / 7, kx = tap % 7;
    float v = pw7[c * 49 + tap];
    if (ky >= 1 && ky <= 5 && kx >= 1 && kx <= 5) v += pw5[c * 25 + (ky - 1) * 5 + (kx - 1)];
    if (ky >= 2 && ky <= 4 && kx >= 2 && kx <= 4) v += pw3[c * 9 + (ky - 2) * 3 + (kx - 2)];
    if (ky == 3 && kx == 3) v += 1.f;
    wcomb[tap * EMBED + c] = v;
  }
  if (i < EMBED) biasc[i] = pb7[i] + pb5[i] + pb3[i];
}

__global__ void copy_feat_kernel(const float* __restrict__ h, float* __restrict__ tmp) {
  size_t t = (size_t)blockIdx.x * blockDim.x + threadIdx.x;
  if (t >= (size_t)BATCH * N0 * EMBED) return;
  size_t per = (size_t)N0 * EMBED;
  size_t b = t / per, r = t % per;
  tmp[t] = h[((size_t)b * NTOK + 1) * EMBED + r];
}

__global__ __launch_bounds__(256) void dwconv_kernel(
    const float* __restrict__ tmp, const float* __restrict__ wcomb,
    const float* __restrict__ biasc, float* __restrict__ h)
{
  __shared__ float wsm[49][64];
  int cb = blockIdx.x * 64;
  int c = cb + threadIdx.x;
  int b = blockIdx.z;
  int n = blockIdx.y * 4 + threadIdx.y;
  int y = n >> 6, x = n & 63;
  int tid = threadIdx.y * 64 + threadIdx.x;
  for (int i = tid; i < 49 * 64; i += 256) {
    int tap = i >> 6, cc = i & 63;
    wsm[tap][cc] = wcomb[tap * EMBED + cb + cc];
  }
  __syncthreads();
  const float* src = tmp + (size_t)b * N0 * EMBED;
  float acc = biasc[c];
  #pragma unroll
  for (int ky = 0; ky < 7; ky++) {
    int yy = y + ky - 3;
    if (yy < 0 || yy >= 64) continue;
    #pragma unroll
    for (int kx = 0; kx < 7; kx++) {
      int xx = x + kx - 3;
      if (xx < 0 || xx >= 64) continue;
      acc += src[((size_t)yy * 64 + xx) * EMBED + c] * wsm[ky * 7 + kx][threadIdx.x];
    }
  }
  h[((size_t)b * NTOK + 1 + n) * EMBED + c] = acc;
}

__global__ __launch_bounds__(256) void final_kernel(
    const float* __restrict__ h, const float* __restrict__ g,
    const float* __restrict__ be, const float* __restrict__ W2,
    const float* __restrict__ b2, float* __restrict__ out)
{
  __shared__ float red[4];
  int b = blockIdx.x, tid = threadIdx.x;
  const float* x = h + (size_t)b * NTOK * EMBED;
  float v0 = x[tid], v1 = x[tid + 256];
  float mu = block_sum(v0 + v1, red) * (1.f / 512.f);
  float d0 = v0 - mu, d1 = v1 - mu;
  float var = block_sum(d0 * d0 + d1 * d1, red) * (1.f / 512.f);
  float inv = 1.f / sqrtf(var + 1e-5f);
  float xn0 = d0 * inv * g[tid] + be[tid];
  float xn1 = d1 * inv * g[tid + 256] + be[tid + 256];
  float l0 = block_sum(xn0 * W2[tid] + xn1 * W2[tid + 256], red);
  float l1 = block_sum(xn0 * W2[512 + tid] + xn1 * W2[512 + tid + 256], red);
  if (tid == 0) {
    l0 += b2[0]; l1 += b2[1];
    out[b * 2 + 0] = l0;
    out[b * 2 + 1] = l1;
    float mx = fmaxf(l0, l1);
    float e0 = expf(l0 - mx), e1 = expf(l1 - mx);
    float s = e0 + e1;
    out[8 + b * 2 + 0] = e0 / s;
    out[8 + b * 2 + 1] = e1 / s;
    out[16 + b] = (l1 > l0) ? 1.f : 0.f;
  }
}

// ------------------------------- host side -----------------------------------
extern "C" void kernel_launch(void* const* d_in, const int* in_sizes, int n_in,
                              void* d_out, int out_size, void* d_ws, size_t ws_size,
                              hipStream_t stream)
{
  const float* data = (const float*)d_in[0];
  const float* W1   = (const float*)d_in[1];
  const float* b1   = (const float*)d_in[2];
  const float* cls  = (const float*)d_in[3];
  const float* lng[2]  = {(const float*)d_in[4],  (const float*)d_in[10]};
  const float* lnb[2]  = {(const float*)d_in[5],  (const float*)d_in[11]};
  const float* Wqkv[2] = {(const float*)d_in[6],  (const float*)d_in[12]};
  const float* Wo[2]   = {(const float*)d_in[7],  (const float*)d_in[13]};
  const float* bo[2]   = {(const float*)d_in[8],  (const float*)d_in[14]};
  const float* resw[2] = {(const float*)d_in[9],  (const float*)d_in[15]};
  const float* pw7 = (const float*)d_in[16];
  const float* pb7 = (const float*)d_in[17];
  const float* pw5 = (const float*)d_in[18];
  const float* pb5 = (const float*)d_in[19];
  const float* pw3 = (const float*)d_in[20];
  const float* pb3 = (const float*)d_in[21];
  const float* lnfg = (const float*)d_in[22];
  const float* lnfb = (const float*)d_in[23];
  const float* W2  = (const float*)d_in[24];
  const float* b2  = (const float*)d_in[25];

  float* ws = (float*)d_ws;
  size_t off = 0;
  auto alloc = [&](size_t n) { float* p = ws + off; off += n; return p; };
  float* hbuf  = alloc((size_t)BATCH * NTOK * EMBED);
  float* xpad  = alloc((size_t)BATCH * NPAD * EMBED);   // reused as attn_out
  float* qbuf  = alloc((size_t)BH * NPAD * DH);         // reused as conv tmp
  float* kbuf  = alloc((size_t)BH * NPAD * DH);
  float* vbuf  = alloc((size_t)BH * NPAD * DH);
  float* qland = alloc((size_t)BH * MM * DH);
  float* kland = alloc((size_t)BH * MM * DH);
  float* a2    = alloc((size_t)BH * MM * MM);
  float* za    = alloc((size_t)BH * MM * MM);
  float* zb    = alloc((size_t)BH * MM * MM);
  float* xzb   = alloc((size_t)BH * MM * MM);
  float* t1b   = alloc((size_t)BH * MM * MM);
  float* t2b   = alloc((size_t)BH * MM * MM);
  float* kvb   = alloc((size_t)BH * MM * DH);
  float* kv2b  = alloc((size_t)BH * MM * DH);           // holds kv2T [bh][64][256]
  float* wcomb = alloc(49 * EMBED);
  float* biasc = alloc(EMBED);
  float* denoms = alloc(64);
  float* mpart = alloc((size_t)NSEG * BH * MM);
  float* lpart = alloc((size_t)NSEG * BH * MM);
  float* attn = xpad;
  float* Opart = za;   // overlay: a3v partials in za..t2b (8.9M < 10.5M floats)

  gemm_abt<<<dim3(EMBED / 64, (BATCH * N0) / 64), 256, 0, stream>>>(
      data, W1, BATCH * N0, EMBED, CIN, b1, hbuf, nullptr, nullptr, 0);
  cls_kernel<<<dim3((BATCH * EMBED + 255) / 256), 256, 0, stream>>>(cls, hbuf);

  for (int layer = 0; layer < 2; layer++) {
    ln_pad_kernel<<<dim3(BATCH * NTOK), 256, 0, stream>>>(hbuf, lng[layer], lnb[layer], xpad);
    zero_pad_kernel<<<dim3((BATCH * 255 * EMBED + 255) / 256), 256, 0, stream>>>(xpad);
    gemm_abt<<<dim3((3 * EMBED) / 64, (BATCH * NPAD) / 64), 256, 0, stream>>>(
        xpad, Wqkv[layer], BATCH * NPAD, 3 * EMBED, EMBED, nullptr, qbuf, kbuf, vbuf, 1);
    landmarks_kernel<<<dim3(MM / 4, BH), 256, 0, stream>>>(qbuf, kbuf, qland, kland);
    s2_softmax_kernel<<<dim3(MM, BH), 256, 0, stream>>>(qland, kland, a2);
    init_denom_kernel<<<1, 64, 0, stream>>>(denoms);
    denom_kernel<<<dim3(BH), 256, 0, stream>>>(a2, denoms);

    // a3@v before pinv so Opart can overlay the pinv scratch
    a3v_part_kernel<<<dim3(8 * NSEG, BH), 256, 0, stream>>>(
        qland, kbuf, vbuf, Opart, mpart, lpart);
    a3v_merge_kernel<<<dim3(MM / 64, BH), 256, 0, stream>>>(Opart, mpart, lpart, kvb);

    z0_kernel<<<dim3(MM / 64, MM / 4, BH), dim3(64, 4), 0, stream>>>(a2, denoms, za);
    float* zin = za;
    float* zout = zb;
    for (int it = 0; it < 6; it++) {
      gemm_nn_mfma<<<dim3(4, 4, BH), 256, 0, stream>>>(a2, zin, xzb, MM, 0.f, 1.f, 1.f, 0);
      gemm_nn_mfma<<<dim3(4, 4, BH), 256, 0, stream>>>(xzb, xzb, t1b, MM, 7.f, -1.f, 1.f, 0);
      gemm_nn_mfma<<<dim3(4, 4, BH), 256, 0, stream>>>(xzb, t1b, t2b, MM, 15.f, -1.f, 1.f, 0);
      gemm_nn_mfma<<<dim3(4, 4, BH), 256, 0, stream>>>(zin, t2b, zout, MM, 13.f, -1.f, 0.25f, 0);
      float* t = zin; zin = zout; zout = t;
    }
    // kv2T = (z @ kv)^T : [bh][64][256]
    gemm_nn_mfma<<<dim3(1, 4, BH), 256, 0, stream>>>(zin, kvb, kv2b, DH, 0.f, 1.f, 1.f, 1);
    attn1_mfma<<<dim3((NTOK + 63) / 64, BH), 256, 0, stream>>>(
        qbuf, kland, kv2b, vbuf, resw[layer], attn);
    gemm_abt<<<dim3(EMBED / 64, (BATCH * NTOK + 63) / 64), 256, 0, stream>>>(
        attn, Wo[layer], BATCH * NTOK, EMBED, EMBED, bo[layer], hbuf, nullptr, nullptr, 2);

    if (layer == 0) {
      prep_wcomb_kernel<<<dim3((EMBED * 49 + 255) / 256), 256, 0, stream>>>(
          pw7, pw5, pw3, pb7, pb5, pb3, wcomb, biasc);
      copy_feat_kernel<<<dim3((unsigned)(((size_t)BATCH * N0 * EMBED + 255) / 256)), 256, 0, stream>>>(hbuf, qbuf);
      dwconv_kernel<<<dim3(EMBED / 64, N0 / 4, BATCH), dim3(64, 4), 0, stream>>>(qbuf, wcomb, biasc, hbuf);
    }
  }

  final_kernel<<<dim3(BATCH), 256, 0, stream>>>(hbuf, lnfg, lnfb, W2, b2, (float*)d_out);
}

// Round 5
// 2093.544 us; speedup vs baseline: 5.9379x; 1.2257x over previous
//
#include <hip/hip_runtime.h>
#include <math.h>

#define EMBED 512
#define HEADS 8
#define DH 64
#define MM 256
#define LSEG 17
#define NPAD 4352
#define NTOK 4097
#define N0 4096
#define BATCH 4
#define CIN 1536
#define QSCALE 0.125f
#define BH 32   // BATCH*HEADS
#define NSEG 17 // key segments of 256 for a3v

typedef float fp32x4 __attribute__((ext_vector_type(4)));
typedef short bf16x8 __attribute__((ext_vector_type(8)));
typedef short bf16x4 __attribute__((ext_vector_type(4)));

__device__ __forceinline__ unsigned short f2bf(float f) {
  unsigned int u = __float_as_uint(f);
  u += 0x7fffu + ((u >> 16) & 1u);
  return (unsigned short)(u >> 16);
}

// ---------------- block reduction helpers (blockDim.x == 256) ----------------
__device__ __forceinline__ float block_sum(float v, float* red) {
  #pragma unroll
  for (int o = 1; o < 64; o <<= 1) v += __shfl_xor(v, o);
  int lane = threadIdx.x & 63, wid = threadIdx.x >> 6;
  if (lane == 0) red[wid] = v;
  __syncthreads();
  float r = red[0] + red[1] + red[2] + red[3];
  __syncthreads();
  return r;
}
__device__ __forceinline__ float block_max(float v, float* red) {
  #pragma unroll
  for (int o = 1; o < 64; o <<= 1) v = fmaxf(v, __shfl_xor(v, o));
  int lane = threadIdx.x & 63, wid = threadIdx.x >> 6;
  if (lane == 0) red[wid] = v;
  __syncthreads();
  float r = fmaxf(fmaxf(red[0], red[1]), fmaxf(red[2], red[3]));
  __syncthreads();
  return r;
}

// ------------- bf16-MFMA tiled GEMM  C = A(M,K) @ W(N,K)^T  ------------------
__global__ __launch_bounds__(256) void gemm_abt(
    const float* __restrict__ A, const float* __restrict__ W,
    int Mrows, int Ncols, int K, const float* __restrict__ bias,
    float* __restrict__ out0, float* __restrict__ out1, float* __restrict__ out2,
    int mode)
{
  __shared__ unsigned short As[64][40];
  __shared__ unsigned short Ws[64][40];
  int tid = threadIdx.x;
  int lane = tid & 63;
  int wv = tid >> 6;
  int rowBase = blockIdx.y * 64, colBase = blockIdx.x * 64;
  int quad = lane >> 4;
  int l15 = lane & 15;
  int sr = tid >> 2;
  int skc = (tid & 3) * 8;

  fp32x4 acc[4] = {fp32x4{0,0,0,0}, fp32x4{0,0,0,0}, fp32x4{0,0,0,0}, fp32x4{0,0,0,0}};

  for (int kb = 0; kb < K; kb += 32) {
    __syncthreads();
    {
      int grow = rowBase + sr;
      float va[8];
      if (grow < Mrows) {
        const float4* p = (const float4*)&A[(size_t)grow * K + kb + skc];
        float4 v0 = p[0], v1 = p[1];
        va[0]=v0.x; va[1]=v0.y; va[2]=v0.z; va[3]=v0.w;
        va[4]=v1.x; va[5]=v1.y; va[6]=v1.z; va[7]=v1.w;
      } else {
        #pragma unroll
        for (int j = 0; j < 8; j++) va[j] = 0.f;
      }
      bf16x8 pk;
      #pragma unroll
      for (int j = 0; j < 8; j++) pk[j] = (short)f2bf(va[j]);
      *(bf16x8*)&As[sr][skc] = pk;
    }
    {
      int gcol = colBase + sr;
      const float4* p = (const float4*)&W[(size_t)gcol * K + kb + skc];
      float4 v0 = p[0], v1 = p[1];
      float vb[8] = {v0.x, v0.y, v0.z, v0.w, v1.x, v1.y, v1.z, v1.w};
      bf16x8 pk;
      #pragma unroll
      for (int j = 0; j < 8; j++) pk[j] = (short)f2bf(vb[j]);
      *(bf16x8*)&Ws[sr][skc] = pk;
    }
    __syncthreads();
    bf16x8 aF = *(const bf16x8*)&As[wv * 16 + l15][quad * 8];
    #pragma unroll
    for (int ns = 0; ns < 4; ns++) {
      bf16x8 bF = *(const bf16x8*)&Ws[ns * 16 + l15][quad * 8];
      acc[ns] = __builtin_amdgcn_mfma_f32_16x16x32_bf16(aF, bF, acc[ns], 0, 0, 0);
    }
  }

  #pragma unroll
  for (int ns = 0; ns < 4; ns++) {
    int col = colBase + ns * 16 + l15;
    #pragma unroll
    for (int i = 0; i < 4; i++) {
      int row = rowBase + wv * 16 + quad * 4 + i;
      if (row >= Mrows) continue;
      float v = acc[ns][i];
      if (mode == 0) {
        v += bias[col];
        v = fmaxf(v, 0.f);
        int b = row / N0, n = row % N0;
        out0[((size_t)b * NTOK + 1 + n) * EMBED + col] = v;
      } else if (mode == 1) {
        int b = row / NPAD, n = row % NPAD;
        int sec = col / EMBED;
        int hh = (col % EMBED) / DH;
        int d = col & 63;
        float* dst = (sec == 0) ? out0 : ((sec == 1) ? out1 : out2);
        if (sec == 0) v *= QSCALE;
        dst[(((size_t)b * HEADS + hh) * NPAD + n) * DH + d] = v;
      } else {
        v += bias[col];
        out0[(size_t)row * EMBED + col] += v;
      }
    }
  }
}

// ---- bf16-MFMA batched NN GEMM:  C = gamma*(sgn*(A@B) + beta*A)  ------------
#define BSWZ(n, k) ((((k) + (((n) >> 3) & 3) * 8)) & 31)
__global__ __launch_bounds__(256) void gemm_nn_mfma(
    const float* __restrict__ A, const float* __restrict__ B, float* __restrict__ C,
    int Nsize, float beta, float sgn, float gamma, int transOut)
{
  __shared__ unsigned short As[64][40];
  __shared__ unsigned short BsT[64][40];
  int batch = blockIdx.z;
  const float* Ab = A + (size_t)batch * MM * MM;
  const float* Bb = B + (size_t)batch * MM * Nsize;
  float* Cb = C + (size_t)batch * MM * Nsize;
  int tid = threadIdx.x;
  int lane = tid & 63, wv = tid >> 6, quad = lane >> 4, l15 = lane & 15;
  int rowBase = blockIdx.y * 64, colBase = blockIdx.x * 64;
  int asr = tid >> 2, ask = (tid & 3) * 8;
  int bkr = tid >> 3;
  int bnc = (tid & 7) * 8;
  fp32x4 acc[4] = {fp32x4{0,0,0,0}, fp32x4{0,0,0,0}, fp32x4{0,0,0,0}, fp32x4{0,0,0,0}};

  for (int kb = 0; kb < MM; kb += 32) {
    __syncthreads();
    {
      const float4* p = (const float4*)&Ab[(size_t)(rowBase + asr) * MM + kb + ask];
      float4 v0 = p[0], v1 = p[1];
      float va[8] = {v0.x, v0.y, v0.z, v0.w, v1.x, v1.y, v1.z, v1.w};
      bf16x8 pk;
      #pragma unroll
      for (int j = 0; j < 8; j++) pk[j] = (short)f2bf(va[j]);
      *(bf16x8*)&As[asr][ask] = pk;
    }
    {
      const float4* p = (const float4*)&Bb[(size_t)(kb + bkr) * Nsize + colBase + bnc];
      float4 v0 = p[0], v1 = p[1];
      float vb[8] = {v0.x, v0.y, v0.z, v0.w, v1.x, v1.y, v1.z, v1.w};
      #pragma unroll
      for (int j = 0; j < 8; j++) {
        int n = bnc + j;
        BsT[n][BSWZ(n, bkr)] = f2bf(vb[j]);
      }
    }
    __syncthreads();
    bf16x8 aF = *(const bf16x8*)&As[wv * 16 + l15][quad * 8];
    #pragma unroll
    for (int ct = 0; ct < 4; ct++) {
      int n = ct * 16 + l15;
      bf16x8 bF = *(const bf16x8*)&BsT[n][BSWZ(n, quad * 8)];
      acc[ct] = __builtin_amdgcn_mfma_f32_16x16x32_bf16(aF, bF, acc[ct], 0, 0, 0);
    }
  }

  #pragma unroll
  for (int ct = 0; ct < 4; ct++) {
    int col = colBase + ct * 16 + l15;
    #pragma unroll
    for (int i = 0; i < 4; i++) {
      int row = rowBase + wv * 16 + quad * 4 + i;
      float v = sgn * acc[ct][i];
      if (beta != 0.f) v += beta * Ab[(size_t)row * MM + col];
      v *= gamma;
      if (transOut == 0) Cb[(size_t)row * Nsize + col] = v;
      else               Cb[(size_t)col * MM + row] = v;
    }
  }
}

// ---------------- small utility kernels ----------------
__global__ void cls_kernel(const float* __restrict__ cls, float* __restrict__ h) {
  int t = blockIdx.x * blockDim.x + threadIdx.x;
  if (t >= BATCH * EMBED) return;
  int b = t / EMBED, c = t % EMBED;
  h[(size_t)b * NTOK * EMBED + c] = cls[c];
}

__global__ void zero_pad_kernel(float* __restrict__ xpad) {
  int t = blockIdx.x * blockDim.x + threadIdx.x;
  const int per = 255 * EMBED;
  if (t >= BATCH * per) return;
  int b = t / per, r = t % per;
  xpad[(size_t)b * NPAD * EMBED + r] = 0.f;
}

__global__ __launch_bounds__(256) void ln_pad_kernel(
    const float* __restrict__ h, const float* __restrict__ g,
    const float* __restrict__ be, float* __restrict__ xpad)
{
  __shared__ float red[4];
  int row = blockIdx.x;
  int b = row / NTOK, j = row % NTOK;
  const float* x = h + (size_t)row * EMBED;
  int tid = threadIdx.x;
  float v0 = x[tid], v1 = x[tid + 256];
  float mu = block_sum(v0 + v1, red) * (1.f / 512.f);
  float d0 = v0 - mu, d1 = v1 - mu;
  float var = block_sum(d0 * d0 + d1 * d1, red) * (1.f / 512.f);
  float inv = 1.f / sqrtf(var + 1e-5f);
  float* o = xpad + ((size_t)b * NPAD + 255 + j) * EMBED;
  o[tid]       = d0 * inv * g[tid]       + be[tid];
  o[tid + 256] = d1 * inv * g[tid + 256] + be[tid + 256];
}

__global__ __launch_bounds__(256) void landmarks_kernel(
    const float* __restrict__ q, const float* __restrict__ k,
    float* __restrict__ qland, float* __restrict__ kland)
{
  int bh = blockIdx.y;
  int m = blockIdx.x * 4 + (threadIdx.x >> 6);
  int d = threadIdx.x & 63;
  const float* qb = q + (size_t)bh * NPAD * DH;
  const float* kb = k + (size_t)bh * NPAD * DH;
  float sq = 0.f, sk = 0.f;
  int base = m * LSEG;
  #pragma unroll
  for (int t = 0; t < LSEG; t++) {
    sq += qb[(size_t)(base + t) * DH + d];
    sk += kb[(size_t)(base + t) * DH + d];
  }
  qland[((size_t)bh * MM + m) * DH + d] = sq * (1.f / LSEG);
  kland[((size_t)bh * MM + m) * DH + d] = sk * (1.f / LSEG);
}

__global__ __launch_bounds__(256) void s2_softmax_kernel(
    const float* __restrict__ qland, const float* __restrict__ kland,
    float* __restrict__ a2)
{
  __shared__ float qrow[64];
  __shared__ float red[4];
  int bh = blockIdx.y, m = blockIdx.x, tid = threadIdx.x;
  if (tid < 64) qrow[tid] = qland[((size_t)bh * MM + m) * DH + tid];
  __syncthreads();
  const float* kb = kland + (size_t)bh * MM * DH + (size_t)tid * DH;
  float s = 0.f;
  #pragma unroll 16
  for (int d = 0; d < 64; d++) s += qrow[d] * kb[d];
  float mx = block_max(s, red);
  float e = __expf(s - mx);
  float tot = block_sum(e, red);
  a2[((size_t)bh * MM + m) * MM + tid] = e / tot;
}

__global__ void init_denom_kernel(float* __restrict__ denoms) {
  if (threadIdx.x < 2) denoms[threadIdx.x] = 0.f;
}

__global__ __launch_bounds__(256) void denom_kernel(
    const float* __restrict__ a2, float* __restrict__ denoms)
{
  __shared__ float red[4];
  int bh = blockIdx.x, tid = threadIdx.x;
  const float* A = a2 + (size_t)bh * MM * MM;
  float rs = 0.f, cs = 0.f;
  for (int j = 0; j < MM; j++) rs += A[(size_t)tid * MM + j];
  for (int i = 0; i < MM; i++) cs += A[(size_t)i * MM + tid];
  float mr = block_max(rs, red);
  float mc = block_max(cs, red);
  if (tid == 0) {
    atomicMax((int*)&denoms[0], __float_as_int(mr));
    atomicMax((int*)&denoms[1], __float_as_int(mc));
  }
}

__global__ void z0_kernel(const float* __restrict__ a2,
                          const float* __restrict__ denoms, float* __restrict__ z)
{
  int bh = blockIdx.z;
  int i = blockIdx.y * 4 + threadIdx.y;
  int j = blockIdx.x * 64 + threadIdx.x;
  float denom = denoms[0] * denoms[1];
  z[((size_t)bh * MM + i) * MM + j] = a2[((size_t)bh * MM + j) * MM + i] / denom;
}

// ---- MFMA a3@v partial flash: block = 64 landmarks x 256-key segment --------
// S = qland_tile @ k_seg^T, partial softmax vs segment max, O = P @ V_seg.
// Writes unnormalized partial O + (m, l); merged exactly by a3v_merge_kernel.
__global__ __launch_bounds__(256) void a3v_part_mfma(
    const float* __restrict__ qland, const float* __restrict__ k,
    const float* __restrict__ v, float* __restrict__ Opart,
    float* __restrict__ mpart, float* __restrict__ lpart)
{
  __shared__ __align__(16) unsigned short qs[64][40];    //  5 KB
  __shared__ __align__(16) unsigned short ks[256][72];   // 36.9 KB, reused for P[64][264]
  __shared__ __align__(16) unsigned short vt[64][72];    //  9.2 KB: V^T chunk [dh][key64]
  int tid = threadIdx.x;
  int lane = tid & 63, wv = tid >> 6, quad = lane >> 4, l15 = lane & 15;
  int bh = blockIdx.y;
  int ltile = blockIdx.x & 3;
  int seg = blockIdx.x >> 2;
  int l0 = ltile * 64;
  int key0 = seg * 256;
  const float* qb = qland + (size_t)bh * MM * DH;
  const float* kb = k + (size_t)bh * NPAD * DH;
  const float* vb = v + (size_t)bh * NPAD * DH;

  // stage qland rows l0..l0+63 bf16 (stride 40)
  {
    int sr = tid >> 2, dc = (tid & 3) * 16;
    const float4* p = (const float4*)&qb[(size_t)(l0 + sr) * DH + dc];
    float4 v0 = p[0], v1 = p[1], v2 = p[2], v3 = p[3];
    float va[16] = {v0.x,v0.y,v0.z,v0.w, v1.x,v1.y,v1.z,v1.w,
                    v2.x,v2.y,v2.z,v2.w, v3.x,v3.y,v3.z,v3.w};
    bf16x8 p0, p1;
    #pragma unroll
    for (int j = 0; j < 8; j++) { p0[j] = (short)f2bf(va[j]); p1[j] = (short)f2bf(va[8 + j]); }
    *(bf16x8*)&qs[sr][dc] = p0;
    *(bf16x8*)&qs[sr][dc + 8] = p1;
  }
  // stage k segment 256x64 bf16 (stride 72)
  #pragma unroll
  for (int i = 0; i < 16; i++) {
    int idx = i * 1024 + tid * 4;
    int r = idx >> 6, c = idx & 63;
    float4 vv = *(const float4*)&kb[(size_t)(key0 + r) * DH + c];
    bf16x4 pk = { (short)f2bf(vv.x), (short)f2bf(vv.y), (short)f2bf(vv.z), (short)f2bf(vv.w) };
    *(bf16x4*)&ks[r][c] = pk;
  }
  __syncthreads();

  // S = Q @ K^T : 64 x 256
  fp32x4 sacc[16];
  #pragma unroll
  for (int ct = 0; ct < 16; ct++) sacc[ct] = fp32x4{0,0,0,0};
  bf16x8 aF0 = *(const bf16x8*)&qs[wv * 16 + l15][quad * 8];
  bf16x8 aF1 = *(const bf16x8*)&qs[wv * 16 + l15][32 + quad * 8];
  #pragma unroll
  for (int ct = 0; ct < 16; ct++) {
    bf16x8 b0 = *(const bf16x8*)&ks[ct * 16 + l15][quad * 8];
    bf16x8 b1 = *(const bf16x8*)&ks[ct * 16 + l15][32 + quad * 8];
    sacc[ct] = __builtin_amdgcn_mfma_f32_16x16x32_bf16(aF0, b0, sacc[ct], 0, 0, 0);
    sacc[ct] = __builtin_amdgcn_mfma_f32_16x16x32_bf16(aF1, b1, sacc[ct], 0, 0, 0);
  }

  // partial softmax vs segment max (rows = quad*4+i, cols over 16 ct x l15)
  float mrow[4], lrow[4];
  #pragma unroll
  for (int i = 0; i < 4; i++) {
    float m = -3.0e38f;
    #pragma unroll
    for (int ct = 0; ct < 16; ct++) m = fmaxf(m, sacc[ct][i]);
    #pragma unroll
    for (int o = 1; o < 16; o <<= 1) m = fmaxf(m, __shfl_xor(m, o));
    float s = 0.f;
    #pragma unroll
    for (int ct = 0; ct < 16; ct++) {
      float e = __expf(sacc[ct][i] - m);
      sacc[ct][i] = e;
      s += e;
    }
    #pragma unroll
    for (int o = 1; o < 16; o <<= 1) s += __shfl_xor(s, o);
    mrow[i] = m;
    lrow[i] = s;
  }
  __syncthreads();   // done reading ks as K
  // write P (unnormalized exp <= 1, bf16) into ks region, stride 264
  unsigned short* P = &ks[0][0];
  #pragma unroll
  for (int ct = 0; ct < 16; ct++)
    #pragma unroll
    for (int i = 0; i < 4; i++)
      P[(size_t)(wv * 16 + quad * 4 + i) * 264 + ct * 16 + l15] = f2bf(sacc[ct][i]);
  __syncthreads();

  // O = P @ V : 4 chunks of 64 keys, V staged transposed
  fp32x4 oacc[4] = {fp32x4{0,0,0,0}, fp32x4{0,0,0,0}, fp32x4{0,0,0,0}, fp32x4{0,0,0,0}};
  int dh = tid & 63, kgrp = tid >> 6;
  for (int ch = 0; ch < 4; ch++) {
    if (ch) __syncthreads();
    // stage V^T chunk: thread reads 16 keys at its dh (coalesced 256B per instr)
    {
      int kbase = kgrp * 16;
      #pragma unroll
      for (int g = 0; g < 4; g++) {
        short pk[4];
        #pragma unroll
        for (int r = 0; r < 4; r++)
          pk[r] = (short)f2bf(vb[(size_t)(key0 + ch * 64 + kbase + g * 4 + r) * DH + dh]);
        *(bf16x4*)&vt[dh][kbase + g * 4] = *(bf16x4*)pk;
      }
    }
    __syncthreads();
    #pragma unroll
    for (int ks2 = 0; ks2 < 2; ks2++) {
      bf16x8 aP = *(const bf16x8*)&P[(size_t)(wv * 16 + l15) * 264 + ch * 64 + ks2 * 32 + quad * 8];
      #pragma unroll
      for (int ct = 0; ct < 4; ct++) {
        bf16x8 bV = *(const bf16x8*)&vt[ct * 16 + l15][ks2 * 32 + quad * 8];
        oacc[ct] = __builtin_amdgcn_mfma_f32_16x16x32_bf16(aP, bV, oacc[ct], 0, 0, 0);
      }
    }
  }

  size_t base = ((size_t)seg * BH + bh) * MM + l0;
  #pragma unroll
  for (int ct = 0; ct < 4; ct++)
    #pragma unroll
    for (int i = 0; i < 4; i++) {
      int row = wv * 16 + quad * 4 + i;
      Opart[(base + row) * DH + ct * 16 + l15] = oacc[ct][i];
    }
  if (l15 == 0) {
    #pragma unroll
    for (int i = 0; i < 4; i++) {
      int row = wv * 16 + quad * 4 + i;
      mpart[base + row] = mrow[i];
      lpart[base + row] = lrow[i];
    }
  }
}

__global__ __launch_bounds__(256) void a3v_merge_kernel(
    const float* __restrict__ Opart, const float* __restrict__ mpart,
    const float* __restrict__ lpart, float* __restrict__ kv)
{
  int bh = blockIdx.y;
  int lbase = blockIdx.x * 64;
  int d = threadIdx.x & 63, lsub = threadIdx.x >> 6;
  for (int li = lsub; li < 64; li += 4) {
    int lm = lbase + li;
    float M = -3.0e38f;
    #pragma unroll
    for (int s = 0; s < NSEG; s++)
      M = fmaxf(M, mpart[((size_t)s * BH + bh) * MM + lm]);
    float L = 0.f, O = 0.f;
    #pragma unroll
    for (int s = 0; s < NSEG; s++) {
      size_t idx = ((size_t)s * BH + bh) * MM + lm;
      float w = __expf(mpart[idx] - M);
      L += lpart[idx] * w;
      O += Opart[idx * DH + d] * w;
    }
    kv[((size_t)bh * MM + lm) * DH + d] = O / L;
  }
}

// ---- MFMA fused a1-softmax @ kv2T + depthwise res-conv(33): 64 rows/block ---
__global__ __launch_bounds__(256, 2) void attn1_mfma(
    const float* __restrict__ q, const float* __restrict__ kland,
    const float* __restrict__ kv2T, const float* __restrict__ v,
    const float* __restrict__ resw, float* __restrict__ attn)
{
  __shared__ __align__(16) unsigned short qs[64][40];
  __shared__ __align__(16) unsigned short klp[256][72];
  __shared__ __align__(16) unsigned short kvs[64][264];
  __shared__ float wsm[33];
  int tid = threadIdx.x;
  int lane = tid & 63, wv = tid >> 6, quad = lane >> 4, l15 = lane & 15;
  int bh = blockIdx.y, b = bh >> 3, hh = bh & 7;
  int n0 = 255 + blockIdx.x * 64;
  const float* qb  = q + (size_t)bh * NPAD * DH;
  const float* klb = kland + (size_t)bh * MM * DH;
  const float* kvb = kv2T + (size_t)bh * DH * MM;
  const float* vb  = v + (size_t)bh * NPAD * DH;
  if (tid < 33) wsm[tid] = resw[hh * 33 + tid];

  {
    int sr = tid >> 2, dc = (tid & 3) * 16;
    int g = n0 + sr; if (g > NPAD - 1) g = NPAD - 1;
    const float4* p = (const float4*)&qb[(size_t)g * DH + dc];
    float4 v0 = p[0], v1 = p[1], v2 = p[2], v3 = p[3];
    float va[16] = {v0.x,v0.y,v0.z,v0.w, v1.x,v1.y,v1.z,v1.w,
                    v2.x,v2.y,v2.z,v2.w, v3.x,v3.y,v3.z,v3.w};
    bf16x8 p0, p1;
    #pragma unroll
    for (int j = 0; j < 8; j++) { p0[j] = (short)f2bf(va[j]); p1[j] = (short)f2bf(va[8 + j]); }
    *(bf16x8*)&qs[sr][dc] = p0;
    *(bf16x8*)&qs[sr][dc + 8] = p1;
  }
  #pragma unroll
  for (int i = 0; i < 16; i++) {
    int idx = i * 1024 + tid * 4;
    int r = idx >> 6, c = idx & 63;
    float4 vv = *(const float4*)&klb[(size_t)r * DH + c];
    bf16x4 pk = { (short)f2bf(vv.x), (short)f2bf(vv.y), (short)f2bf(vv.z), (short)f2bf(vv.w) };
    *(bf16x4*)&klp[r][c] = pk;
  }
  #pragma unroll
  for (int i = 0; i < 16; i++) {
    int idx = i * 1024 + tid * 4;
    int r = idx >> 8, c = idx & 255;
    float4 vv = *(const float4*)&kvb[(size_t)r * MM + c];
    bf16x4 pk = { (short)f2bf(vv.x), (short)f2bf(vv.y), (short)f2bf(vv.z), (short)f2bf(vv.w) };
    *(bf16x4*)&kvs[r][c] = pk;
  }
  __syncthreads();

  fp32x4 sacc[16];
  #pragma unroll
  for (int ct = 0; ct < 16; ct++) sacc[ct] = fp32x4{0,0,0,0};
  bf16x8 aF0 = *(const bf16x8*)&qs[wv * 16 + l15][quad * 8];
  bf16x8 aF1 = *(const bf16x8*)&qs[wv * 16 + l15][32 + quad * 8];
  #pragma unroll
  for (int ct = 0; ct < 16; ct++) {
    bf16x8 b0 = *(const bf16x8*)&klp[ct * 16 + l15][quad * 8];
    bf16x8 b1 = *(const bf16x8*)&klp[ct * 16 + l15][32 + quad * 8];
    sacc[ct] = __builtin_amdgcn_mfma_f32_16x16x32_bf16(aF0, b0, sacc[ct], 0, 0, 0);
    sacc[ct] = __builtin_amdgcn_mfma_f32_16x16x32_bf16(aF1, b1, sacc[ct], 0, 0, 0);
  }
  #pragma unroll
  for (int i = 0; i < 4; i++) {
    float m = -3.0e38f;
    #pragma unroll
    for (int ct = 0; ct < 16; ct++) m = fmaxf(m, sacc[ct][i]);
    #pragma unroll
    for (int o = 1; o < 16; o <<= 1) m = fmaxf(m, __shfl_xor(m, o));
    float s = 0.f;
    #pragma unroll
    for (int ct = 0; ct < 16; ct++) {
      float e = __expf(sacc[ct][i] - m);
      sacc[ct][i] = e;
      s += e;
    }
    #pragma unroll
    for (int o = 1; o < 16; o <<= 1) s += __shfl_xor(s, o);
    float inv = 1.f / s;
    #pragma unroll
    for (int ct = 0; ct < 16; ct++) sacc[ct][i] *= inv;
  }
  __syncthreads();
  unsigned short* P = &klp[0][0];
  #pragma unroll
  for (int ct = 0; ct < 16; ct++)
    #pragma unroll
    for (int i = 0; i < 4; i++)
      P[(size_t)(wv * 16 + quad * 4 + i) * 264 + ct * 16 + l15] = f2bf(sacc[ct][i]);
  __syncthreads();

  fp32x4 oacc[4] = {fp32x4{0,0,0,0}, fp32x4{0,0,0,0}, fp32x4{0,0,0,0}, fp32x4{0,0,0,0}};
  #pragma unroll
  for (int ks = 0; ks < 8; ks++) {
    bf16x8 aP = *(const bf16x8*)&P[(size_t)(wv * 16 + l15) * 264 + ks * 32 + quad * 8];
    #pragma unroll
    for (int ct = 0; ct < 4; ct++) {
      bf16x8 bV = *(const bf16x8*)&kvs[ct * 16 + l15][ks * 32 + quad * 8];
      oacc[ct] = __builtin_amdgcn_mfma_f32_16x16x32_bf16(aP, bV, oacc[ct], 0, 0, 0);
    }
  }
  __syncthreads();
  float* vwin = (float*)&kvs[0][0];
  #pragma unroll
  for (int i = 0; i < 6; i++) {
    int r = i * 16 + (tid >> 4), c = (tid & 15) * 4;
    int g = n0 - 16 + r;
    float4 vv;
    if (g <= NPAD - 1) vv = *(const float4*)&vb[(size_t)g * DH + c];
    else { vv.x = 0.f; vv.y = 0.f; vv.z = 0.f; vv.w = 0.f; }
    *(float4*)&vwin[r * 68 + c] = vv;
  }
  __syncthreads();
  #pragma unroll
  for (int ct = 0; ct < 4; ct++) {
    int c = ct * 16 + l15;
    #pragma unroll
    for (int i = 0; i < 4; i++) {
      int rl = wv * 16 + quad * 4 + i;
      int n = n0 + rl;
      if (n > NPAD - 1) continue;
      float ca = 0.f;
      #pragma unroll 11
      for (int t = 0; t < 33; t++) ca += vwin[(rl + t) * 68 + c] * wsm[t];
      attn[((size_t)b * NTOK + (n - 255)) * EMBED + hh * DH + c] = oacc[ct][i] + ca;
    }
  }
}

// combine 7x7 + 5x5 + 3x3 + identity into one 7x7 depthwise kernel
__global__ void prep_wcomb_kernel(
    const float* __restrict__ pw7, const float* __restrict__ pw5,
    const float* __restrict__ pw3, const float* __restrict__ pb7,
    const float* __restrict__ pb5, const float* __restrict__ pb3,
    float* __restrict__ wcomb, float* __restrict__ biasc)
{
  int i = blockIdx.x * blockDim.x + threadIdx.x;
  if (i < EMBED * 49) {
    int c = i / 49, tap = i % 49;
    int ky = tap / 7, kx = tap % 7;
    float v = pw7[c * 49 + tap];
    if (ky >= 1 && ky <= 5 && kx >= 1 && kx <= 5) v += pw5[c * 25 + (ky - 1) * 5 + (kx - 1)];
    if (ky >= 2 && ky <= 4 && kx >= 2 && kx <= 4) v += pw3[c * 9 + (ky - 2) * 3 + (kx - 2)];
    if (ky == 3 && kx == 3) v += 1.f;
    wcomb[tap * EMBED + c] = v;
  }
  if (i < EMBED) biasc[i] = pb7[i] + pb5[i] + pb3[i];
}

__global__ void copy_feat_kernel(const float* __restrict__ h, float* __restrict__ tmp) {
  size_t t = (size_t)blockIdx.x * blockDim.x + threadIdx.x;
  if (t >= (size_t)BATCH * N0 * EMBED) return;
  size_t per = (size_t)N0 * EMBED;
  size_t b = t / per, r = t % per;
  tmp[t] = h[((size_t)b * NTOK + 1) * EMBED + r];
}

__global__ __launch_bounds__(256) void dwconv_kernel(
    const float* __restrict__ tmp, const float* __restrict__ wcomb,
    const float* __restrict__ biasc, float* __restrict__ h)
{
  __shared__ float wsm[49][64];
  int cb = blockIdx.x * 64;
  int c = cb + threadIdx.x;
  int b = blockIdx.z;
  int n = blockIdx.y * 4 + threadIdx.y;
  int y = n >> 6, x = n & 63;
  int tid = threadIdx.y * 64 + threadIdx.x;
  for (int i = tid; i < 49 * 64; i += 256) {
    int tap = i >> 6, cc = i & 63;
    wsm[tap][cc] = wcomb[tap * EMBED + cb + cc];
  }
  __syncthreads();
  const float* src = tmp + (size_t)b * N0 * EMBED;
  float acc = biasc[c];
  #pragma unroll
  for (int ky = 0; ky < 7; ky++) {
    int yy = y + ky - 3;
    if (yy < 0 || yy >= 64) continue;
    #pragma unroll
    for (int kx = 0; kx < 7; kx++) {
      int xx = x + kx - 3;
      if (xx < 0 || xx >= 64) continue;
      acc += src[((size_t)yy * 64 + xx) * EMBED + c] * wsm[ky * 7 + kx][threadIdx.x];
    }
  }
  h[((size_t)b * NTOK + 1 + n) * EMBED + c] = acc;
}

__global__ __launch_bounds__(256) void final_kernel(
    const float* __restrict__ h, const float* __restrict__ g,
    const float* __restrict__ be, const float* __restrict__ W2,
    const float* __restrict__ b2, float* __restrict__ out)
{
  __shared__ float red[4];
  int b = blockIdx.x, tid = threadIdx.x;
  const float* x = h + (size_t)b * NTOK * EMBED;
  float v0 = x[tid], v1 = x[tid + 256];
  float mu = block_sum(v0 + v1, red) * (1.f / 512.f);
  float d0 = v0 - mu, d1 = v1 - mu;
  float var = block_sum(d0 * d0 + d1 * d1, red) * (1.f / 512.f);
  float inv = 1.f / sqrtf(var + 1e-5f);
  float xn0 = d0 * inv * g[tid] + be[tid];
  float xn1 = d1 * inv * g[tid + 256] + be[tid + 256];
  float l0 = block_sum(xn0 * W2[tid] + xn1 * W2[tid + 256], red);
  float l1 = block_sum(xn0 * W2[512 + tid] + xn1 * W2[512 + tid + 256], red);
  if (tid == 0) {
    l0 += b2[0]; l1 += b2[1];
    out[b * 2 + 0] = l0;
    out[b * 2 + 1] = l1;
    float mx = fmaxf(l0, l1);
    float e0 = expf(l0 - mx), e1 = expf(l1 - mx);
    float s = e0 + e1;
    out[8 + b * 2 + 0] = e0 / s;
    out[8 + b * 2 + 1] = e1 / s;
    out[16 + b] = (l1 > l0) ? 1.f : 0.f;
  }
}

// ------------------------------- host side -----------------------------------
extern "C" void kernel_launch(void* const* d_in, const int* in_sizes, int n_in,
                              void* d_out, int out_size, void* d_ws, size_t ws_size,
                              hipStream_t stream)
{
  const float* data = (const float*)d_in[0];
  const float* W1   = (const float*)d_in[1];
  const float* b1   = (const float*)d_in[2];
  const float* cls  = (const float*)d_in[3];
  const float* lng[2]  = {(const float*)d_in[4],  (const float*)d_in[10]};
  const float* lnb[2]  = {(const float*)d_in[5],  (const float*)d_in[11]};
  const float* Wqkv[2] = {(const float*)d_in[6],  (const float*)d_in[12]};
  const float* Wo[2]   = {(const float*)d_in[7],  (const float*)d_in[13]};
  const float* bo[2]   = {(const float*)d_in[8],  (const float*)d_in[14]};
  const float* resw[2] = {(const float*)d_in[9],  (const float*)d_in[15]};
  const float* pw7 = (const float*)d_in[16];
  const float* pb7 = (const float*)d_in[17];
  const float* pw5 = (const float*)d_in[18];
  const float* pb5 = (const float*)d_in[19];
  const float* pw3 = (const float*)d_in[20];
  const float* pb3 = (const float*)d_in[21];
  const float* lnfg = (const float*)d_in[22];
  const float* lnfb = (const float*)d_in[23];
  const float* W2  = (const float*)d_in[24];
  const float* b2  = (const float*)d_in[25];

  float* ws = (float*)d_ws;
  size_t off = 0;
  auto alloc = [&](size_t n) { float* p = ws + off; off += n; return p; };
  float* hbuf  = alloc((size_t)BATCH * NTOK * EMBED);
  float* xpad  = alloc((size_t)BATCH * NPAD * EMBED);   // reused as attn_out
  float* qbuf  = alloc((size_t)BH * NPAD * DH);         // reused as conv tmp
  float* kbuf  = alloc((size_t)BH * NPAD * DH);
  float* vbuf  = alloc((size_t)BH * NPAD * DH);
  float* qland = alloc((size_t)BH * MM * DH);
  float* kland = alloc((size_t)BH * MM * DH);
  float* a2    = alloc((size_t)BH * MM * MM);
  float* za    = alloc((size_t)BH * MM * MM);
  float* zb    = alloc((size_t)BH * MM * MM);
  float* xzb   = alloc((size_t)BH * MM * MM);
  float* t1b   = alloc((size_t)BH * MM * MM);
  float* t2b   = alloc((size_t)BH * MM * MM);
  float* kvb   = alloc((size_t)BH * MM * DH);
  float* kv2b  = alloc((size_t)BH * MM * DH);           // holds kv2T [bh][64][256]
  float* wcomb = alloc(49 * EMBED);
  float* biasc = alloc(EMBED);
  float* denoms = alloc(64);
  float* mpart = alloc((size_t)NSEG * BH * MM);
  float* lpart = alloc((size_t)NSEG * BH * MM);
  float* attn = xpad;
  float* Opart = za;   // overlay: a3v partials in za..t2b (8.9M < 10.5M floats)

  gemm_abt<<<dim3(EMBED / 64, (BATCH * N0) / 64), 256, 0, stream>>>(
      data, W1, BATCH * N0, EMBED, CIN, b1, hbuf, nullptr, nullptr, 0);
  cls_kernel<<<dim3((BATCH * EMBED + 255) / 256), 256, 0, stream>>>(cls, hbuf);

  for (int layer = 0; layer < 2; layer++) {
    ln_pad_kernel<<<dim3(BATCH * NTOK), 256, 0, stream>>>(hbuf, lng[layer], lnb[layer], xpad);
    zero_pad_kernel<<<dim3((BATCH * 255 * EMBED + 255) / 256), 256, 0, stream>>>(xpad);
    gemm_abt<<<dim3((3 * EMBED) / 64, (BATCH * NPAD) / 64), 256, 0, stream>>>(
        xpad, Wqkv[layer], BATCH * NPAD, 3 * EMBED, EMBED, nullptr, qbuf, kbuf, vbuf, 1);
    landmarks_kernel<<<dim3(MM / 4, BH), 256, 0, stream>>>(qbuf, kbuf, qland, kland);
    s2_softmax_kernel<<<dim3(MM, BH), 256, 0, stream>>>(qland, kland, a2);
    init_denom_kernel<<<1, 64, 0, stream>>>(denoms);
    denom_kernel<<<dim3(BH), 256, 0, stream>>>(a2, denoms);

    // a3@v before pinv so Opart can overlay the pinv scratch
    a3v_part_mfma<<<dim3(4 * NSEG, BH), 256, 0, stream>>>(
        qland, kbuf, vbuf, Opart, mpart, lpart);
    a3v_merge_kernel<<<dim3(MM / 64, BH), 256, 0, stream>>>(Opart, mpart, lpart, kvb);

    z0_kernel<<<dim3(MM / 64, MM / 4, BH), dim3(64, 4), 0, stream>>>(a2, denoms, za);
    float* zin = za;
    float* zout = zb;
    for (int it = 0; it < 6; it++) {
      gemm_nn_mfma<<<dim3(4, 4, BH), 256, 0, stream>>>(a2, zin, xzb, MM, 0.f, 1.f, 1.f, 0);
      gemm_nn_mfma<<<dim3(4, 4, BH), 256, 0, stream>>>(xzb, xzb, t1b, MM, 7.f, -1.f, 1.f, 0);
      gemm_nn_mfma<<<dim3(4, 4, BH), 256, 0, stream>>>(xzb, t1b, t2b, MM, 15.f, -1.f, 1.f, 0);
      gemm_nn_mfma<<<dim3(4, 4, BH), 256, 0, stream>>>(zin, t2b, zout, MM, 13.f, -1.f, 0.25f, 0);
      float* t = zin; zin = zout; zout = t;
    }
    gemm_nn_mfma<<<dim3(1, 4, BH), 256, 0, stream>>>(zin, kvb, kv2b, DH, 0.f, 1.f, 1.f, 1);
    attn1_mfma<<<dim3((NTOK + 63) / 64, BH), 256, 0, stream>>>(
        qbuf, kland, kv2b, vbuf, resw[layer], attn);
    gemm_abt<<<dim3(EMBED / 64, (BATCH * NTOK + 63) / 64), 256, 0, stream>>>(
        attn, Wo[layer], BATCH * NTOK, EMBED, EMBED, bo[layer], hbuf, nullptr, nullptr, 2);

    if (layer == 0) {
      prep_wcomb_kernel<<<dim3((EMBED * 49 + 255) / 256), 256, 0, stream>>>(
          pw7, pw5, pw3, pb7, pb5, pb3, wcomb, biasc);
      copy_feat_kernel<<<dim3((unsigned)(((size_t)BATCH * N0 * EMBED + 255) / 256)), 256, 0, stream>>>(hbuf, qbuf);
      dwconv_kernel<<<dim3(EMBED / 64, N0 / 4, BATCH), dim3(64, 4), 0, stream>>>(qbuf, wcomb, biasc, hbuf);
    }
  }

  final_kernel<<<dim3(BATCH), 256, 0, stream>>>(hbuf, lnfg, lnfb, W2, b2, (float*)d_out);
}

// Round 6
// 1703.022 us; speedup vs baseline: 7.2995x; 1.2293x over previous
//
#include <hip/hip_runtime.h>
#include <math.h>

#define EMBED 512
#define HEADS 8
#define DH 64
#define MM 256
#define LSEG 17
#define NPAD 4352
#define NTOK 4097
#define N0 4096
#define BATCH 4
#define CIN 1536
#define QSCALE 0.125f
#define BH 32   // BATCH*HEADS
#define NSEG 17 // key segments of 256 for a3v

typedef float fp32x4 __attribute__((ext_vector_type(4)));
typedef short bf16x8 __attribute__((ext_vector_type(8)));
typedef short bf16x4 __attribute__((ext_vector_type(4)));
typedef unsigned short ushort_t;

__device__ __forceinline__ unsigned short f2bf(float f) {
  unsigned int u = __float_as_uint(f);
  u += 0x7fffu + ((u >> 16) & 1u);
  return (unsigned short)(u >> 16);
}
__device__ __forceinline__ float bf2f(unsigned short u) {
  return __uint_as_float((unsigned)u << 16);
}

// ---------------- block reduction helpers (blockDim.x == 256) ----------------
__device__ __forceinline__ float block_sum(float v, float* red) {
  #pragma unroll
  for (int o = 1; o < 64; o <<= 1) v += __shfl_xor(v, o);
  int lane = threadIdx.x & 63, wid = threadIdx.x >> 6;
  if (lane == 0) red[wid] = v;
  __syncthreads();
  float r = red[0] + red[1] + red[2] + red[3];
  __syncthreads();
  return r;
}
__device__ __forceinline__ float block_max(float v, float* red) {
  #pragma unroll
  for (int o = 1; o < 64; o <<= 1) v = fmaxf(v, __shfl_xor(v, o));
  int lane = threadIdx.x & 63, wid = threadIdx.x >> 6;
  if (lane == 0) red[wid] = v;
  __syncthreads();
  float r = fmaxf(fmaxf(red[0], red[1]), fmaxf(red[2], red[3]));
  __syncthreads();
  return r;
}

// ------------- bf16-MFMA tiled GEMM  C = A(M,K) @ W(N,K)^T  ------------------
// mode 0: relu(acc+bias) -> h scatter; mode 1: qkv scatter; mode 2: residual add
// mode 3: residual add + copy (minus cls row) to out1 (conv tmp)
__global__ __launch_bounds__(256) void gemm_abt(
    const float* __restrict__ A, const float* __restrict__ W,
    int Mrows, int Ncols, int K, const float* __restrict__ bias,
    float* __restrict__ out0, float* __restrict__ out1, float* __restrict__ out2,
    int mode)
{
  __shared__ unsigned short As[64][40];
  __shared__ unsigned short Ws[64][40];
  int tid = threadIdx.x;
  int lane = tid & 63;
  int wv = tid >> 6;
  int rowBase = blockIdx.y * 64, colBase = blockIdx.x * 64;
  int quad = lane >> 4;
  int l15 = lane & 15;
  int sr = tid >> 2;
  int skc = (tid & 3) * 8;

  fp32x4 acc[4] = {fp32x4{0,0,0,0}, fp32x4{0,0,0,0}, fp32x4{0,0,0,0}, fp32x4{0,0,0,0}};

  for (int kb = 0; kb < K; kb += 32) {
    __syncthreads();
    {
      int grow = rowBase + sr;
      float va[8];
      if (grow < Mrows) {
        const float4* p = (const float4*)&A[(size_t)grow * K + kb + skc];
        float4 v0 = p[0], v1 = p[1];
        va[0]=v0.x; va[1]=v0.y; va[2]=v0.z; va[3]=v0.w;
        va[4]=v1.x; va[5]=v1.y; va[6]=v1.z; va[7]=v1.w;
      } else {
        #pragma unroll
        for (int j = 0; j < 8; j++) va[j] = 0.f;
      }
      bf16x8 pk;
      #pragma unroll
      for (int j = 0; j < 8; j++) pk[j] = (short)f2bf(va[j]);
      *(bf16x8*)&As[sr][skc] = pk;
    }
    {
      int gcol = colBase + sr;
      const float4* p = (const float4*)&W[(size_t)gcol * K + kb + skc];
      float4 v0 = p[0], v1 = p[1];
      float vb[8] = {v0.x, v0.y, v0.z, v0.w, v1.x, v1.y, v1.z, v1.w};
      bf16x8 pk;
      #pragma unroll
      for (int j = 0; j < 8; j++) pk[j] = (short)f2bf(vb[j]);
      *(bf16x8*)&Ws[sr][skc] = pk;
    }
    __syncthreads();
    bf16x8 aF = *(const bf16x8*)&As[wv * 16 + l15][quad * 8];
    #pragma unroll
    for (int ns = 0; ns < 4; ns++) {
      bf16x8 bF = *(const bf16x8*)&Ws[ns * 16 + l15][quad * 8];
      acc[ns] = __builtin_amdgcn_mfma_f32_16x16x32_bf16(aF, bF, acc[ns], 0, 0, 0);
    }
  }

  #pragma unroll
  for (int ns = 0; ns < 4; ns++) {
    int col = colBase + ns * 16 + l15;
    #pragma unroll
    for (int i = 0; i < 4; i++) {
      int row = rowBase + wv * 16 + quad * 4 + i;
      if (row >= Mrows) continue;
      float v = acc[ns][i];
      if (mode == 0) {
        v += bias[col];
        v = fmaxf(v, 0.f);
        int b = row / N0, n = row % N0;
        out0[((size_t)b * NTOK + 1 + n) * EMBED + col] = v;
      } else if (mode == 1) {
        int b = row / NPAD, n = row % NPAD;
        int sec = col / EMBED;
        int hh = (col % EMBED) / DH;
        int d = col & 63;
        float* dst = (sec == 0) ? out0 : ((sec == 1) ? out1 : out2);
        if (sec == 0) v *= QSCALE;
        dst[(((size_t)b * HEADS + hh) * NPAD + n) * DH + d] = v;
      } else if (mode == 2) {
        v += bias[col];
        out0[(size_t)row * EMBED + col] += v;
      } else {
        v += bias[col];
        float full = out0[(size_t)row * EMBED + col] + v;
        out0[(size_t)row * EMBED + col] = full;
        int b = row / NTOK, t = row % NTOK;
        if (t > 0) out1[((size_t)b * N0 + (t - 1)) * EMBED + col] = full;
      }
    }
  }
}

// ---- bf16-storage batched NN GEMM:  C = gamma*(sgn*(A@B) + beta*A) ----------
// A: (batch,256,256) bf16  B: (batch,256,Nsize) bf16  C bf16 (opt transposed)
#define BSWZ(n, k) ((((k) + (((n) >> 3) & 3) * 8)) & 31)
__global__ __launch_bounds__(256) void gemm_nn_bf16(
    const unsigned short* __restrict__ A, const unsigned short* __restrict__ B,
    unsigned short* __restrict__ C,
    int Nsize, float beta, float sgn, float gamma, int transOut)
{
  __shared__ unsigned short As[64][40];
  __shared__ unsigned short BsT[64][40];
  int batch = blockIdx.z;
  const unsigned short* Ab = A + (size_t)batch * MM * MM;
  const unsigned short* Bb = B + (size_t)batch * MM * Nsize;
  unsigned short* Cb = C + (size_t)batch * MM * Nsize;
  int tid = threadIdx.x;
  int lane = tid & 63, wv = tid >> 6, quad = lane >> 4, l15 = lane & 15;
  int rowBase = blockIdx.y * 64, colBase = blockIdx.x * 64;
  int asr = tid >> 2, ask = (tid & 3) * 8;
  int bkr = tid >> 3;
  int bnc = (tid & 7) * 8;
  fp32x4 acc[4] = {fp32x4{0,0,0,0}, fp32x4{0,0,0,0}, fp32x4{0,0,0,0}, fp32x4{0,0,0,0}};

  for (int kb = 0; kb < MM; kb += 32) {
    __syncthreads();
    *(bf16x8*)&As[asr][ask] =
        *(const bf16x8*)&Ab[(size_t)(rowBase + asr) * MM + kb + ask];
    {
      bf16x8 vb = *(const bf16x8*)&Bb[(size_t)(kb + bkr) * Nsize + colBase + bnc];
      #pragma unroll
      for (int j = 0; j < 8; j++) {
        int n = bnc + j;
        BsT[n][BSWZ(n, bkr)] = (unsigned short)vb[j];
      }
    }
    __syncthreads();
    bf16x8 aF = *(const bf16x8*)&As[wv * 16 + l15][quad * 8];
    #pragma unroll
    for (int ct = 0; ct < 4; ct++) {
      int n = ct * 16 + l15;
      bf16x8 bF = *(const bf16x8*)&BsT[n][BSWZ(n, quad * 8)];
      acc[ct] = __builtin_amdgcn_mfma_f32_16x16x32_bf16(aF, bF, acc[ct], 0, 0, 0);
    }
  }

  #pragma unroll
  for (int ct = 0; ct < 4; ct++) {
    int col = colBase + ct * 16 + l15;
    #pragma unroll
    for (int i = 0; i < 4; i++) {
      int row = rowBase + wv * 16 + quad * 4 + i;
      float v = sgn * acc[ct][i];
      if (beta != 0.f) v += beta * bf2f(Ab[(size_t)row * MM + col]);
      v *= gamma;
      if (transOut == 0) Cb[(size_t)row * Nsize + col] = f2bf(v);
      else               Cb[(size_t)col * MM + row] = f2bf(v);
    }
  }
}

// ---------------- small utility kernels ----------------
__global__ void cls_kernel(const float* __restrict__ cls, float* __restrict__ h) {
  int t = blockIdx.x * blockDim.x + threadIdx.x;
  if (t >= BATCH * EMBED) return;
  int b = t / EMBED, c = t % EMBED;
  h[(size_t)b * NTOK * EMBED + c] = cls[c];
}

__global__ void zero_pad_kernel(float* __restrict__ xpad) {
  int t = blockIdx.x * blockDim.x + threadIdx.x;
  const int per = 255 * EMBED;
  if (t >= BATCH * per) return;
  int b = t / per, r = t % per;
  xpad[(size_t)b * NPAD * EMBED + r] = 0.f;
}

__global__ __launch_bounds__(256) void ln_pad_kernel(
    const float* __restrict__ h, const float* __restrict__ g,
    const float* __restrict__ be, float* __restrict__ xpad)
{
  __shared__ float red[4];
  int row = blockIdx.x;
  int b = row / NTOK, j = row % NTOK;
  const float* x = h + (size_t)row * EMBED;
  int tid = threadIdx.x;
  float v0 = x[tid], v1 = x[tid + 256];
  float mu = block_sum(v0 + v1, red) * (1.f / 512.f);
  float d0 = v0 - mu, d1 = v1 - mu;
  float var = block_sum(d0 * d0 + d1 * d1, red) * (1.f / 512.f);
  float inv = 1.f / sqrtf(var + 1e-5f);
  float* o = xpad + ((size_t)b * NPAD + 255 + j) * EMBED;
  o[tid]       = d0 * inv * g[tid]       + be[tid];
  o[tid + 256] = d1 * inv * g[tid + 256] + be[tid + 256];
}

__global__ __launch_bounds__(256) void landmarks_kernel(
    const float* __restrict__ q, const float* __restrict__ k,
    float* __restrict__ qland, float* __restrict__ kland)
{
  int bh = blockIdx.y;
  int m = blockIdx.x * 4 + (threadIdx.x >> 6);
  int d = threadIdx.x & 63;
  const float* qb = q + (size_t)bh * NPAD * DH;
  const float* kb = k + (size_t)bh * NPAD * DH;
  float sq = 0.f, sk = 0.f;
  int base = m * LSEG;
  #pragma unroll
  for (int t = 0; t < LSEG; t++) {
    sq += qb[(size_t)(base + t) * DH + d];
    sk += kb[(size_t)(base + t) * DH + d];
  }
  qland[((size_t)bh * MM + m) * DH + d] = sq * (1.f / LSEG);
  kland[((size_t)bh * MM + m) * DH + d] = sk * (1.f / LSEG);
}

// a2 written as bf16
__global__ __launch_bounds__(256) void s2_softmax_kernel(
    const float* __restrict__ qland, const float* __restrict__ kland,
    unsigned short* __restrict__ a2)
{
  __shared__ float qrow[64];
  __shared__ float red[4];
  int bh = blockIdx.y, m = blockIdx.x, tid = threadIdx.x;
  if (tid < 64) qrow[tid] = qland[((size_t)bh * MM + m) * DH + tid];
  __syncthreads();
  const float* kb = kland + (size_t)bh * MM * DH + (size_t)tid * DH;
  float s = 0.f;
  #pragma unroll 16
  for (int d = 0; d < 64; d++) s += qrow[d] * kb[d];
  float mx = block_max(s, red);
  float e = __expf(s - mx);
  float tot = block_sum(e, red);
  a2[((size_t)bh * MM + m) * MM + tid] = f2bf(e / tot);
}

__global__ void init_denom_kernel(float* __restrict__ denoms) {
  if (threadIdx.x < 2) denoms[threadIdx.x] = 0.f;
}

__global__ __launch_bounds__(256) void denom_kernel(
    const unsigned short* __restrict__ a2, float* __restrict__ denoms)
{
  __shared__ float red[4];
  int bh = blockIdx.x, tid = threadIdx.x;
  const unsigned short* A = a2 + (size_t)bh * MM * MM;
  float rs = 0.f, cs = 0.f;
  for (int j = 0; j < MM; j++) rs += bf2f(A[(size_t)tid * MM + j]);
  for (int i = 0; i < MM; i++) cs += bf2f(A[(size_t)i * MM + tid]);
  float mr = block_max(rs, red);
  float mc = block_max(cs, red);
  if (tid == 0) {
    atomicMax((int*)&denoms[0], __float_as_int(mr));
    atomicMax((int*)&denoms[1], __float_as_int(mc));
  }
}

__global__ void z0_kernel(const unsigned short* __restrict__ a2,
                          const float* __restrict__ denoms,
                          unsigned short* __restrict__ z)
{
  int bh = blockIdx.z;
  int i = blockIdx.y * 4 + threadIdx.y;
  int j = blockIdx.x * 64 + threadIdx.x;
  float denom = denoms[0] * denoms[1];
  z[((size_t)bh * MM + i) * MM + j] = f2bf(bf2f(a2[((size_t)bh * MM + j) * MM + i]) / denom);
}

// ---- MFMA a3@v partial flash: block = 64 landmarks x 256-key segment --------
__global__ __launch_bounds__(256) void a3v_part_mfma(
    const float* __restrict__ qland, const float* __restrict__ k,
    const float* __restrict__ v, float* __restrict__ Opart,
    float* __restrict__ mpart, float* __restrict__ lpart)
{
  __shared__ __align__(16) unsigned short qs[64][40];
  __shared__ __align__(16) unsigned short ks[256][72];   // reused for P[64][264]
  __shared__ __align__(16) unsigned short vt[64][72];
  int tid = threadIdx.x;
  int lane = tid & 63, wv = tid >> 6, quad = lane >> 4, l15 = lane & 15;
  int bh = blockIdx.y;
  int ltile = blockIdx.x & 3;
  int seg = blockIdx.x >> 2;
  int l0 = ltile * 64;
  int key0 = seg * 256;
  const float* qb = qland + (size_t)bh * MM * DH;
  const float* kb = k + (size_t)bh * NPAD * DH;
  const float* vb = v + (size_t)bh * NPAD * DH;

  {
    int sr = tid >> 2, dc = (tid & 3) * 16;
    const float4* p = (const float4*)&qb[(size_t)(l0 + sr) * DH + dc];
    float4 v0 = p[0], v1 = p[1], v2 = p[2], v3 = p[3];
    float va[16] = {v0.x,v0.y,v0.z,v0.w, v1.x,v1.y,v1.z,v1.w,
                    v2.x,v2.y,v2.z,v2.w, v3.x,v3.y,v3.z,v3.w};
    bf16x8 p0, p1;
    #pragma unroll
    for (int j = 0; j < 8; j++) { p0[j] = (short)f2bf(va[j]); p1[j] = (short)f2bf(va[8 + j]); }
    *(bf16x8*)&qs[sr][dc] = p0;
    *(bf16x8*)&qs[sr][dc + 8] = p1;
  }
  #pragma unroll
  for (int i = 0; i < 16; i++) {
    int idx = i * 1024 + tid * 4;
    int r = idx >> 6, c = idx & 63;
    float4 vv = *(const float4*)&kb[(size_t)(key0 + r) * DH + c];
    bf16x4 pk = { (short)f2bf(vv.x), (short)f2bf(vv.y), (short)f2bf(vv.z), (short)f2bf(vv.w) };
    *(bf16x4*)&ks[r][c] = pk;
  }
  __syncthreads();

  fp32x4 sacc[16];
  #pragma unroll
  for (int ct = 0; ct < 16; ct++) sacc[ct] = fp32x4{0,0,0,0};
  bf16x8 aF0 = *(const bf16x8*)&qs[wv * 16 + l15][quad * 8];
  bf16x8 aF1 = *(const bf16x8*)&qs[wv * 16 + l15][32 + quad * 8];
  #pragma unroll
  for (int ct = 0; ct < 16; ct++) {
    bf16x8 b0 = *(const bf16x8*)&ks[ct * 16 + l15][quad * 8];
    bf16x8 b1 = *(const bf16x8*)&ks[ct * 16 + l15][32 + quad * 8];
    sacc[ct] = __builtin_amdgcn_mfma_f32_16x16x32_bf16(aF0, b0, sacc[ct], 0, 0, 0);
    sacc[ct] = __builtin_amdgcn_mfma_f32_16x16x32_bf16(aF1, b1, sacc[ct], 0, 0, 0);
  }

  float mrow[4], lrow[4];
  #pragma unroll
  for (int i = 0; i < 4; i++) {
    float m = -3.0e38f;
    #pragma unroll
    for (int ct = 0; ct < 16; ct++) m = fmaxf(m, sacc[ct][i]);
    #pragma unroll
    for (int o = 1; o < 16; o <<= 1) m = fmaxf(m, __shfl_xor(m, o));
    float s = 0.f;
    #pragma unroll
    for (int ct = 0; ct < 16; ct++) {
      float e = __expf(sacc[ct][i] - m);
      sacc[ct][i] = e;
      s += e;
    }
    #pragma unroll
    for (int o = 1; o < 16; o <<= 1) s += __shfl_xor(s, o);
    mrow[i] = m;
    lrow[i] = s;
  }
  __syncthreads();
  unsigned short* P = &ks[0][0];
  #pragma unroll
  for (int ct = 0; ct < 16; ct++)
    #pragma unroll
    for (int i = 0; i < 4; i++)
      P[(size_t)(wv * 16 + quad * 4 + i) * 264 + ct * 16 + l15] = f2bf(sacc[ct][i]);
  __syncthreads();

  fp32x4 oacc[4] = {fp32x4{0,0,0,0}, fp32x4{0,0,0,0}, fp32x4{0,0,0,0}, fp32x4{0,0,0,0}};
  int dh = tid & 63, kgrp = tid >> 6;
  for (int ch = 0; ch < 4; ch++) {
    if (ch) __syncthreads();
    {
      int kbase = kgrp * 16;
      #pragma unroll
      for (int g = 0; g < 4; g++) {
        short pk[4];
        #pragma unroll
        for (int r = 0; r < 4; r++)
          pk[r] = (short)f2bf(vb[(size_t)(key0 + ch * 64 + kbase + g * 4 + r) * DH + dh]);
        *(bf16x4*)&vt[dh][kbase + g * 4] = *(bf16x4*)pk;
      }
    }
    __syncthreads();
    #pragma unroll
    for (int ks2 = 0; ks2 < 2; ks2++) {
      bf16x8 aP = *(const bf16x8*)&P[(size_t)(wv * 16 + l15) * 264 + ch * 64 + ks2 * 32 + quad * 8];
      #pragma unroll
      for (int ct = 0; ct < 4; ct++) {
        bf16x8 bV = *(const bf16x8*)&vt[ct * 16 + l15][ks2 * 32 + quad * 8];
        oacc[ct] = __builtin_amdgcn_mfma_f32_16x16x32_bf16(aP, bV, oacc[ct], 0, 0, 0);
      }
    }
  }

  size_t base = ((size_t)seg * BH + bh) * MM + l0;
  #pragma unroll
  for (int ct = 0; ct < 4; ct++)
    #pragma unroll
    for (int i = 0; i < 4; i++) {
      int row = wv * 16 + quad * 4 + i;
      Opart[(base + row) * DH + ct * 16 + l15] = oacc[ct][i];
    }
  if (l15 == 0) {
    #pragma unroll
    for (int i = 0; i < 4; i++) {
      int row = wv * 16 + quad * 4 + i;
      mpart[base + row] = mrow[i];
      lpart[base + row] = lrow[i];
    }
  }
}

// merge -> kv in bf16
__global__ __launch_bounds__(256) void a3v_merge_kernel(
    const float* __restrict__ Opart, const float* __restrict__ mpart,
    const float* __restrict__ lpart, unsigned short* __restrict__ kv)
{
  int bh = blockIdx.y;
  int lbase = blockIdx.x * 64;
  int d = threadIdx.x & 63, lsub = threadIdx.x >> 6;
  for (int li = lsub; li < 64; li += 4) {
    int lm = lbase + li;
    float M = -3.0e38f;
    #pragma unroll
    for (int s = 0; s < NSEG; s++)
      M = fmaxf(M, mpart[((size_t)s * BH + bh) * MM + lm]);
    float L = 0.f, O = 0.f;
    #pragma unroll
    for (int s = 0; s < NSEG; s++) {
      size_t idx = ((size_t)s * BH + bh) * MM + lm;
      float w = __expf(mpart[idx] - M);
      L += lpart[idx] * w;
      O += Opart[idx * DH + d] * w;
    }
    kv[((size_t)bh * MM + lm) * DH + d] = f2bf(O / L);
  }
}

// ---- MFMA fused a1-softmax @ kv2T(bf16) + res-conv(33): 64 rows/block -------
__global__ __launch_bounds__(256, 2) void attn1_mfma(
    const float* __restrict__ q, const float* __restrict__ kland,
    const unsigned short* __restrict__ kv2T, const float* __restrict__ v,
    const float* __restrict__ resw, float* __restrict__ attn)
{
  __shared__ __align__(16) unsigned short qs[64][40];
  __shared__ __align__(16) unsigned short klp[256][72];
  __shared__ __align__(16) unsigned short kvs[64][264];
  __shared__ float wsm[33];
  int tid = threadIdx.x;
  int lane = tid & 63, wv = tid >> 6, quad = lane >> 4, l15 = lane & 15;
  int bh = blockIdx.y, b = bh >> 3, hh = bh & 7;
  int n0 = 255 + blockIdx.x * 64;
  const float* qb  = q + (size_t)bh * NPAD * DH;
  const float* klb = kland + (size_t)bh * MM * DH;
  const unsigned short* kvb = kv2T + (size_t)bh * DH * MM;
  const float* vb  = v + (size_t)bh * NPAD * DH;
  if (tid < 33) wsm[tid] = resw[hh * 33 + tid];

  {
    int sr = tid >> 2, dc = (tid & 3) * 16;
    int g = n0 + sr; if (g > NPAD - 1) g = NPAD - 1;
    const float4* p = (const float4*)&qb[(size_t)g * DH + dc];
    float4 v0 = p[0], v1 = p[1], v2 = p[2], v3 = p[3];
    float va[16] = {v0.x,v0.y,v0.z,v0.w, v1.x,v1.y,v1.z,v1.w,
                    v2.x,v2.y,v2.z,v2.w, v3.x,v3.y,v3.z,v3.w};
    bf16x8 p0, p1;
    #pragma unroll
    for (int j = 0; j < 8; j++) { p0[j] = (short)f2bf(va[j]); p1[j] = (short)f2bf(va[8 + j]); }
    *(bf16x8*)&qs[sr][dc] = p0;
    *(bf16x8*)&qs[sr][dc + 8] = p1;
  }
  #pragma unroll
  for (int i = 0; i < 16; i++) {
    int idx = i * 1024 + tid * 4;
    int r = idx >> 6, c = idx & 63;
    float4 vv = *(const float4*)&klb[(size_t)r * DH + c];
    bf16x4 pk = { (short)f2bf(vv.x), (short)f2bf(vv.y), (short)f2bf(vv.z), (short)f2bf(vv.w) };
    *(bf16x4*)&klp[r][c] = pk;
  }
  #pragma unroll
  for (int i = 0; i < 8; i++) {
    int idx = i * 2048 + tid * 8;
    int r = idx >> 8, c = idx & 255;
    *(bf16x8*)&kvs[r][c] = *(const bf16x8*)&kvb[(size_t)r * MM + c];
  }
  __syncthreads();

  fp32x4 sacc[16];
  #pragma unroll
  for (int ct = 0; ct < 16; ct++) sacc[ct] = fp32x4{0,0,0,0};
  bf16x8 aF0 = *(const bf16x8*)&qs[wv * 16 + l15][quad * 8];
  bf16x8 aF1 = *(const bf16x8*)&qs[wv * 16 + l15][32 + quad * 8];
  #pragma unroll
  for (int ct = 0; ct < 16; ct++) {
    bf16x8 b0 = *(const bf16x8*)&klp[ct * 16 + l15][quad * 8];
    bf16x8 b1 = *(const bf16x8*)&klp[ct * 16 + l15][32 + quad * 8];
    sacc[ct] = __builtin_amdgcn_mfma_f32_16x16x32_bf16(aF0, b0, sacc[ct], 0, 0, 0);
    sacc[ct] = __builtin_amdgcn_mfma_f32_16x16x32_bf16(aF1, b1, sacc[ct], 0, 0, 0);
  }
  #pragma unroll
  for (int i = 0; i < 4; i++) {
    float m = -3.0e38f;
    #pragma unroll
    for (int ct = 0; ct < 16; ct++) m = fmaxf(m, sacc[ct][i]);
    #pragma unroll
    for (int o = 1; o < 16; o <<= 1) m = fmaxf(m, __shfl_xor(m, o));
    float s = 0.f;
    #pragma unroll
    for (int ct = 0; ct < 16; ct++) {
      float e = __expf(sacc[ct][i] - m);
      sacc[ct][i] = e;
      s += e;
    }
    #pragma unroll
    for (int o = 1; o < 16; o <<= 1) s += __shfl_xor(s, o);
    float inv = 1.f / s;
    #pragma unroll
    for (int ct = 0; ct < 16; ct++) sacc[ct][i] *= inv;
  }
  __syncthreads();
  unsigned short* P = &klp[0][0];
  #pragma unroll
  for (int ct = 0; ct < 16; ct++)
    #pragma unroll
    for (int i = 0; i < 4; i++)
      P[(size_t)(wv * 16 + quad * 4 + i) * 264 + ct * 16 + l15] = f2bf(sacc[ct][i]);
  __syncthreads();

  fp32x4 oacc[4] = {fp32x4{0,0,0,0}, fp32x4{0,0,0,0}, fp32x4{0,0,0,0}, fp32x4{0,0,0,0}};
  #pragma unroll
  for (int ks = 0; ks < 8; ks++) {
    bf16x8 aP = *(const bf16x8*)&P[(size_t)(wv * 16 + l15) * 264 + ks * 32 + quad * 8];
    #pragma unroll
    for (int ct = 0; ct < 4; ct++) {
      bf16x8 bV = *(const bf16x8*)&kvs[ct * 16 + l15][ks * 32 + quad * 8];
      oacc[ct] = __builtin_amdgcn_mfma_f32_16x16x32_bf16(aP, bV, oacc[ct], 0, 0, 0);
    }
  }
  __syncthreads();
  float* vwin = (float*)&kvs[0][0];
  #pragma unroll
  for (int i = 0; i < 6; i++) {
    int r = i * 16 + (tid >> 4), c = (tid & 15) * 4;
    int g = n0 - 16 + r;
    float4 vv;
    if (g <= NPAD - 1) vv = *(const float4*)&vb[(size_t)g * DH + c];
    else { vv.x = 0.f; vv.y = 0.f; vv.z = 0.f; vv.w = 0.f; }
    *(float4*)&vwin[r * 68 + c] = vv;
  }
  __syncthreads();
  #pragma unroll
  for (int ct = 0; ct < 4; ct++) {
    int c = ct * 16 + l15;
    #pragma unroll
    for (int i = 0; i < 4; i++) {
      int rl = wv * 16 + quad * 4 + i;
      int n = n0 + rl;
      if (n > NPAD - 1) continue;
      float ca = 0.f;
      #pragma unroll 11
      for (int t = 0; t < 33; t++) ca += vwin[(rl + t) * 68 + c] * wsm[t];
      attn[((size_t)b * NTOK + (n - 255)) * EMBED + hh * DH + c] = oacc[ct][i] + ca;
    }
  }
}

// combine 7x7 + 5x5 + 3x3 + identity into one 7x7 depthwise kernel
__global__ void prep_wcomb_kernel(
    const float* __restrict__ pw7, const float* __restrict__ pw5,
    const float* __restrict__ pw3, const float* __restrict__ pb7,
    const float* __restrict__ pb5, const float* __restrict__ pb3,
    float* __restrict__ wcomb, float* __restrict__ biasc)
{
  int i = blockIdx.x * blockDim.x + threadIdx.x;
  if (i < EMBED * 49) {
    int c = i / 49, tap = i % 49;
    int ky = tap / 7, kx = tap % 7;
    float v = pw7[c * 49 + tap];
    if (ky >= 1 && ky <= 5 && kx >= 1 && kx <= 5) v += pw5[c * 25 + (ky - 1) * 5 + (kx - 1)];
    if (ky >= 2 && ky <= 4 && kx >= 2 && kx <= 4) v += pw3[c * 9 + (ky - 2) * 3 + (kx - 2)];
    if (ky == 3 && kx == 3) v += 1.f;
    wcomb[tap * EMBED + c] = v;
  }
  if (i < EMBED) biasc[i] = pb7[i] + pb5[i] + pb3[i];
}

// float4-per-thread depthwise conv: block (32,8) = 128 ch x 8 positions
__global__ __launch_bounds__(256) void dwconv_kernel(
    const float* __restrict__ tmp, const float* __restrict__ wcomb,
    const float* __restrict__ biasc, float* __restrict__ h)
{
  __shared__ float4 wsm[49][32];
  int tx = threadIdx.x;    // channel group 0..31
  int ty = threadIdx.y;    // position 0..7
  int cb = blockIdx.x * 128;
  int c = cb + tx * 4;
  int b = blockIdx.z;
  int n = blockIdx.y * 8 + ty;
  int y = n >> 6, x = n & 63;
  int tid = ty * 32 + tx;
  for (int i = tid; i < 49 * 32; i += 256) {
    int tap = i >> 5, g = i & 31;
    wsm[tap][g] = *(const float4*)&wcomb[tap * EMBED + cb + g * 4];
  }
  __syncthreads();
  const float* src = tmp + (size_t)b * N0 * EMBED;
  float4 acc = *(const float4*)&biasc[c];
  #pragma unroll
  for (int ky = 0; ky < 7; ky++) {
    int yy = y + ky - 3;
    if (yy < 0 || yy >= 64) continue;
    #pragma unroll
    for (int kx = 0; kx < 7; kx++) {
      int xx = x + kx - 3;
      if (xx < 0 || xx >= 64) continue;
      float4 vv = *(const float4*)&src[((size_t)yy * 64 + xx) * EMBED + c];
      float4 w = wsm[ky * 7 + kx][tx];
      acc.x += vv.x * w.x;
      acc.y += vv.y * w.y;
      acc.z += vv.z * w.z;
      acc.w += vv.w * w.w;
    }
  }
  *(float4*)&h[((size_t)b * NTOK + 1 + n) * EMBED + c] = acc;
}

__global__ __launch_bounds__(256) void final_kernel(
    const float* __restrict__ h, const float* __restrict__ g,
    const float* __restrict__ be, const float* __restrict__ W2,
    const float* __restrict__ b2, float* __restrict__ out)
{
  __shared__ float red[4];
  int b = blockIdx.x, tid = threadIdx.x;
  const float* x = h + (size_t)b * NTOK * EMBED;
  float v0 = x[tid], v1 = x[tid + 256];
  float mu = block_sum(v0 + v1, red) * (1.f / 512.f);
  float d0 = v0 - mu, d1 = v1 - mu;
  float var = block_sum(d0 * d0 + d1 * d1, red) * (1.f / 512.f);
  float inv = 1.f / sqrtf(var + 1e-5f);
  float xn0 = d0 * inv * g[tid] + be[tid];
  float xn1 = d1 * inv * g[tid + 256] + be[tid + 256];
  float l0 = block_sum(xn0 * W2[tid] + xn1 * W2[tid + 256], red);
  float l1 = block_sum(xn0 * W2[512 + tid] + xn1 * W2[512 + tid + 256], red);
  if (tid == 0) {
    l0 += b2[0]; l1 += b2[1];
    out[b * 2 + 0] = l0;
    out[b * 2 + 1] = l1;
    float mx = fmaxf(l0, l1);
    float e0 = expf(l0 - mx), e1 = expf(l1 - mx);
    float s = e0 + e1;
    out[8 + b * 2 + 0] = e0 / s;
    out[8 + b * 2 + 1] = e1 / s;
    out[16 + b] = (l1 > l0) ? 1.f : 0.f;
  }
}

// ------------------------------- host side -----------------------------------
extern "C" void kernel_launch(void* const* d_in, const int* in_sizes, int n_in,
                              void* d_out, int out_size, void* d_ws, size_t ws_size,
                              hipStream_t stream)
{
  const float* data = (const float*)d_in[0];
  const float* W1   = (const float*)d_in[1];
  const float* b1   = (const float*)d_in[2];
  const float* cls  = (const float*)d_in[3];
  const float* lng[2]  = {(const float*)d_in[4],  (const float*)d_in[10]};
  const float* lnb[2]  = {(const float*)d_in[5],  (const float*)d_in[11]};
  const float* Wqkv[2] = {(const float*)d_in[6],  (const float*)d_in[12]};
  const float* Wo[2]   = {(const float*)d_in[7],  (const float*)d_in[13]};
  const float* bo[2]   = {(const float*)d_in[8],  (const float*)d_in[14]};
  const float* resw[2] = {(const float*)d_in[9],  (const float*)d_in[15]};
  const float* pw7 = (const float*)d_in[16];
  const float* pb7 = (const float*)d_in[17];
  const float* pw5 = (const float*)d_in[18];
  const float* pb5 = (const float*)d_in[19];
  const float* pw3 = (const float*)d_in[20];
  const float* pb3 = (const float*)d_in[21];
  const float* lnfg = (const float*)d_in[22];
  const float* lnfb = (const float*)d_in[23];
  const float* W2  = (const float*)d_in[24];
  const float* b2  = (const float*)d_in[25];

  float* ws = (float*)d_ws;
  size_t off = 0;
  auto alloc = [&](size_t n) { float* p = ws + off; off += n; return p; };
  float* hbuf  = alloc((size_t)BATCH * NTOK * EMBED);
  float* xpad  = alloc((size_t)BATCH * NPAD * EMBED);   // reused as attn_out
  float* qbuf  = alloc((size_t)BH * NPAD * DH);         // reused as conv tmp
  float* kbuf  = alloc((size_t)BH * NPAD * DH);
  float* vbuf  = alloc((size_t)BH * NPAD * DH);
  float* qland = alloc((size_t)BH * MM * DH);
  float* kland = alloc((size_t)BH * MM * DH);
  float* a2f   = alloc((size_t)BH * MM * MM);   // used as bf16 (half occupied)
  float* za    = alloc((size_t)BH * MM * MM);
  float* zb    = alloc((size_t)BH * MM * MM);
  float* xzb   = alloc((size_t)BH * MM * MM);
  float* t1b   = alloc((size_t)BH * MM * MM);
  float* t2b   = alloc((size_t)BH * MM * MM);
  float* kvb   = alloc((size_t)BH * MM * DH);
  float* kv2b  = alloc((size_t)BH * MM * DH);
  float* wcomb = alloc(49 * EMBED);
  float* biasc = alloc(EMBED);
  float* denoms = alloc(64);
  float* mpart = alloc((size_t)NSEG * BH * MM);
  float* lpart = alloc((size_t)NSEG * BH * MM);
  float* attn = xpad;
  float* Opart = za;   // overlay: a3v partials in za..t2b (consumed before z0)

  unsigned short* a2B  = (unsigned short*)a2f;
  unsigned short* zaB  = (unsigned short*)za;
  unsigned short* zbB  = (unsigned short*)zb;
  unsigned short* xzB  = (unsigned short*)xzb;
  unsigned short* t1B  = (unsigned short*)t1b;
  unsigned short* t2B  = (unsigned short*)t2b;
  unsigned short* kvB  = (unsigned short*)kvb;
  unsigned short* kv2B = (unsigned short*)kv2b;

  gemm_abt<<<dim3(EMBED / 64, (BATCH * N0) / 64), 256, 0, stream>>>(
      data, W1, BATCH * N0, EMBED, CIN, b1, hbuf, nullptr, nullptr, 0);
  cls_kernel<<<dim3((BATCH * EMBED + 255) / 256), 256, 0, stream>>>(cls, hbuf);

  for (int layer = 0; layer < 2; layer++) {
    ln_pad_kernel<<<dim3(BATCH * NTOK), 256, 0, stream>>>(hbuf, lng[layer], lnb[layer], xpad);
    zero_pad_kernel<<<dim3((BATCH * 255 * EMBED + 255) / 256), 256, 0, stream>>>(xpad);
    gemm_abt<<<dim3((3 * EMBED) / 64, (BATCH * NPAD) / 64), 256, 0, stream>>>(
        xpad, Wqkv[layer], BATCH * NPAD, 3 * EMBED, EMBED, nullptr, qbuf, kbuf, vbuf, 1);
    landmarks_kernel<<<dim3(MM / 4, BH), 256, 0, stream>>>(qbuf, kbuf, qland, kland);
    s2_softmax_kernel<<<dim3(MM, BH), 256, 0, stream>>>(qland, kland, a2B);
    init_denom_kernel<<<1, 64, 0, stream>>>(denoms);
    denom_kernel<<<dim3(BH), 256, 0, stream>>>(a2B, denoms);

    // a3@v before pinv so Opart can overlay the pinv scratch
    a3v_part_mfma<<<dim3(4 * NSEG, BH), 256, 0, stream>>>(
        qland, kbuf, vbuf, Opart, mpart, lpart);
    a3v_merge_kernel<<<dim3(MM / 64, BH), 256, 0, stream>>>(Opart, mpart, lpart, kvB);

    z0_kernel<<<dim3(MM / 64, MM / 4, BH), dim3(64, 4), 0, stream>>>(a2B, denoms, zaB);
    unsigned short* zin = zaB;
    unsigned short* zout = zbB;
    for (int it = 0; it < 6; it++) {
      gemm_nn_bf16<<<dim3(4, 4, BH), 256, 0, stream>>>(a2B, zin, xzB, MM, 0.f, 1.f, 1.f, 0);
      gemm_nn_bf16<<<dim3(4, 4, BH), 256, 0, stream>>>(xzB, xzB, t1B, MM, 7.f, -1.f, 1.f, 0);
      gemm_nn_bf16<<<dim3(4, 4, BH), 256, 0, stream>>>(xzB, t1B, t2B, MM, 15.f, -1.f, 1.f, 0);
      gemm_nn_bf16<<<dim3(4, 4, BH), 256, 0, stream>>>(zin, t2B, zout, MM, 13.f, -1.f, 0.25f, 0);
      unsigned short* t = zin; zin = zout; zout = t;
    }
    gemm_nn_bf16<<<dim3(1, 4, BH), 256, 0, stream>>>(zin, kvB, kv2B, DH, 0.f, 1.f, 1.f, 1);
    attn1_mfma<<<dim3((NTOK + 63) / 64, BH), 256, 0, stream>>>(
        qbuf, kland, kv2B, vbuf, resw[layer], attn);
    gemm_abt<<<dim3(EMBED / 64, (BATCH * NTOK + 63) / 64), 256, 0, stream>>>(
        attn, Wo[layer], BATCH * NTOK, EMBED, EMBED, bo[layer], hbuf,
        (layer == 0) ? qbuf : nullptr, nullptr, (layer == 0) ? 3 : 2);

    if (layer == 0) {
      prep_wcomb_kernel<<<dim3((EMBED * 49 + 255) / 256), 256, 0, stream>>>(
          pw7, pw5, pw3, pb7, pb5, pb3, wcomb, biasc);
      dwconv_kernel<<<dim3(EMBED / 128, N0 / 8, BATCH), dim3(32, 8), 0, stream>>>(
          qbuf, wcomb, biasc, hbuf);
    }
  }

  final_kernel<<<dim3(BATCH), 256, 0, stream>>>(hbuf, lnfg, lnfb, W2, b2, (float*)d_out);
}

// Round 7
// 1588.919 us; speedup vs baseline: 7.8237x; 1.0718x over previous
//
#include <hip/hip_runtime.h>
#include <math.h>

#define EMBED 512
#define HEADS 8
#define DH 64
#define MM 256
#define LSEG 17
#define NPAD 4352
#define NTOK 4097
#define N0 4096
#define BATCH 4
#define CIN 1536
#define QSCALE 0.125f
#define BH 32   // BATCH*HEADS
#define NSEG 17 // key segments of 256 for a3v

typedef float fp32x4 __attribute__((ext_vector_type(4)));
typedef short bf16x8 __attribute__((ext_vector_type(8)));
typedef short bf16x4 __attribute__((ext_vector_type(4)));
typedef unsigned short u16;

__device__ __forceinline__ unsigned short f2bf(float f) {
  unsigned int u = __float_as_uint(f);
  u += 0x7fffu + ((u >> 16) & 1u);
  return (unsigned short)(u >> 16);
}
__device__ __forceinline__ float bf2f(unsigned short u) {
  return __uint_as_float((unsigned)u << 16);
}

// ---------------- block reduction helpers (blockDim.x == 256) ----------------
__device__ __forceinline__ float block_sum(float v, float* red) {
  #pragma unroll
  for (int o = 1; o < 64; o <<= 1) v += __shfl_xor(v, o);
  int lane = threadIdx.x & 63, wid = threadIdx.x >> 6;
  if (lane == 0) red[wid] = v;
  __syncthreads();
  float r = red[0] + red[1] + red[2] + red[3];
  __syncthreads();
  return r;
}
__device__ __forceinline__ float block_max(float v, float* red) {
  #pragma unroll
  for (int o = 1; o < 64; o <<= 1) v = fmaxf(v, __shfl_xor(v, o));
  int lane = threadIdx.x & 63, wid = threadIdx.x >> 6;
  if (lane == 0) red[wid] = v;
  __syncthreads();
  float r = fmaxf(fmaxf(red[0], red[1]), fmaxf(red[2], red[3]));
  __syncthreads();
  return r;
}

// fp32 -> bf16 convert (n multiple of 8)
__global__ void f2bf_kernel(const float* __restrict__ in, u16* __restrict__ out, int n) {
  int t = (blockIdx.x * 256 + threadIdx.x) * 8;
  if (t >= n) return;
  float4 a = *(const float4*)&in[t];
  float4 b = *(const float4*)&in[t + 4];
  bf16x8 pk;
  pk[0]=(short)f2bf(a.x); pk[1]=(short)f2bf(a.y); pk[2]=(short)f2bf(a.z); pk[3]=(short)f2bf(a.w);
  pk[4]=(short)f2bf(b.x); pk[5]=(short)f2bf(b.y); pk[6]=(short)f2bf(b.z); pk[7]=(short)f2bf(b.w);
  *(bf16x8*)&out[t] = pk;
}

// ------- bf16-MFMA GEMM  C = A(M,K)bf16 @ W(N,K)bf16^T,  64x128 tile --------
// mode 0: relu(acc+bias) -> hbuf fp32 scatter
// mode 1: qkv scatter -> q/k/v bf16
// mode 2: fout += acc+bias (residual)
// mode 3: mode2 + copy full rows (minus cls) to fout2 (conv tmp fp32)
__global__ __launch_bounds__(256) void gemm_abt(
    const u16* __restrict__ A, const u16* __restrict__ W,
    int Mrows, int Ncols, int K, const float* __restrict__ bias,
    float* __restrict__ fout, float* __restrict__ fout2,
    u16* __restrict__ uo0, u16* __restrict__ uo1, u16* __restrict__ uo2,
    int mode)
{
  __shared__ u16 As[64][40];
  __shared__ u16 Ws[128][40];
  int tid = threadIdx.x;
  int lane = tid & 63;
  int wv = tid >> 6;
  int rowBase = blockIdx.y * 64, colBase = blockIdx.x * 128;
  int quad = lane >> 4;
  int l15 = lane & 15;
  int sr = tid >> 2;
  int skc = (tid & 3) * 8;

  fp32x4 acc[8];
  #pragma unroll
  for (int i = 0; i < 8; i++) acc[i] = fp32x4{0,0,0,0};

  for (int kb = 0; kb < K; kb += 32) {
    __syncthreads();
    {
      int grow = rowBase + sr;
      bf16x8 av;
      if (grow < Mrows) av = *(const bf16x8*)&A[(size_t)grow * K + kb + skc];
      else { bf16x8 z = {0,0,0,0,0,0,0,0}; av = z; }
      *(bf16x8*)&As[sr][skc] = av;
    }
    #pragma unroll
    for (int h = 0; h < 2; h++) {
      int r = sr + h * 64;
      *(bf16x8*)&Ws[r][skc] =
          *(const bf16x8*)&W[(size_t)(colBase + r) * K + kb + skc];
    }
    __syncthreads();
    bf16x8 aF = *(const bf16x8*)&As[wv * 16 + l15][quad * 8];
    #pragma unroll
    for (int ct = 0; ct < 8; ct++) {
      bf16x8 bF = *(const bf16x8*)&Ws[ct * 16 + l15][quad * 8];
      acc[ct] = __builtin_amdgcn_mfma_f32_16x16x32_bf16(aF, bF, acc[ct], 0, 0, 0);
    }
  }

  #pragma unroll
  for (int ct = 0; ct < 8; ct++) {
    int col = colBase + ct * 16 + l15;
    #pragma unroll
    for (int i = 0; i < 4; i++) {
      int row = rowBase + wv * 16 + quad * 4 + i;
      if (row >= Mrows) continue;
      float v = acc[ct][i];
      if (mode == 0) {
        v += bias[col];
        v = fmaxf(v, 0.f);
        int b = row / N0, n = row % N0;
        fout[((size_t)b * NTOK + 1 + n) * EMBED + col] = v;
      } else if (mode == 1) {
        int b = row / NPAD, n = row % NPAD;
        int sec = col / EMBED;
        int hh = (col % EMBED) / DH;
        int d = col & 63;
        u16* dst = (sec == 0) ? uo0 : ((sec == 1) ? uo1 : uo2);
        if (sec == 0) v *= QSCALE;
        dst[(((size_t)b * HEADS + hh) * NPAD + n) * DH + d] = f2bf(v);
      } else if (mode == 2) {
        v += bias[col];
        fout[(size_t)row * EMBED + col] += v;
      } else {
        v += bias[col];
        float full = fout[(size_t)row * EMBED + col] + v;
        fout[(size_t)row * EMBED + col] = full;
        int b = row / NTOK, t = row % NTOK;
        if (t > 0) fout2[((size_t)b * N0 + (t - 1)) * EMBED + col] = full;
      }
    }
  }
}

// ---- pinv GEMM (dual-layout bf16): C = gamma*(sgn*(A@B) + beta*A) ----------
// A: [batch][256][K=256] row-major. Bc: [batch][Nsize][256] = B^T row-major.
// Cr (row-major [256][Nsize]) and/or Cc (col-major [Nsize][256]) outputs.
__global__ __launch_bounds__(256) void gemm_nn2(
    const u16* __restrict__ A, const u16* __restrict__ Bc,
    u16* __restrict__ Cr, u16* __restrict__ Cc,
    int Nsize, float beta, float sgn, float gamma)
{
  __shared__ u16 As[64][40];
  __shared__ u16 Bs[64][40];
  int batch = blockIdx.z;
  const u16* Ab = A + (size_t)batch * MM * MM;
  const u16* Bb = Bc + (size_t)batch * MM * Nsize;
  int tid = threadIdx.x;
  int lane = tid & 63, wv = tid >> 6, quad = lane >> 4, l15 = lane & 15;
  int rowBase = blockIdx.y * 64, colBase = blockIdx.x * 64;
  int sr = tid >> 2, skc = (tid & 3) * 8;
  fp32x4 acc[4] = {fp32x4{0,0,0,0}, fp32x4{0,0,0,0}, fp32x4{0,0,0,0}, fp32x4{0,0,0,0}};

  for (int kb = 0; kb < MM; kb += 32) {
    __syncthreads();
    *(bf16x8*)&As[sr][skc] = *(const bf16x8*)&Ab[(size_t)(rowBase + sr) * MM + kb + skc];
    *(bf16x8*)&Bs[sr][skc] = *(const bf16x8*)&Bb[(size_t)(colBase + sr) * MM + kb + skc];
    __syncthreads();
    bf16x8 aF = *(const bf16x8*)&As[wv * 16 + l15][quad * 8];
    #pragma unroll
    for (int ct = 0; ct < 4; ct++) {
      bf16x8 bF = *(const bf16x8*)&Bs[ct * 16 + l15][quad * 8];
      acc[ct] = __builtin_amdgcn_mfma_f32_16x16x32_bf16(aF, bF, acc[ct], 0, 0, 0);
    }
  }

  #pragma unroll
  for (int ct = 0; ct < 4; ct++) {
    int col = colBase + ct * 16 + l15;
    #pragma unroll
    for (int i = 0; i < 4; i++) {
      int row = rowBase + wv * 16 + quad * 4 + i;
      float v = sgn * acc[ct][i];
      if (beta != 0.f) v += beta * bf2f(Ab[(size_t)row * MM + col]);
      v *= gamma;
      u16 o = f2bf(v);
      if (Cr) Cr[(size_t)batch * MM * Nsize + (size_t)row * Nsize + col] = o;
      if (Cc) Cc[(size_t)batch * MM * Nsize + (size_t)col * MM + row] = o;
    }
  }
}

// ---------------- small utility kernels ----------------
__global__ void cls_kernel(const float* __restrict__ cls, float* __restrict__ h) {
  int t = blockIdx.x * blockDim.x + threadIdx.x;
  if (t >= BATCH * EMBED) return;
  int b = t / EMBED, c = t % EMBED;
  h[(size_t)b * NTOK * EMBED + c] = cls[c];
}

__global__ void zero_pad_kernel(u16* __restrict__ xpad) {
  int t = blockIdx.x * blockDim.x + threadIdx.x;
  const int per = 255 * EMBED;
  if (t >= BATCH * per) return;
  int b = t / per, r = t % per;
  xpad[(size_t)b * NPAD * EMBED + r] = 0;
}

// LN -> bf16 padded
__global__ __launch_bounds__(256) void ln_pad_kernel(
    const float* __restrict__ h, const float* __restrict__ g,
    const float* __restrict__ be, u16* __restrict__ xpad)
{
  __shared__ float red[4];
  int row = blockIdx.x;
  int b = row / NTOK, j = row % NTOK;
  const float* x = h + (size_t)row * EMBED;
  int tid = threadIdx.x;
  float v0 = x[tid], v1 = x[tid + 256];
  float mu = block_sum(v0 + v1, red) * (1.f / 512.f);
  float d0 = v0 - mu, d1 = v1 - mu;
  float var = block_sum(d0 * d0 + d1 * d1, red) * (1.f / 512.f);
  float inv = 1.f / sqrtf(var + 1e-5f);
  u16* o = xpad + ((size_t)b * NPAD + 255 + j) * EMBED;
  o[tid]       = f2bf(d0 * inv * g[tid]       + be[tid]);
  o[tid + 256] = f2bf(d1 * inv * g[tid + 256] + be[tid + 256]);
}

__global__ __launch_bounds__(256) void landmarks_kernel(
    const u16* __restrict__ q, const u16* __restrict__ k,
    float* __restrict__ qland, float* __restrict__ kland)
{
  int bh = blockIdx.y;
  int m = blockIdx.x * 4 + (threadIdx.x >> 6);
  int d = threadIdx.x & 63;
  const u16* qb = q + (size_t)bh * NPAD * DH;
  const u16* kb = k + (size_t)bh * NPAD * DH;
  float sq = 0.f, sk = 0.f;
  int base = m * LSEG;
  #pragma unroll
  for (int t = 0; t < LSEG; t++) {
    sq += bf2f(qb[(size_t)(base + t) * DH + d]);
    sk += bf2f(kb[(size_t)(base + t) * DH + d]);
  }
  qland[((size_t)bh * MM + m) * DH + d] = sq * (1.f / LSEG);
  kland[((size_t)bh * MM + m) * DH + d] = sk * (1.f / LSEG);
}

__global__ __launch_bounds__(256) void s2_softmax_kernel(
    const float* __restrict__ qland, const float* __restrict__ kland,
    u16* __restrict__ a2)
{
  __shared__ float qrow[64];
  __shared__ float red[4];
  int bh = blockIdx.y, m = blockIdx.x, tid = threadIdx.x;
  if (tid < 64) qrow[tid] = qland[((size_t)bh * MM + m) * DH + tid];
  __syncthreads();
  const float* kb = kland + (size_t)bh * MM * DH + (size_t)tid * DH;
  float s = 0.f;
  #pragma unroll 16
  for (int d = 0; d < 64; d++) s += qrow[d] * kb[d];
  float mx = block_max(s, red);
  float e = __expf(s - mx);
  float tot = block_sum(e, red);
  a2[((size_t)bh * MM + m) * MM + tid] = f2bf(e / tot);
}

__global__ void init_denom_kernel(float* __restrict__ denoms) {
  if (threadIdx.x < 2) denoms[threadIdx.x] = 0.f;
}

__global__ __launch_bounds__(256) void denom_kernel(
    const u16* __restrict__ a2, float* __restrict__ denoms)
{
  __shared__ float red[4];
  int bh = blockIdx.x, tid = threadIdx.x;
  const u16* A = a2 + (size_t)bh * MM * MM;
  float rs = 0.f, cs = 0.f;
  for (int j = 0; j < MM; j++) rs += bf2f(A[(size_t)tid * MM + j]);
  for (int i = 0; i < MM; i++) cs += bf2f(A[(size_t)i * MM + tid]);
  float mr = block_max(rs, red);
  float mc = block_max(cs, red);
  if (tid == 0) {
    atomicMax((int*)&denoms[0], __float_as_int(mr));
    atomicMax((int*)&denoms[1], __float_as_int(mc));
  }
}

// z0: zr = a2^T/denom (row-major), zc = a2/denom (= z^T row-major)
__global__ __launch_bounds__(256) void z0_trans_kernel(
    const u16* __restrict__ a2, const float* __restrict__ denoms,
    u16* __restrict__ zr, u16* __restrict__ zc)
{
  __shared__ u16 tile[64][72];
  int bh = blockIdx.z, i0 = blockIdx.y * 64, j0 = blockIdx.x * 64;
  int tid = threadIdx.x;
  float inv = 1.f / (denoms[0] * denoms[1]);
  const u16* Ab = a2 + (size_t)bh * MM * MM;
  #pragma unroll
  for (int it = 0; it < 4; it++) {
    int idx = it * 1024 + tid * 4;
    int r = idx >> 6, c = idx & 63;
    bf16x4 v = *(const bf16x4*)&Ab[(size_t)(i0 + r) * MM + j0 + c];
    u16 o[4];
    #pragma unroll
    for (int j = 0; j < 4; j++) o[j] = f2bf(bf2f((unsigned short)v[j]) * inv);
    *(bf16x4*)&zc[(size_t)bh * MM * MM + (size_t)(i0 + r) * MM + j0 + c] = *(bf16x4*)o;
    #pragma unroll
    for (int j = 0; j < 4; j++) tile[c + j][r] = o[j];
  }
  __syncthreads();
  #pragma unroll
  for (int it = 0; it < 4; it++) {
    int idx = it * 1024 + tid * 4;
    int r = idx >> 6, c = idx & 63;
    u16 o[4] = {tile[r][c], tile[r][c + 1], tile[r][c + 2], tile[r][c + 3]};
    *(bf16x4*)&zr[(size_t)bh * MM * MM + (size_t)(j0 + r) * MM + i0 + c] = *(bf16x4*)o;
  }
}

// ---- MFMA a3@v partial flash: block = 64 landmarks x 256-key segment --------
__global__ __launch_bounds__(256) void a3v_part_mfma(
    const float* __restrict__ qland, const u16* __restrict__ k,
    const u16* __restrict__ v, u16* __restrict__ Opart,
    float* __restrict__ mpart, float* __restrict__ lpart)
{
  __shared__ __align__(16) u16 qs[64][40];
  __shared__ __align__(16) u16 ks[256][72];   // reused for P[64][264]
  __shared__ __align__(16) u16 vt[64][72];
  int tid = threadIdx.x;
  int lane = tid & 63, wv = tid >> 6, quad = lane >> 4, l15 = lane & 15;
  int bh = blockIdx.y;
  int ltile = blockIdx.x & 3;
  int seg = blockIdx.x >> 2;
  int l0 = ltile * 64;
  int key0 = seg * 256;
  const float* qb = qland + (size_t)bh * MM * DH;
  const u16* kb = k + (size_t)bh * NPAD * DH;
  const u16* vb = v + (size_t)bh * NPAD * DH;

  {
    int sr = tid >> 2, dc = (tid & 3) * 16;
    const float4* p = (const float4*)&qb[(size_t)(l0 + sr) * DH + dc];
    float4 v0 = p[0], v1 = p[1], v2 = p[2], v3 = p[3];
    float va[16] = {v0.x,v0.y,v0.z,v0.w, v1.x,v1.y,v1.z,v1.w,
                    v2.x,v2.y,v2.z,v2.w, v3.x,v3.y,v3.z,v3.w};
    bf16x8 p0, p1;
    #pragma unroll
    for (int j = 0; j < 8; j++) { p0[j] = (short)f2bf(va[j]); p1[j] = (short)f2bf(va[8 + j]); }
    *(bf16x8*)&qs[sr][dc] = p0;
    *(bf16x8*)&qs[sr][dc + 8] = p1;
  }
  #pragma unroll
  for (int i = 0; i < 16; i++) {
    int idx = i * 1024 + tid * 4;
    int r = idx >> 6, c = idx & 63;
    *(bf16x4*)&ks[r][c] = *(const bf16x4*)&kb[(size_t)(key0 + r) * DH + c];
  }
  __syncthreads();

  fp32x4 sacc[16];
  #pragma unroll
  for (int ct = 0; ct < 16; ct++) sacc[ct] = fp32x4{0,0,0,0};
  bf16x8 aF0 = *(const bf16x8*)&qs[wv * 16 + l15][quad * 8];
  bf16x8 aF1 = *(const bf16x8*)&qs[wv * 16 + l15][32 + quad * 8];
  #pragma unroll
  for (int ct = 0; ct < 16; ct++) {
    bf16x8 b0 = *(const bf16x8*)&ks[ct * 16 + l15][quad * 8];
    bf16x8 b1 = *(const bf16x8*)&ks[ct * 16 + l15][32 + quad * 8];
    sacc[ct] = __builtin_amdgcn_mfma_f32_16x16x32_bf16(aF0, b0, sacc[ct], 0, 0, 0);
    sacc[ct] = __builtin_amdgcn_mfma_f32_16x16x32_bf16(aF1, b1, sacc[ct], 0, 0, 0);
  }

  float mrow[4], lrow[4];
  #pragma unroll
  for (int i = 0; i < 4; i++) {
    float m = -3.0e38f;
    #pragma unroll
    for (int ct = 0; ct < 16; ct++) m = fmaxf(m, sacc[ct][i]);
    #pragma unroll
    for (int o = 1; o < 16; o <<= 1) m = fmaxf(m, __shfl_xor(m, o));
    float s = 0.f;
    #pragma unroll
    for (int ct = 0; ct < 16; ct++) {
      float e = __expf(sacc[ct][i] - m);
      sacc[ct][i] = e;
      s += e;
    }
    #pragma unroll
    for (int o = 1; o < 16; o <<= 1) s += __shfl_xor(s, o);
    mrow[i] = m;
    lrow[i] = s;
  }
  __syncthreads();
  u16* P = &ks[0][0];
  #pragma unroll
  for (int ct = 0; ct < 16; ct++)
    #pragma unroll
    for (int i = 0; i < 4; i++)
      P[(size_t)(wv * 16 + quad * 4 + i) * 264 + ct * 16 + l15] = f2bf(sacc[ct][i]);
  __syncthreads();

  fp32x4 oacc[4] = {fp32x4{0,0,0,0}, fp32x4{0,0,0,0}, fp32x4{0,0,0,0}, fp32x4{0,0,0,0}};
  int dh = tid & 63, kgrp = tid >> 6;
  for (int ch = 0; ch < 4; ch++) {
    if (ch) __syncthreads();
    {
      int kbase = kgrp * 16;
      #pragma unroll
      for (int g = 0; g < 4; g++) {
        u16 pk[4];
        #pragma unroll
        for (int r = 0; r < 4; r++)
          pk[r] = vb[(size_t)(key0 + ch * 64 + kbase + g * 4 + r) * DH + dh];
        *(bf16x4*)&vt[dh][kbase + g * 4] = *(bf16x4*)pk;
      }
    }
    __syncthreads();
    #pragma unroll
    for (int ks2 = 0; ks2 < 2; ks2++) {
      bf16x8 aP = *(const bf16x8*)&P[(size_t)(wv * 16 + l15) * 264 + ch * 64 + ks2 * 32 + quad * 8];
      #pragma unroll
      for (int ct = 0; ct < 4; ct++) {
        bf16x8 bV = *(const bf16x8*)&vt[ct * 16 + l15][ks2 * 32 + quad * 8];
        oacc[ct] = __builtin_amdgcn_mfma_f32_16x16x32_bf16(aP, bV, oacc[ct], 0, 0, 0);
      }
    }
  }

  size_t base = ((size_t)seg * BH + bh) * MM + l0;
  #pragma unroll
  for (int ct = 0; ct < 4; ct++)
    #pragma unroll
    for (int i = 0; i < 4; i++) {
      int row = wv * 16 + quad * 4 + i;
      Opart[(base + row) * DH + ct * 16 + l15] = f2bf(oacc[ct][i]);
    }
  if (l15 == 0) {
    #pragma unroll
    for (int i = 0; i < 4; i++) {
      int row = wv * 16 + quad * 4 + i;
      mpart[base + row] = mrow[i];
      lpart[base + row] = lrow[i];
    }
  }
}

// merge partials -> kv^T (col-major for the z@kv GEMM's B operand)
__global__ __launch_bounds__(256) void a3v_merge_kernel(
    const u16* __restrict__ Opart, const float* __restrict__ mpart,
    const float* __restrict__ lpart, u16* __restrict__ kvT)
{
  int bh = blockIdx.y;
  int lbase = blockIdx.x * 64;
  int d = threadIdx.x & 63, lsub = threadIdx.x >> 6;
  for (int li = lsub; li < 64; li += 4) {
    int lm = lbase + li;
    float M = -3.0e38f;
    #pragma unroll
    for (int s = 0; s < NSEG; s++)
      M = fmaxf(M, mpart[((size_t)s * BH + bh) * MM + lm]);
    float L = 0.f, O = 0.f;
    #pragma unroll
    for (int s = 0; s < NSEG; s++) {
      size_t idx = ((size_t)s * BH + bh) * MM + lm;
      float w = __expf(mpart[idx] - M);
      L += lpart[idx] * w;
      O += bf2f(Opart[idx * DH + d]) * w;
    }
    kvT[((size_t)bh * DH + d) * MM + lm] = f2bf(O / L);
  }
}

// ---- MFMA fused a1-softmax @ kv2T + res-conv(33): 64 rows/block -------------
__global__ __launch_bounds__(256, 2) void attn1_mfma(
    const u16* __restrict__ q, const float* __restrict__ kland,
    const u16* __restrict__ kv2T, const u16* __restrict__ v,
    const float* __restrict__ resw, u16* __restrict__ attn)
{
  __shared__ __align__(16) u16 qs[64][40];
  __shared__ __align__(16) u16 klp[256][72];
  __shared__ __align__(16) u16 kvs[64][264];
  __shared__ float wsm[33];
  int tid = threadIdx.x;
  int lane = tid & 63, wv = tid >> 6, quad = lane >> 4, l15 = lane & 15;
  int bh = blockIdx.y, b = bh >> 3, hh = bh & 7;
  int n0 = 255 + blockIdx.x * 64;
  const u16* qb  = q + (size_t)bh * NPAD * DH;
  const float* klb = kland + (size_t)bh * MM * DH;
  const u16* kvb = kv2T + (size_t)bh * DH * MM;
  const u16* vb  = v + (size_t)bh * NPAD * DH;
  if (tid < 33) wsm[tid] = resw[hh * 33 + tid];

  {
    int sr = tid >> 2, dc = (tid & 3) * 16;
    int g = n0 + sr; if (g > NPAD - 1) g = NPAD - 1;
    *(bf16x8*)&qs[sr][dc]     = *(const bf16x8*)&qb[(size_t)g * DH + dc];
    *(bf16x8*)&qs[sr][dc + 8] = *(const bf16x8*)&qb[(size_t)g * DH + dc + 8];
  }
  #pragma unroll
  for (int i = 0; i < 16; i++) {
    int idx = i * 1024 + tid * 4;
    int r = idx >> 6, c = idx & 63;
    float4 vv = *(const float4*)&klb[(size_t)r * DH + c];
    bf16x4 pk = { (short)f2bf(vv.x), (short)f2bf(vv.y), (short)f2bf(vv.z), (short)f2bf(vv.w) };
    *(bf16x4*)&klp[r][c] = pk;
  }
  #pragma unroll
  for (int i = 0; i < 8; i++) {
    int idx = i * 2048 + tid * 8;
    int r = idx >> 8, c = idx & 255;
    *(bf16x8*)&kvs[r][c] = *(const bf16x8*)&kvb[(size_t)r * MM + c];
  }
  __syncthreads();

  fp32x4 sacc[16];
  #pragma unroll
  for (int ct = 0; ct < 16; ct++) sacc[ct] = fp32x4{0,0,0,0};
  bf16x8 aF0 = *(const bf16x8*)&qs[wv * 16 + l15][quad * 8];
  bf16x8 aF1 = *(const bf16x8*)&qs[wv * 16 + l15][32 + quad * 8];
  #pragma unroll
  for (int ct = 0; ct < 16; ct++) {
    bf16x8 b0 = *(const bf16x8*)&klp[ct * 16 + l15][quad * 8];
    bf16x8 b1 = *(const bf16x8*)&klp[ct * 16 + l15][32 + quad * 8];
    sacc[ct] = __builtin_amdgcn_mfma_f32_16x16x32_bf16(aF0, b0, sacc[ct], 0, 0, 0);
    sacc[ct] = __builtin_amdgcn_mfma_f32_16x16x32_bf16(aF1, b1, sacc[ct], 0, 0, 0);
  }
  #pragma unroll
  for (int i = 0; i < 4; i++) {
    float m = -3.0e38f;
    #pragma unroll
    for (int ct = 0; ct < 16; ct++) m = fmaxf(m, sacc[ct][i]);
    #pragma unroll
    for (int o = 1; o < 16; o <<= 1) m = fmaxf(m, __shfl_xor(m, o));
    float s = 0.f;
    #pragma unroll
    for (int ct = 0; ct < 16; ct++) {
      float e = __expf(sacc[ct][i] - m);
      sacc[ct][i] = e;
      s += e;
    }
    #pragma unroll
    for (int o = 1; o < 16; o <<= 1) s += __shfl_xor(s, o);
    float inv = 1.f / s;
    #pragma unroll
    for (int ct = 0; ct < 16; ct++) sacc[ct][i] *= inv;
  }
  __syncthreads();
  u16* P = &klp[0][0];
  #pragma unroll
  for (int ct = 0; ct < 16; ct++)
    #pragma unroll
    for (int i = 0; i < 4; i++)
      P[(size_t)(wv * 16 + quad * 4 + i) * 264 + ct * 16 + l15] = f2bf(sacc[ct][i]);
  __syncthreads();

  fp32x4 oacc[4] = {fp32x4{0,0,0,0}, fp32x4{0,0,0,0}, fp32x4{0,0,0,0}, fp32x4{0,0,0,0}};
  #pragma unroll
  for (int ks = 0; ks < 8; ks++) {
    bf16x8 aP = *(const bf16x8*)&P[(size_t)(wv * 16 + l15) * 264 + ks * 32 + quad * 8];
    #pragma unroll
    for (int ct = 0; ct < 4; ct++) {
      bf16x8 bV = *(const bf16x8*)&kvs[ct * 16 + l15][ks * 32 + quad * 8];
      oacc[ct] = __builtin_amdgcn_mfma_f32_16x16x32_bf16(aP, bV, oacc[ct], 0, 0, 0);
    }
  }
  __syncthreads();
  float* vwin = (float*)&kvs[0][0];
  #pragma unroll
  for (int i = 0; i < 6; i++) {
    int r = i * 16 + (tid >> 4), c = (tid & 15) * 4;
    int g = n0 - 16 + r;
    float4 vv;
    if (g <= NPAD - 1) {
      bf16x4 bv = *(const bf16x4*)&vb[(size_t)g * DH + c];
      vv.x = bf2f((unsigned short)bv[0]); vv.y = bf2f((unsigned short)bv[1]);
      vv.z = bf2f((unsigned short)bv[2]); vv.w = bf2f((unsigned short)bv[3]);
    } else { vv.x = 0.f; vv.y = 0.f; vv.z = 0.f; vv.w = 0.f; }
    *(float4*)&vwin[r * 68 + c] = vv;
  }
  __syncthreads();
  #pragma unroll
  for (int ct = 0; ct < 4; ct++) {
    int c = ct * 16 + l15;
    #pragma unroll
    for (int i = 0; i < 4; i++) {
      int rl = wv * 16 + quad * 4 + i;
      int n = n0 + rl;
      if (n > NPAD - 1) continue;
      float ca = 0.f;
      #pragma unroll 11
      for (int t = 0; t < 33; t++) ca += vwin[(rl + t) * 68 + c] * wsm[t];
      attn[((size_t)b * NTOK + (n - 255)) * EMBED + hh * DH + c] = f2bf(oacc[ct][i] + ca);
    }
  }
}

// combine 7x7 + 5x5 + 3x3 + identity into one 7x7 depthwise kernel
__global__ void prep_wcomb_kernel(
    const float* __restrict__ pw7, const float* __restrict__ pw5,
    const float* __restrict__ pw3, const float* __restrict__ pb7,
    const float* __restrict__ pb5, const float* __restrict__ pb3,
    float* __restrict__ wcomb, float* __restrict__ biasc)
{
  int i = blockIdx.x * blockDim.x + threadIdx.x;
  if (i < EMBED * 49) {
    int c = i / 49, tap = i % 49;
    int ky = tap / 7, kx = tap % 7;
    float v = pw7[c * 49 + tap];
    if (ky >= 1 && ky <= 5 && kx >= 1 && kx <= 5) v += pw5[c * 25 + (ky - 1) * 5 + (kx - 1)];
    if (ky >= 2 && ky <= 4 && kx >= 2 && kx <= 4) v += pw3[c * 9 + (ky - 2) * 3 + (kx - 2)];
    if (ky == 3 && kx == 3) v += 1.f;
    wcomb[tap * EMBED + c] = v;
  }
  if (i < EMBED) biasc[i] = pb7[i] + pb5[i] + pb3[i];
}

// float4-per-thread depthwise conv: block (32,8) = 128 ch x 8 positions
__global__ __launch_bounds__(256) void dwconv_kernel(
    const float* __restrict__ tmp, const float* __restrict__ wcomb,
    const float* __restrict__ biasc, float* __restrict__ h)
{
  __shared__ float4 wsm[49][32];
  int tx = threadIdx.x;
  int ty = threadIdx.y;
  int cb = blockIdx.x * 128;
  int c = cb + tx * 4;
  int b = blockIdx.z;
  int n = blockIdx.y * 8 + ty;
  int y = n >> 6, x = n & 63;
  int tid = ty * 32 + tx;
  for (int i = tid; i < 49 * 32; i += 256) {
    int tap = i >> 5, g = i & 31;
    wsm[tap][g] = *(const float4*)&wcomb[tap * EMBED + cb + g * 4];
  }
  __syncthreads();
  const float* src = tmp + (size_t)b * N0 * EMBED;
  float4 acc = *(const float4*)&biasc[c];
  #pragma unroll
  for (int ky = 0; ky < 7; ky++) {
    int yy = y + ky - 3;
    if (yy < 0 || yy >= 64) continue;
    #pragma unroll
    for (int kx = 0; kx < 7; kx++) {
      int xx = x + kx - 3;
      if (xx < 0 || xx >= 64) continue;
      float4 vv = *(const float4*)&src[((size_t)yy * 64 + xx) * EMBED + c];
      float4 w = wsm[ky * 7 + kx][tx];
      acc.x += vv.x * w.x;
      acc.y += vv.y * w.y;
      acc.z += vv.z * w.z;
      acc.w += vv.w * w.w;
    }
  }
  *(float4*)&h[((size_t)b * NTOK + 1 + n) * EMBED + c] = acc;
}

__global__ __launch_bounds__(256) void final_kernel(
    const float* __restrict__ h, const float* __restrict__ g,
    const float* __restrict__ be, const float* __restrict__ W2,
    const float* __restrict__ b2, float* __restrict__ out)
{
  __shared__ float red[4];
  int b = blockIdx.x, tid = threadIdx.x;
  const float* x = h + (size_t)b * NTOK * EMBED;
  float v0 = x[tid], v1 = x[tid + 256];
  float mu = block_sum(v0 + v1, red) * (1.f / 512.f);
  float d0 = v0 - mu, d1 = v1 - mu;
  float var = block_sum(d0 * d0 + d1 * d1, red) * (1.f / 512.f);
  float inv = 1.f / sqrtf(var + 1e-5f);
  float xn0 = d0 * inv * g[tid] + be[tid];
  float xn1 = d1 * inv * g[tid + 256] + be[tid + 256];
  float l0 = block_sum(xn0 * W2[tid] + xn1 * W2[tid + 256], red);
  float l1 = block_sum(xn0 * W2[512 + tid] + xn1 * W2[512 + tid + 256], red);
  if (tid == 0) {
    l0 += b2[0]; l1 += b2[1];
    out[b * 2 + 0] = l0;
    out[b * 2 + 1] = l1;
    float mx = fmaxf(l0, l1);
    float e0 = expf(l0 - mx), e1 = expf(l1 - mx);
    float s = e0 + e1;
    out[8 + b * 2 + 0] = e0 / s;
    out[8 + b * 2 + 1] = e1 / s;
    out[16 + b] = (l1 > l0) ? 1.f : 0.f;
  }
}

// ------------------------------- host side -----------------------------------
extern "C" void kernel_launch(void* const* d_in, const int* in_sizes, int n_in,
                              void* d_out, int out_size, void* d_ws, size_t ws_size,
                              hipStream_t stream)
{
  const float* data = (const float*)d_in[0];
  const float* W1   = (const float*)d_in[1];
  const float* b1   = (const float*)d_in[2];
  const float* cls  = (const float*)d_in[3];
  const float* lng[2]  = {(const float*)d_in[4],  (const float*)d_in[10]};
  const float* lnb[2]  = {(const float*)d_in[5],  (const float*)d_in[11]};
  const float* Wqkv[2] = {(const float*)d_in[6],  (const float*)d_in[12]};
  const float* Wo[2]   = {(const float*)d_in[7],  (const float*)d_in[13]};
  const float* bo[2]   = {(const float*)d_in[8],  (const float*)d_in[14]};
  const float* resw[2] = {(const float*)d_in[9],  (const float*)d_in[15]};
  const float* pw7 = (const float*)d_in[16];
  const float* pb7 = (const float*)d_in[17];
  const float* pw5 = (const float*)d_in[18];
  const float* pb5 = (const float*)d_in[19];
  const float* pw3 = (const float*)d_in[20];
  const float* pb3 = (const float*)d_in[21];
  const float* lnfg = (const float*)d_in[22];
  const float* lnfb = (const float*)d_in[23];
  const float* W2  = (const float*)d_in[24];
  const float* b2  = (const float*)d_in[25];

  float* ws = (float*)d_ws;
  size_t off = 0;
  auto alloc = [&](size_t n) { float* p = ws + off; off += n; return p; };
  float* hbuf   = alloc((size_t)BATCH * NTOK * EMBED);          // fp32
  float* xpadf  = alloc((size_t)BATCH * NPAD * EMBED);          // bf16 (half) + attn reuse
  float* qbuff  = alloc((size_t)BH * NPAD * DH);                // q bf16 / databf / conv tmp fp32
  float* kbuff  = alloc((size_t)BH * NPAD * DH);                // k bf16 (half) + databf tail
  float* vbuff  = alloc((size_t)BH * NPAD * DH);                // v bf16 (half) + W1bf tail
  float* qland  = alloc((size_t)BH * MM * DH);
  float* kland  = alloc((size_t)BH * MM * DH);
  float* a2f    = alloc((size_t)BH * MM * MM / 2);              // bf16
  float* zaRf   = alloc((size_t)BH * MM * MM / 2);
  float* zaCf   = alloc((size_t)BH * MM * MM / 2);
  float* zbRf   = alloc((size_t)BH * MM * MM / 2);
  float* zbCf   = alloc((size_t)BH * MM * MM / 2);
  float* xzRf   = alloc((size_t)BH * MM * MM / 2);
  float* xzCf   = alloc((size_t)BH * MM * MM / 2);
  float* t1Cf   = alloc((size_t)BH * MM * MM / 2);
  float* t2Cf   = alloc((size_t)BH * MM * MM / 2);
  float* kvTf   = alloc((size_t)BH * MM * DH / 2);
  float* kv2Tf  = alloc((size_t)BH * MM * DH / 2);
  float* wqkvbf = alloc((size_t)2 * 3 * EMBED * EMBED / 2);     // bf16 x2 layers
  float* wobf   = alloc((size_t)2 * EMBED * EMBED / 2);
  float* wcomb  = alloc(49 * EMBED);
  float* biasc  = alloc(EMBED);
  float* denoms = alloc(64);
  float* mpart  = alloc((size_t)NSEG * BH * MM);
  float* lpart  = alloc((size_t)NSEG * BH * MM);

  u16* xpadB = (u16*)xpadf;
  u16* qB = (u16*)qbuff;
  u16* kB = (u16*)kbuff;
  u16* vB = (u16*)vbuff;
  u16* a2B = (u16*)a2f;
  u16* zaR = (u16*)zaRf; u16* zaC = (u16*)zaCf;
  u16* zbR = (u16*)zbRf; u16* zbC = (u16*)zbCf;
  u16* xzR = (u16*)xzRf; u16* xzC = (u16*)xzCf;
  u16* t1C = (u16*)t1Cf; u16* t2C = (u16*)t2Cf;
  u16* kvT = (u16*)kvTf; u16* kv2T = (u16*)kv2Tf;
  u16* attnB = xpadB;
  u16* OpartB = zaR;                       // overlay: free until z0_trans
  u16* databf = (u16*)qbuff;               // overlay: consumed by input GEMM only
  u16* W1bf = (u16*)vbuff;                 // overlay: consumed by input GEMM only
  u16* WqkvB[2] = {(u16*)wqkvbf, (u16*)wqkvbf + (size_t)3 * EMBED * EMBED};
  u16* WoB[2]   = {(u16*)wobf,   (u16*)wobf + (size_t)EMBED * EMBED};
  float* convtmp = qbuff;

  // ---- one-time bf16 conversions ----
  int ndata = BATCH * N0 * CIN;
  f2bf_kernel<<<dim3((ndata / 8 + 255) / 256), 256, 0, stream>>>(data, databf, ndata);
  f2bf_kernel<<<dim3((EMBED * CIN / 8 + 255) / 256), 256, 0, stream>>>(W1, W1bf, EMBED * CIN);
  for (int l = 0; l < 2; l++) {
    f2bf_kernel<<<dim3((3 * EMBED * EMBED / 8 + 255) / 256), 256, 0, stream>>>(Wqkv[l], WqkvB[l], 3 * EMBED * EMBED);
    f2bf_kernel<<<dim3((EMBED * EMBED / 8 + 255) / 256), 256, 0, stream>>>(Wo[l], WoB[l], EMBED * EMBED);
  }

  gemm_abt<<<dim3(EMBED / 128, (BATCH * N0) / 64), 256, 0, stream>>>(
      databf, W1bf, BATCH * N0, EMBED, CIN, b1, hbuf, nullptr, nullptr, nullptr, nullptr, 0);
  cls_kernel<<<dim3((BATCH * EMBED + 255) / 256), 256, 0, stream>>>(cls, hbuf);

  for (int layer = 0; layer < 2; layer++) {
    ln_pad_kernel<<<dim3(BATCH * NTOK), 256, 0, stream>>>(hbuf, lng[layer], lnb[layer], xpadB);
    zero_pad_kernel<<<dim3((BATCH * 255 * EMBED + 255) / 256), 256, 0, stream>>>(xpadB);
    gemm_abt<<<dim3((3 * EMBED) / 128, (BATCH * NPAD) / 64), 256, 0, stream>>>(
        xpadB, WqkvB[layer], BATCH * NPAD, 3 * EMBED, EMBED, nullptr,
        nullptr, nullptr, qB, kB, vB, 1);
    landmarks_kernel<<<dim3(MM / 4, BH), 256, 0, stream>>>(qB, kB, qland, kland);
    s2_softmax_kernel<<<dim3(MM, BH), 256, 0, stream>>>(qland, kland, a2B);
    init_denom_kernel<<<1, 64, 0, stream>>>(denoms);
    denom_kernel<<<dim3(BH), 256, 0, stream>>>(a2B, denoms);

    // a3@v before pinv so Opart can overlay the pinv scratch
    a3v_part_mfma<<<dim3(4 * NSEG, BH), 256, 0, stream>>>(
        qland, kB, vB, OpartB, mpart, lpart);
    a3v_merge_kernel<<<dim3(MM / 64, BH), 256, 0, stream>>>(OpartB, mpart, lpart, kvT);

    z0_trans_kernel<<<dim3(4, 4, BH), 256, 0, stream>>>(a2B, denoms, zaR, zaC);
    u16 *zinR = zaR, *zinC = zaC, *zoutR = zbR, *zoutC = zbC;
    for (int it = 0; it < 6; it++) {
      gemm_nn2<<<dim3(4, 4, BH), 256, 0, stream>>>(a2B, zinC, xzR, xzC, MM, 0.f, 1.f, 1.f);
      gemm_nn2<<<dim3(4, 4, BH), 256, 0, stream>>>(xzR, xzC, nullptr, t1C, MM, 7.f, -1.f, 1.f);
      gemm_nn2<<<dim3(4, 4, BH), 256, 0, stream>>>(xzR, t1C, nullptr, t2C, MM, 15.f, -1.f, 1.f);
      gemm_nn2<<<dim3(4, 4, BH), 256, 0, stream>>>(zinR, t2C, zoutR, zoutC, MM, 13.f, -1.f, 0.25f);
      u16* t;
      t = zinR; zinR = zoutR; zoutR = t;
      t = zinC; zinC = zoutC; zoutC = t;
    }
    // kv2T[dh][m] = (z @ kv)^T
    gemm_nn2<<<dim3(1, 4, BH), 256, 0, stream>>>(zinR, kvT, nullptr, kv2T, DH, 0.f, 1.f, 1.f);
    attn1_mfma<<<dim3((NTOK + 63) / 64, BH), 256, 0, stream>>>(
        qB, kland, kv2T, vB, resw[layer], attnB);
    gemm_abt<<<dim3(EMBED / 128, (BATCH * NTOK + 63) / 64), 256, 0, stream>>>(
        attnB, WoB[layer], BATCH * NTOK, EMBED, EMBED, bo[layer], hbuf,
        (layer == 0) ? convtmp : nullptr, nullptr, nullptr, nullptr,
        (layer == 0) ? 3 : 2);

    if (layer == 0) {
      prep_wcomb_kernel<<<dim3((EMBED * 49 + 255) / 256), 256, 0, stream>>>(
          pw7, pw5, pw3, pb7, pb5, pb3, wcomb, biasc);
      dwconv_kernel<<<dim3(EMBED / 128, N0 / 8, BATCH), dim3(32, 8), 0, stream>>>(
          convtmp, wcomb, biasc, hbuf);
    }
  }

  final_kernel<<<dim3(BATCH), 256, 0, stream>>>(hbuf, lnfg, lnfb, W2, b2, (float*)d_out);
}